// Round 1
// baseline (6698.501 us; speedup 1.0000x reference)
//
#include <hip/hip_runtime.h>

#define EPSF    1e-6f
#define BN_EPSF 1e-3f

// ---------------- conv1: 3->64, 3x3 s2 SAME, 240->120 (chunk of 8 images) ----
__global__ __launch_bounds__(64) void k_conv1(
        const float* __restrict__ img, int b0,
        const float* __restrict__ w, const float* __restrict__ bias,
        float* __restrict__ out) {
    const int co = threadIdx.x;            // 64
    const int ox = blockIdx.x;             // 120
    const int oy = blockIdx.y;             // 120
    const int bl = blockIdx.z;             // 8
    const int b  = b0 + bl;
    float acc = bias[co];
    #pragma unroll
    for (int ky = 0; ky < 3; ++ky) {
        const int iy = 2*oy + ky;
        if (iy >= 240) continue;
        #pragma unroll
        for (int kx = 0; kx < 3; ++kx) {
            const int ix = 2*ox + kx;
            if (ix >= 240) continue;
            const float* ip = img + ((size_t)(b*240 + iy)*240 + ix)*3;
            const float* wp = w + ((ky*3 + kx)*3)*64 + co;
            acc = fmaf(ip[0], wp[0],   acc);
            acc = fmaf(ip[1], wp[64],  acc);
            acc = fmaf(ip[2], wp[128], acc);
        }
    }
    out[((size_t)(bl*120 + oy)*120 + ox)*64 + co] = fmaxf(acc, 0.f);
}

// ---------------- conv2: 64->128, 3x3 s2 SAME, 120->60, x-tile 4 -------------
__global__ __launch_bounds__(128) void k_conv2(
        const float* __restrict__ in, const float* __restrict__ w,
        const float* __restrict__ bias, float* __restrict__ out) {
    const int co = threadIdx.x;            // 128
    const int x0 = blockIdx.x * 4;         // 15 tiles
    const int oy = blockIdx.y;             // 60
    const int bl = blockIdx.z;             // 8
    float a0=0.f, a1=0.f, a2=0.f, a3=0.f;
    #pragma unroll
    for (int ky = 0; ky < 3; ++ky) {
        const int iy = 2*oy + ky;
        if (iy >= 120) continue;
        const float* irow = in + (size_t)(bl*120 + iy)*120*64;
        #pragma unroll
        for (int kx = 0; kx < 3; ++kx) {
            const int ix0 = 2*x0 + kx;         // u-th x uses ix0 + 2u
            const bool v3 = (ix0 + 6) < 120;   // only u=3 can go OOB
            const float* wb = w + ((ky*3+kx)*64)*128 + co;
            for (int ci = 0; ci < 64; ci += 4) {
                const float4 i0 = *(const float4*)(irow + (size_t)(ix0    )*64 + ci);
                const float4 i1 = *(const float4*)(irow + (size_t)(ix0 + 2)*64 + ci);
                const float4 i2 = *(const float4*)(irow + (size_t)(ix0 + 4)*64 + ci);
                const float4 i3 = v3 ? *(const float4*)(irow + (size_t)(ix0 + 6)*64 + ci)
                                     : make_float4(0.f,0.f,0.f,0.f);
                const float w0 = wb[(ci+0)*128];
                const float w1 = wb[(ci+1)*128];
                const float w2 = wb[(ci+2)*128];
                const float w3 = wb[(ci+3)*128];
                a0 = fmaf(i0.x,w0,fmaf(i0.y,w1,fmaf(i0.z,w2,fmaf(i0.w,w3,a0))));
                a1 = fmaf(i1.x,w0,fmaf(i1.y,w1,fmaf(i1.z,w2,fmaf(i1.w,w3,a1))));
                a2 = fmaf(i2.x,w0,fmaf(i2.y,w1,fmaf(i2.z,w2,fmaf(i2.w,w3,a2))));
                a3 = fmaf(i3.x,w0,fmaf(i3.y,w1,fmaf(i3.z,w2,fmaf(i3.w,w3,a3))));
            }
        }
    }
    const float bb = bias[co];
    float* orow = out + ((size_t)(bl*60 + oy)*60 + x0)*128 + co;
    orow[0]   = fmaxf(a0 + bb, 0.f);
    orow[128] = fmaxf(a1 + bb, 0.f);
    orow[256] = fmaxf(a2 + bb, 0.f);
    orow[384] = fmaxf(a3 + bb, 0.f);
}

// ---------------- conv3: 128->256, 3x3 s2 SAME, 60->30, x-tile 6, +relu ------
__global__ __launch_bounds__(256) void k_conv3(
        const float* __restrict__ in, const float* __restrict__ w,
        const float* __restrict__ bias, float* __restrict__ feat, int f0) {
    const int co = threadIdx.x;            // 256
    const int x0 = blockIdx.x * 6;         // 5 tiles
    const int oy = blockIdx.y;             // 30
    const int bl = blockIdx.z;             // 8
    float acc[6] = {0.f,0.f,0.f,0.f,0.f,0.f};
    #pragma unroll
    for (int ky = 0; ky < 3; ++ky) {
        const int iy = 2*oy + ky;
        if (iy >= 60) continue;
        const float* irow = in + (size_t)(bl*60 + iy)*60*128;
        #pragma unroll
        for (int kx = 0; kx < 3; ++kx) {
            const int ix0 = 2*x0 + kx;
            const bool v5 = (ix0 + 10) < 60;   // only u=5 can go OOB
            const float* wb = w + ((ky*3+kx)*128)*256 + co;
            for (int ci = 0; ci < 128; ci += 4) {
                float4 iv[6];
                #pragma unroll
                for (int u = 0; u < 5; ++u)
                    iv[u] = *(const float4*)(irow + (size_t)(ix0 + 2*u)*128 + ci);
                iv[5] = v5 ? *(const float4*)(irow + (size_t)(ix0 + 10)*128 + ci)
                           : make_float4(0.f,0.f,0.f,0.f);
                const float w0 = wb[(ci+0)*256];
                const float w1 = wb[(ci+1)*256];
                const float w2 = wb[(ci+2)*256];
                const float w3 = wb[(ci+3)*256];
                #pragma unroll
                for (int u = 0; u < 6; ++u)
                    acc[u] = fmaf(iv[u].x,w0,fmaf(iv[u].y,w1,fmaf(iv[u].z,w2,fmaf(iv[u].w,w3,acc[u]))));
            }
        }
    }
    const float bb = bias[co];
    #pragma unroll
    for (int u = 0; u < 6; ++u)
        feat[((size_t)(f0+bl)*900 + oy*30 + x0 + u)*256 + co] = fmaxf(acc[u] + bb, 0.f);
}

// ---------------- l2norm over 256 channels, in place -------------------------
__global__ __launch_bounds__(256) void k_l2norm(float* __restrict__ feat) {
    const int p = blockIdx.x;              // 32*900
    const int t = threadIdx.x;             // 256
    float* fp = feat + (size_t)p*256;
    const float v = fp[t];
    float s = v*v;
    #pragma unroll
    for (int m = 1; m < 64; m <<= 1) s += __shfl_xor(s, m);
    __shared__ float red[4];
    if ((t & 63) == 0) red[t >> 6] = s;
    __syncthreads();
    const float tot = red[0] + red[1] + red[2] + red[3];
    fp[t] = v / sqrtf(tot + EPSF);
}

// ---------------- corr: per-b GEMM 900x256 @ (900x256)^T, 64x64 tile ---------
__global__ __launch_bounds__(256) void k_corr(
        const float* __restrict__ feat, float* __restrict__ corr) {
    const int b  = blockIdx.z;             // 16
    const int p0 = blockIdx.y * 64;        // 15
    const int q0 = blockIdx.x * 64;        // 15
    const float* Ap = feat + (size_t)b*900*256;
    const float* Bp = feat + (size_t)(16+b)*900*256;
    __shared__ float As[32][64];           // [k][p]
    __shared__ float Bs[32][64];           // [k][q]
    const int t  = threadIdx.x;            // 256
    const int tr = (t & 15) * 4;
    const int tc = (t >> 4) * 4;
    const int r  = t >> 2;                 // staging row 0..63
    const int kg = (t & 3) * 8;            // staging k-group
    float acc[4][4] = {};
    for (int k0 = 0; k0 < 256; k0 += 32) {
        float av[8] = {0,0,0,0,0,0,0,0};
        float bv[8] = {0,0,0,0,0,0,0,0};
        if (p0 + r < 900) {
            const float4 x0 = *(const float4*)(Ap + (size_t)(p0+r)*256 + k0 + kg);
            const float4 x1 = *(const float4*)(Ap + (size_t)(p0+r)*256 + k0 + kg + 4);
            av[0]=x0.x; av[1]=x0.y; av[2]=x0.z; av[3]=x0.w;
            av[4]=x1.x; av[5]=x1.y; av[6]=x1.z; av[7]=x1.w;
        }
        if (q0 + r < 900) {
            const float4 y0 = *(const float4*)(Bp + (size_t)(q0+r)*256 + k0 + kg);
            const float4 y1 = *(const float4*)(Bp + (size_t)(q0+r)*256 + k0 + kg + 4);
            bv[0]=y0.x; bv[1]=y0.y; bv[2]=y0.z; bv[3]=y0.w;
            bv[4]=y1.x; bv[5]=y1.y; bv[6]=y1.z; bv[7]=y1.w;
        }
        __syncthreads();
        #pragma unroll
        for (int e = 0; e < 8; ++e) { As[kg+e][r] = av[e]; Bs[kg+e][r] = bv[e]; }
        __syncthreads();
        #pragma unroll 8
        for (int kk = 0; kk < 32; ++kk) {
            const float4 a  = *(const float4*)&As[kk][tr];
            const float4 bq = *(const float4*)&Bs[kk][tc];
            const float aa[4] = {a.x, a.y, a.z, a.w};
            const float bb[4] = {bq.x, bq.y, bq.z, bq.w};
            #pragma unroll
            for (int i = 0; i < 4; ++i)
                #pragma unroll
                for (int j = 0; j < 4; ++j)
                    acc[i][j] = fmaf(aa[i], bb[j], acc[i][j]);
        }
        __syncthreads();
    }
    #pragma unroll
    for (int i = 0; i < 4; ++i) {
        const int p = p0 + tr + i;
        if (p < 900) {
            float* crow = corr + ((size_t)b*900 + p)*900;
            #pragma unroll
            for (int j = 0; j < 4; ++j) {
                const int q = q0 + tc + j;
                if (q < 900) crow[q] = acc[i][j];
            }
        }
    }
}

// ---------------- relu + L2 norm over 900 correlation channels ---------------
__global__ __launch_bounds__(256) void k_corrnorm(float* __restrict__ corr) {
    const int row = blockIdx.x;            // 16*900
    const int t = threadIdx.x;             // 256
    float* cp = corr + (size_t)row*900;
    float v[4];
    float s = 0.f;
    #pragma unroll
    for (int i = 0; i < 4; ++i) {
        const int q = t + 256*i;
        float x = 0.f;
        if (q < 900) x = fmaxf(cp[q], 0.f);
        v[i] = x;
        s += x*x;
    }
    #pragma unroll
    for (int m = 1; m < 64; m <<= 1) s += __shfl_xor(s, m);
    __shared__ float red[4];
    if ((t & 63) == 0) red[t >> 6] = s;
    __syncthreads();
    const float sc = 1.f / sqrtf(red[0]+red[1]+red[2]+red[3] + EPSF);
    #pragma unroll
    for (int i = 0; i < 4; ++i) {
        const int q = t + 256*i;
        if (q < 900) cp[q] = v[i] * sc;
    }
}

// ---------------- cw1 conv as implicit-im2col GEMM ---------------------------
// M=9216 (b,oy,ox), N=128, K=44100=(ky*7+kx)*900+q ; K split in 4, partials out
#define CW1_KLEN 11025
__global__ __launch_bounds__(256) void k_cw1(
        const float* __restrict__ X, const float* __restrict__ W,
        float* __restrict__ part) {
    const int mt = blockIdx.x;             // 144
    const int ks = blockIdx.y;             // 4
    const int m0 = mt * 64;
    const int kbeg = ks * CW1_KLEN;
    const int kend = kbeg + CW1_KLEN;
    __shared__ float As[32][68];           // [k][m], pad 68 to spread write banks
    __shared__ float Bs[32][128];          // [k][n]
    const int t  = threadIdx.x;            // 256
    const int r0 = (t & 7) * 8;            // micro rows (8)
    const int c0 = (t >> 3) * 4;           // micro cols (4)
    const int kk  = t & 31;                // A staging k
    const int rb  = t >> 5;                // A staging row base (+8i)
    const int bkk = t >> 3;                // B staging k row
    const int cb  = (t & 7) * 16;          // B staging col base
    float acc[8][4] = {};
    int abase[8];
    #pragma unroll
    for (int i = 0; i < 8; ++i) {
        const int m  = m0 + rb + 8*i;
        const int bb = m / 576;
        const int re = m - bb*576;
        const int oy = re / 24;
        const int ox = re - oy*24;
        abase[i] = ((bb*30 + oy)*30 + ox)*900;
    }
    for (int k0 = kbeg; k0 < kend; k0 += 32) {
        float av[8] = {0,0,0,0,0,0,0,0};
        const int k = k0 + kk;
        if (k < kend) {
            const int kyx = k / 900;
            const int q   = k - kyx*900;
            const int ky  = kyx / 7;
            const int kx  = kyx - ky*7;
            const int koff = (ky*30 + kx)*900 + q;
            #pragma unroll
            for (int i = 0; i < 8; ++i) av[i] = X[abase[i] + koff];
        }
        float4 bvv[4];
        const int krow = k0 + bkk;
        const bool bvld = krow < kend;
        #pragma unroll
        for (int j = 0; j < 4; ++j)
            bvv[j] = bvld ? *(const float4*)(W + (size_t)krow*128 + cb + 4*j)
                          : make_float4(0.f,0.f,0.f,0.f);
        __syncthreads();
        #pragma unroll
        for (int i = 0; i < 8; ++i) As[kk][rb + 8*i] = av[i];
        #pragma unroll
        for (int j = 0; j < 4; ++j) *(float4*)&Bs[bkk][cb + 4*j] = bvv[j];
        __syncthreads();
        #pragma unroll 4
        for (int u = 0; u < 32; ++u) {
            const float4 a0 = *(const float4*)&As[u][r0];
            const float4 a1 = *(const float4*)&As[u][r0+4];
            const float4 b4 = *(const float4*)&Bs[u][c0];
            const float aa[8] = {a0.x,a0.y,a0.z,a0.w,a1.x,a1.y,a1.z,a1.w};
            const float bb[4] = {b4.x,b4.y,b4.z,b4.w};
            #pragma unroll
            for (int i = 0; i < 8; ++i)
                #pragma unroll
                for (int j = 0; j < 4; ++j)
                    acc[i][j] = fmaf(aa[i], bb[j], acc[i][j]);
        }
    }
    float* pb = part + ((size_t)ks*9216 + m0)*128;
    #pragma unroll
    for (int i = 0; i < 8; ++i)
        *(float4*)&pb[(size_t)(r0+i)*128 + c0] =
            make_float4(acc[i][0], acc[i][1], acc[i][2], acc[i][3]);
}

// ---------------- reduce K-split partials + bias + relu + BN -----------------
__global__ __launch_bounds__(256) void k_r1fin(
        const float* __restrict__ part, const float* __restrict__ cb1,
        const float* __restrict__ g1, const float* __restrict__ be1,
        const float* __restrict__ m1, const float* __restrict__ v1,
        float* __restrict__ r1) {
    const int idx = blockIdx.x*256 + threadIdx.x;
    const int N = 9216*128;
    if (idx >= N) return;
    const int co = idx & 127;
    float s = part[idx] + part[idx + N] + part[idx + 2*N] + part[idx + 3*N];
    s = fmaxf(s + cb1[co], 0.f);
    s = (s - m1[co]) * (g1[co] / sqrtf(v1[co] + BN_EPSF)) + be1[co];
    r1[idx] = s;
}

// ---------------- cw2: 5x5 VALID 128->64, + bias + relu + BN -----------------
__global__ __launch_bounds__(256) void k_cw2(
        const float* __restrict__ in, const float* __restrict__ w,
        const float* __restrict__ cb2, const float* __restrict__ g2,
        const float* __restrict__ be2, const float* __restrict__ m2,
        const float* __restrict__ v2, float* __restrict__ out) {
    const int t  = threadIdx.x;            // 256
    const int co = t & 63;
    const int u  = t >> 6;                 // 0..3
    const int x  = blockIdx.x*4 + u;       // 20
    const int oy = blockIdx.y;             // 20
    const int b  = blockIdx.z;             // 16
    float acc = 0.f;
    #pragma unroll
    for (int ky = 0; ky < 5; ++ky) {
        const float* irow = in + (size_t)(b*24 + oy + ky)*24*128;
        #pragma unroll
        for (int kx = 0; kx < 5; ++kx) {
            const float* ip = irow + (size_t)(x + kx)*128;
            const float* wp = w + ((ky*5 + kx)*128)*64 + co;
            for (int ci = 0; ci < 128; ci += 4) {
                const float4 iv = *(const float4*)(ip + ci);
                acc = fmaf(iv.x, wp[(ci+0)*64],
                      fmaf(iv.y, wp[(ci+1)*64],
                      fmaf(iv.z, wp[(ci+2)*64],
                      fmaf(iv.w, wp[(ci+3)*64], acc))));
            }
        }
    }
    float s = fmaxf(acc + cb2[co], 0.f);
    s = (s - m2[co]) * (g2[co] / sqrtf(v2[co] + BN_EPSF)) + be2[co];
    out[((size_t)(b*20 + oy)*20 + x)*64 + co] = s;
}

// ---------------- dense: [16,25600] @ [25600,18] + db ------------------------
__global__ __launch_bounds__(256) void k_dense(
        const float* __restrict__ r2, const float* __restrict__ dw,
        const float* __restrict__ db, float* __restrict__ out) {
    const int j = blockIdx.x;              // 18
    const int b = blockIdx.y;              // 16
    const int t = threadIdx.x;             // 256
    const float* x = r2 + (size_t)b*25600;
    float s = 0.f;
    for (int k = t; k < 25600; k += 256) s = fmaf(x[k], dw[(size_t)k*18 + j], s);
    #pragma unroll
    for (int m = 1; m < 64; m <<= 1) s += __shfl_xor(s, m);
    __shared__ float red[4];
    if ((t & 63) == 0) red[t >> 6] = s;
    __syncthreads();
    if (t == 0) out[b*18 + j] = red[0] + red[1] + red[2] + red[3] + db[j];
}

extern "C" void kernel_launch(void* const* d_in, const int* in_sizes, int n_in,
                              void* d_out, int out_size, void* d_ws, size_t ws_size,
                              hipStream_t stream) {
    const float* imgA = (const float*)d_in[0];
    const float* imgB = (const float*)d_in[1];
    const float* w1  = (const float*)d_in[2];
    const float* b1  = (const float*)d_in[3];
    const float* w2  = (const float*)d_in[4];
    const float* b2  = (const float*)d_in[5];
    const float* w3  = (const float*)d_in[6];
    const float* b3  = (const float*)d_in[7];
    const float* cw1 = (const float*)d_in[8];
    const float* cb1 = (const float*)d_in[9];
    const float* g1  = (const float*)d_in[10];
    const float* be1 = (const float*)d_in[11];
    const float* m1  = (const float*)d_in[12];
    const float* v1  = (const float*)d_in[13];
    const float* cw2 = (const float*)d_in[14];
    const float* cb2 = (const float*)d_in[15];
    const float* g2  = (const float*)d_in[16];
    const float* be2 = (const float*)d_in[17];
    const float* m2  = (const float*)d_in[18];
    const float* v2  = (const float*)d_in[19];
    const float* dw  = (const float*)d_in[20];
    const float* db  = (const float*)d_in[21];

    // workspace layout (bytes), total required = 81,331,200
    //   [0,         29491200) feat [32,900,256]  -> later reused: part (18.9MB) + r1 + r2
    //   [29491200,  81331200) corr [16,900,900]  -> earlier reused: c1 (29.5MB) + c2 (14.7MB)
    char* ws = (char*)d_ws;
    float* feat = (float*)ws;
    float* corr = (float*)(ws + 29491200);
    float* c1   = corr;
    float* c2   = (float*)(ws + 58982400);
    float* part = feat;
    float* r1   = (float*)(ws + 18874368);
    float* r2   = (float*)(ws + 23592960);

    for (int chunk = 0; chunk < 4; ++chunk) {
        const float* img = (chunk < 2) ? imgA : imgB;
        const int b0 = (chunk & 1) * 8;
        const int f0 = chunk * 8;
        k_conv1<<<dim3(120,120,8), 64,  0, stream>>>(img, b0, w1, b1, c1);
        k_conv2<<<dim3(15,60,8),   128, 0, stream>>>(c1, w2, b2, c2);
        k_conv3<<<dim3(5,30,8),    256, 0, stream>>>(c2, w3, b3, feat, f0);
    }
    k_l2norm  <<<dim3(28800),    256, 0, stream>>>(feat);
    k_corr    <<<dim3(15,15,16), 256, 0, stream>>>(feat, corr);
    k_corrnorm<<<dim3(14400),    256, 0, stream>>>(corr);
    k_cw1     <<<dim3(144,4),    256, 0, stream>>>(corr, cw1, part);
    k_r1fin   <<<dim3(4608),     256, 0, stream>>>(part, cb1, g1, be1, m1, v1, r1);
    k_cw2     <<<dim3(5,20,16),  256, 0, stream>>>(r1, cw2, cb2, g2, be2, m2, v2, r2);
    k_dense   <<<dim3(18,16),    256, 0, stream>>>(r2, dw, db, (float*)d_out);
}

// Round 2
// 1048.499 us; speedup vs baseline: 6.3887x; 6.3887x over previous
//
#include <hip/hip_runtime.h>

#define EPSF    1e-6f
#define BN_EPSF 1e-3f

typedef __attribute__((ext_vector_type(8))) short bf16x8;   // 8 bf16 in 4 VGPRs
typedef __attribute__((ext_vector_type(4))) float f32x4;

__device__ __forceinline__ unsigned short f2bf(float f) {
    unsigned int u = __builtin_bit_cast(unsigned int, f);
    u = (u + 0x7FFFu + ((u >> 16) & 1u)) >> 16;            // RNE
    return (unsigned short)u;
}
__device__ __forceinline__ float bf2f(unsigned short h) {
    unsigned int u = ((unsigned int)h) << 16;
    return __builtin_bit_cast(float, u);
}
// async global->LDS, 16 bytes per lane; lds dest must be wave-uniform base (+lane*16 by HW)
__device__ __forceinline__ void gl16(const void* g, void* l) {
    __builtin_amdgcn_global_load_lds((const __attribute__((address_space(1))) void*)g,
                                     (__attribute__((address_space(3))) void*)l, 16, 0, 0);
}

// ======================= weight conversion kernels ===========================
// w2t[n][k], k=(ky*3+kx)*64+ci, n=128, K=576
__global__ __launch_bounds__(256) void k_w2t(const float* __restrict__ w2,
                                             unsigned short* __restrict__ w2t) {
    int idx = blockIdx.x * 256 + threadIdx.x;              // 73728
    int n = idx / 576, k = idx - n * 576;
    w2t[idx] = f2bf(w2[(size_t)k * 128 + n]);
}
// w3t[n][k], k=(ky*3+kx)*128+ci, n=256, K=1152
__global__ __launch_bounds__(256) void k_w3t(const float* __restrict__ w3,
                                             unsigned short* __restrict__ w3t) {
    int idx = blockIdx.x * 256 + threadIdx.x;              // 294912
    int n = idx / 1152, k = idx - n * 1152;
    w3t[idx] = f2bf(w3[(size_t)k * 256 + n]);
}
// Wt[n][k'], k'=s*928+q (s=ky*7+kx<49, q<928), zero for q>=900. n=128.
__global__ __launch_bounds__(256) void k_wt1(const float* __restrict__ W,
                                             unsigned short* __restrict__ Wt) {
    int kp = blockIdx.x * 256 + threadIdx.x;               // grid.x=178
    int n = blockIdx.y;                                    // 128
    if (kp >= 45472) return;
    int s = kp / 928, q = kp - s * 928;
    unsigned short v = 0;
    if (q < 900) v = f2bf(W[(size_t)(s * 900 + q) * 128 + n]);
    Wt[(size_t)n * 45472 + kp] = v;
}

// ======================= conv1 (fp32 in -> bf16 padded out) ==================
// c1: [8][121][121][64] bf16, borders zeroed by k_zb1
__global__ __launch_bounds__(256) void k_conv1(
        const float* __restrict__ img, int b0,
        const float* __restrict__ w, const float* __restrict__ bias,
        unsigned short* __restrict__ c1) {
    const int co = threadIdx.x & 63, u = threadIdx.x >> 6;
    const int ox = blockIdx.x * 4 + u;                     // 120
    const int oy = blockIdx.y;                             // 120
    const int bl = blockIdx.z;                             // 8
    const int b = b0 + bl;
    float acc = bias[co];
    #pragma unroll
    for (int ky = 0; ky < 3; ++ky) {
        const int iy = 2 * oy + ky;
        if (iy >= 240) continue;
        #pragma unroll
        for (int kx = 0; kx < 3; ++kx) {
            const int ix = 2 * ox + kx;
            if (ix >= 240) continue;
            const float* ip = img + ((size_t)(b * 240 + iy) * 240 + ix) * 3;
            const float* wp = w + ((ky * 3 + kx) * 3) * 64 + co;
            acc = fmaf(ip[0], wp[0], acc);
            acc = fmaf(ip[1], wp[64], acc);
            acc = fmaf(ip[2], wp[128], acc);
        }
    }
    c1[((size_t)(bl * 121 + oy) * 121 + ox) * 64 + co] = f2bf(fmaxf(acc, 0.f));
}
__global__ __launch_bounds__(256) void k_zb1(unsigned short* __restrict__ c1) {
    const int bl = blockIdx.y, z = blockIdx.x, t = threadIdx.x;
    if (z == 0) {
        for (int i = t; i < 121 * 64; i += 256)
            c1[(size_t)(bl * 121 + 120) * 121 * 64 + i] = 0;
    } else {
        for (int i = t; i < 121 * 64; i += 256) {
            int oy = i >> 6, ci = i & 63;
            c1[((size_t)(bl * 121 + oy) * 121 + 120) * 64 + ci] = 0;
        }
    }
}
__global__ __launch_bounds__(256) void k_zb2(unsigned short* __restrict__ c2) {
    const int bl = blockIdx.y, z = blockIdx.x, t = threadIdx.x;
    if (z == 0) {
        for (int i = t; i < 61 * 128; i += 256)
            c2[(size_t)(bl * 61 + 60) * 61 * 128 + i] = 0;
    } else {
        for (int i = t; i < 61 * 128; i += 256) {
            int oy = i >> 7, ci = i & 127;
            c2[((size_t)(bl * 61 + oy) * 61 + 60) * 128 + ci] = 0;
        }
    }
}

// ======================= conv2 MFMA: M=28800 N=128 K=576 =====================
__global__ __launch_bounds__(256) void k_conv2(
        const unsigned short* __restrict__ c1, const unsigned short* __restrict__ w2t,
        const float* __restrict__ b2, unsigned short* __restrict__ c2) {
    __shared__ __align__(16) unsigned short As[2][128 * 32];
    __shared__ __align__(16) unsigned short Bs[2][128 * 32];
    const int t = threadIdx.x, w = t >> 6, l = t & 63;
    const int m0 = blockIdx.x * 128;
    const int ko = (l & 3) * 8;
    size_t aga[2], bga[2];
    #pragma unroll
    for (int i = 0; i < 2; ++i) {
        int r = (w * 2 + i) * 16 + (l >> 2);
        int m = m0 + r;
        int bl = m / 3600, rem = m - bl * 3600, oy = rem / 60, ox = rem - oy * 60;
        aga[i] = (size_t)((bl * 121 + 2 * oy) * 121 + 2 * ox) * 64 + ko;
        bga[i] = (size_t)r * 576 + ko;
    }
    const int wr = (w >> 1) * 64, wc = (w & 1) * 64, lr = l & 15, lk = (l >> 4) * 8;
    f32x4 acc[4][4] = {};
    auto stage = [&](int buf, int s) {
        int ky = s / 6, r6 = s - ky * 6, kx = r6 >> 1, h = r6 & 1;
        int aoff = (ky * 121 + kx) * 64 + h * 32;
        int boff = (ky * 3 + kx) * 64 + h * 32;
        #pragma unroll
        for (int i = 0; i < 2; ++i) {
            gl16(c1 + aga[i] + aoff, &As[buf][(w * 2 + i) * 512]);
            gl16(w2t + bga[i] + boff, &Bs[buf][(w * 2 + i) * 512]);
        }
    };
    stage(0, 0);
    __syncthreads();
    int cur = 0;
    for (int s = 0; s < 18; ++s) {
        if (s + 1 < 18) stage(cur ^ 1, s + 1);
        bf16x8 af[4], bfv[4];
        #pragma unroll
        for (int i = 0; i < 4; ++i) af[i] = *(const bf16x8*)&As[cur][(wr + i * 16 + lr) * 32 + lk];
        #pragma unroll
        for (int j = 0; j < 4; ++j) bfv[j] = *(const bf16x8*)&Bs[cur][(wc + j * 16 + lr) * 32 + lk];
        #pragma unroll
        for (int i = 0; i < 4; ++i)
            #pragma unroll
            for (int j = 0; j < 4; ++j)
                acc[i][j] = __builtin_amdgcn_mfma_f32_16x16x32_bf16(af[i], bfv[j], acc[i][j], 0, 0, 0);
        __syncthreads();
        cur ^= 1;
    }
    float bias[4];
    #pragma unroll
    for (int j = 0; j < 4; ++j) bias[j] = b2[wc + j * 16 + lr];
    #pragma unroll
    for (int i = 0; i < 4; ++i)
        #pragma unroll
        for (int r = 0; r < 4; ++r) {
            int m = m0 + wr + i * 16 + (l >> 4) * 4 + r;
            int bl = m / 3600, rem = m - bl * 3600, oy = rem / 60, ox = rem - oy * 60;
            size_t ob = (size_t)((bl * 61 + oy) * 61 + ox) * 128;
            #pragma unroll
            for (int j = 0; j < 4; ++j)
                c2[ob + wc + j * 16 + lr] = f2bf(fmaxf(acc[i][j][r] + bias[j], 0.f));
        }
}

// ======================= conv3 MFMA: M=7200 N=256 K=1152 =====================
__global__ __launch_bounds__(256) void k_conv3(
        const unsigned short* __restrict__ c2, const unsigned short* __restrict__ w3t,
        const float* __restrict__ b3, unsigned short* __restrict__ feat, int f0) {
    __shared__ __align__(16) unsigned short As[2][128 * 32];
    __shared__ __align__(16) unsigned short Bs[2][64 * 32];
    const int t = threadIdx.x, w = t >> 6, l = t & 63;
    const int m0 = blockIdx.x * 128, n0 = blockIdx.y * 64;   // grid (57,4)
    const int ko = (l & 3) * 8;
    size_t aga[2], bga;
    #pragma unroll
    for (int i = 0; i < 2; ++i) {
        int r = (w * 2 + i) * 16 + (l >> 2);
        int m = min(m0 + r, 7199);
        int bl = m / 900, rem = m - bl * 900, oy = rem / 30, ox = rem - oy * 30;
        aga[i] = (size_t)((bl * 61 + 2 * oy) * 61 + 2 * ox) * 128 + ko;
    }
    { int n = n0 + w * 16 + (l >> 2); bga = (size_t)n * 1152 + ko; }
    const int wr = (w >> 1) * 64, wc = (w & 1) * 32, lr = l & 15, lk = (l >> 4) * 8;
    f32x4 acc[4][2] = {};
    auto stage = [&](int buf, int s) {
        int ky = s / 12, r12 = s - ky * 12, kx = r12 >> 2, h = r12 & 3;
        int aoff = (ky * 61 + kx) * 128 + h * 32;
        int boff = (ky * 3 + kx) * 128 + h * 32;
        #pragma unroll
        for (int i = 0; i < 2; ++i)
            gl16(c2 + aga[i] + aoff, &As[buf][(w * 2 + i) * 512]);
        gl16(w3t + bga + boff, &Bs[buf][w * 512]);
    };
    stage(0, 0);
    __syncthreads();
    int cur = 0;
    for (int s = 0; s < 36; ++s) {
        if (s + 1 < 36) stage(cur ^ 1, s + 1);
        bf16x8 af[4], bfv[2];
        #pragma unroll
        for (int i = 0; i < 4; ++i) af[i] = *(const bf16x8*)&As[cur][(wr + i * 16 + lr) * 32 + lk];
        #pragma unroll
        for (int j = 0; j < 2; ++j) bfv[j] = *(const bf16x8*)&Bs[cur][(wc + j * 16 + lr) * 32 + lk];
        #pragma unroll
        for (int i = 0; i < 4; ++i)
            #pragma unroll
            for (int j = 0; j < 2; ++j)
                acc[i][j] = __builtin_amdgcn_mfma_f32_16x16x32_bf16(af[i], bfv[j], acc[i][j], 0, 0, 0);
        __syncthreads();
        cur ^= 1;
    }
    float bias[2];
    #pragma unroll
    for (int j = 0; j < 2; ++j) bias[j] = b3[n0 + wc + j * 16 + lr];
    #pragma unroll
    for (int i = 0; i < 4; ++i)
        #pragma unroll
        for (int r = 0; r < 4; ++r) {
            int m = m0 + wr + i * 16 + (l >> 4) * 4 + r;
            if (m < 7200) {
                int bl = m / 900, pos = m - bl * 900;
                size_t ob = ((size_t)(f0 + bl) * 960 + pos) * 256;
                #pragma unroll
                for (int j = 0; j < 2; ++j)
                    feat[ob + n0 + wc + j * 16 + lr] = f2bf(fmaxf(acc[i][j][r] + bias[j], 0.f));
            }
        }
}

// ======================= l2norm (bf16, zero pad rows) ========================
__global__ __launch_bounds__(256) void k_l2norm(unsigned short* __restrict__ feat) {
    const int R = blockIdx.x;                  // 32*960
    const int pos = R % 960;
    const int t = threadIdx.x;
    unsigned short* fp = feat + (size_t)R * 256;
    if (pos >= 900) { fp[t] = 0; return; }
    const float v = bf2f(fp[t]);
    float s = v * v;
    #pragma unroll
    for (int m = 1; m < 64; m <<= 1) s += __shfl_xor(s, m);
    __shared__ float red[4];
    if ((t & 63) == 0) red[t >> 6] = s;
    __syncthreads();
    const float tot = red[0] + red[1] + red[2] + red[3];
    fp[t] = f2bf(v / sqrtf(tot + EPSF));
}

// ======================= corr MFMA: per-b 960x960, relu, bf16 ================
__global__ __launch_bounds__(256) void k_corr(
        const unsigned short* __restrict__ feat, unsigned short* __restrict__ corr) {
    __shared__ __align__(16) unsigned short As[2][64 * 32];
    __shared__ __align__(16) unsigned short Bs[2][64 * 32];
    const int t = threadIdx.x, w = t >> 6, l = t & 63;
    const int b = blockIdx.z, p0 = blockIdx.y * 64, q0 = blockIdx.x * 64;
    const int ko = (l & 3) * 8;
    const unsigned short* base = feat + (size_t)((w < 2) ? b : 16 + b) * 960 * 256;
    const int r0 = (w < 2) ? p0 : q0;
    const int wi = w & 1;
    size_t ga[2];
    #pragma unroll
    for (int i = 0; i < 2; ++i) {
        int row = (wi * 2 + i) * 16 + (l >> 2);
        ga[i] = (size_t)(r0 + row) * 256 + ko;
    }
    const int wr = (w >> 1) * 32, wc = (w & 1) * 32, lr = l & 15, lk = (l >> 4) * 8;
    f32x4 acc[2][2] = {};
    auto stage = [&](int buf, int k0) {
        #pragma unroll
        for (int i = 0; i < 2; ++i) {
            unsigned short* dst = (w < 2) ? &As[buf][(wi * 2 + i) * 512]
                                          : &Bs[buf][(wi * 2 + i) * 512];
            gl16(base + ga[i] + k0, dst);
        }
    };
    stage(0, 0);
    __syncthreads();
    int cur = 0;
    for (int s = 0; s < 8; ++s) {
        if (s + 1 < 8) stage(cur ^ 1, (s + 1) * 32);
        bf16x8 af[2], bfv[2];
        #pragma unroll
        for (int i = 0; i < 2; ++i) af[i] = *(const bf16x8*)&As[cur][(wr + i * 16 + lr) * 32 + lk];
        #pragma unroll
        for (int j = 0; j < 2; ++j) bfv[j] = *(const bf16x8*)&Bs[cur][(wc + j * 16 + lr) * 32 + lk];
        #pragma unroll
        for (int i = 0; i < 2; ++i)
            #pragma unroll
            for (int j = 0; j < 2; ++j)
                acc[i][j] = __builtin_amdgcn_mfma_f32_16x16x32_bf16(af[i], bfv[j], acc[i][j], 0, 0, 0);
        __syncthreads();
        cur ^= 1;
    }
    unsigned short* cb = corr + (size_t)b * 960 * 960;
    #pragma unroll
    for (int i = 0; i < 2; ++i)
        #pragma unroll
        for (int r = 0; r < 4; ++r) {
            int row = p0 + wr + i * 16 + (l >> 4) * 4 + r;
            #pragma unroll
            for (int j = 0; j < 2; ++j)
                cb[(size_t)row * 960 + q0 + wc + j * 16 + lr] = f2bf(fmaxf(acc[i][j][r], 0.f));
        }
}

// ======================= corr L2 norm over 900 channels ======================
__global__ __launch_bounds__(256) void k_corrnorm(unsigned short* __restrict__ corr) {
    const int rb = blockIdx.x;                 // 16*900
    const int b = rb / 900, p = rb - b * 900;
    const int t = threadIdx.x;
    unsigned short* cp = corr + ((size_t)b * 960 + p) * 960;
    float v[4];
    float s = 0.f;
    #pragma unroll
    for (int i = 0; i < 4; ++i) {
        const int q = t + 256 * i;
        float x = (q < 900) ? bf2f(cp[q]) : 0.f;
        v[i] = x;
        s += x * x;
    }
    #pragma unroll
    for (int m = 1; m < 64; m <<= 1) s += __shfl_xor(s, m);
    __shared__ float red[4];
    if ((t & 63) == 0) red[t >> 6] = s;
    __syncthreads();
    const float sc = 1.f / sqrtf(red[0] + red[1] + red[2] + red[3] + EPSF);
    #pragma unroll
    for (int i = 0; i < 4; ++i) {
        const int q = t + 256 * i;
        if (q < 900) cp[q] = f2bf(v[i] * sc);
    }
}

// ======================= cw1 MFMA: M=9216 N=128, K' = 49*928, split 7 ========
__global__ __launch_bounds__(256) void k_cw1(
        const unsigned short* __restrict__ corr, const unsigned short* __restrict__ Wt,
        float* __restrict__ part) {
    __shared__ __align__(16) unsigned short As[2][128 * 32];
    __shared__ __align__(16) unsigned short Bs[2][128 * 32];
    const int t = threadIdx.x, w = t >> 6, l = t & 63;
    const int m0 = blockIdx.x * 128, ks = blockIdx.y;       // grid (72,7)
    const int ko = (l & 3) * 8;
    size_t aga[2], bga[2];
    #pragma unroll
    for (int i = 0; i < 2; ++i) {
        int r = (w * 2 + i) * 16 + (l >> 2);
        int m = m0 + r;
        int b = m / 576, rem = m - b * 576, oy = rem / 24, ox = rem - oy * 24;
        aga[i] = (size_t)(b * 960 + oy * 30 + ox) * 960 + ko;
        bga[i] = (size_t)r * 45472 + ko;
    }
    const int sg0 = ks * 7;
    const int wr = (w >> 1) * 64, wc = (w & 1) * 64, lr = l & 15, lk = (l >> 4) * 8;
    f32x4 acc[4][4] = {};
    auto stage = [&](int buf, int s) {
        int si = s / 29, qi = s - si * 29;
        int sg = sg0 + si;
        int ky = sg / 7, kx = sg - ky * 7;
        int aoff = (ky * 30 + kx) * 960 + qi * 32;
        int boff = sg * 928 + qi * 32;
        #pragma unroll
        for (int i = 0; i < 2; ++i) {
            gl16(corr + aga[i] + aoff, &As[buf][(w * 2 + i) * 512]);
            gl16(Wt + bga[i] + boff, &Bs[buf][(w * 2 + i) * 512]);
        }
    };
    stage(0, 0);
    __syncthreads();
    int cur = 0;
    for (int s = 0; s < 203; ++s) {
        if (s + 1 < 203) stage(cur ^ 1, s + 1);
        bf16x8 af[4], bfv[4];
        #pragma unroll
        for (int i = 0; i < 4; ++i) af[i] = *(const bf16x8*)&As[cur][(wr + i * 16 + lr) * 32 + lk];
        #pragma unroll
        for (int j = 0; j < 4; ++j) bfv[j] = *(const bf16x8*)&Bs[cur][(wc + j * 16 + lr) * 32 + lk];
        #pragma unroll
        for (int i = 0; i < 4; ++i)
            #pragma unroll
            for (int j = 0; j < 4; ++j)
                acc[i][j] = __builtin_amdgcn_mfma_f32_16x16x32_bf16(af[i], bfv[j], acc[i][j], 0, 0, 0);
        __syncthreads();
        cur ^= 1;
    }
    float* pb = part + ((size_t)ks * 9216 + m0) * 128;
    #pragma unroll
    for (int i = 0; i < 4; ++i)
        #pragma unroll
        for (int r = 0; r < 4; ++r) {
            int row = wr + i * 16 + (l >> 4) * 4 + r;
            #pragma unroll
            for (int j = 0; j < 4; ++j)
                pb[(size_t)row * 128 + wc + j * 16 + lr] = acc[i][j][r];
        }
}

// ======================= reduce 7 partials + bias + relu + BN ================
__global__ __launch_bounds__(256) void k_r1fin(
        const float* __restrict__ part, const float* __restrict__ cb1,
        const float* __restrict__ g1, const float* __restrict__ be1,
        const float* __restrict__ m1, const float* __restrict__ v1,
        float* __restrict__ r1) {
    const int idx = blockIdx.x * 256 + threadIdx.x;
    const int N = 9216 * 128;
    const int co = idx & 127;
    float s = 0.f;
    #pragma unroll
    for (int i = 0; i < 7; ++i) s += part[idx + (size_t)i * N];
    s = fmaxf(s + cb1[co], 0.f);
    s = (s - m1[co]) * (g1[co] / sqrtf(v1[co] + BN_EPSF)) + be1[co];
    r1[idx] = s;
}

// ======================= cw2 fp32: 5x5 VALID 128->64, bias+relu+BN ===========
__global__ __launch_bounds__(256) void k_cw2(
        const float* __restrict__ in, const float* __restrict__ w,
        const float* __restrict__ cb2, const float* __restrict__ g2,
        const float* __restrict__ be2, const float* __restrict__ m2,
        const float* __restrict__ v2, float* __restrict__ out) {
    const int t = threadIdx.x;
    const int co = t & 63;
    const int u = t >> 6;
    const int x = blockIdx.x * 4 + u;
    const int oy = blockIdx.y;
    const int b = blockIdx.z;
    float acc = 0.f;
    #pragma unroll
    for (int ky = 0; ky < 5; ++ky) {
        const float* irow = in + (size_t)(b * 24 + oy + ky) * 24 * 128;
        #pragma unroll
        for (int kx = 0; kx < 5; ++kx) {
            const float* ip = irow + (size_t)(x + kx) * 128;
            const float* wp = w + ((ky * 5 + kx) * 128) * 64 + co;
            for (int ci = 0; ci < 128; ci += 4) {
                const float4 iv = *(const float4*)(ip + ci);
                acc = fmaf(iv.x, wp[(ci + 0) * 64],
                      fmaf(iv.y, wp[(ci + 1) * 64],
                      fmaf(iv.z, wp[(ci + 2) * 64],
                      fmaf(iv.w, wp[(ci + 3) * 64], acc))));
            }
        }
    }
    float s = fmaxf(acc + cb2[co], 0.f);
    s = (s - m2[co]) * (g2[co] / sqrtf(v2[co] + BN_EPSF)) + be2[co];
    out[((size_t)(b * 20 + oy) * 20 + x) * 64 + co] = s;
}

// ======================= dense ==============================================
__global__ __launch_bounds__(256) void k_dense(
        const float* __restrict__ r2, const float* __restrict__ dw,
        const float* __restrict__ db, float* __restrict__ out) {
    const int j = blockIdx.x, b = blockIdx.y, t = threadIdx.x;
    const float* x = r2 + (size_t)b * 25600;
    float s = 0.f;
    for (int k = t; k < 25600; k += 256) s = fmaf(x[k], dw[(size_t)k * 18 + j], s);
    #pragma unroll
    for (int m = 1; m < 64; m <<= 1) s += __shfl_xor(s, m);
    __shared__ float red[4];
    if ((t & 63) == 0) red[t >> 6] = s;
    __syncthreads();
    if (t == 0) out[b * 18 + j] = red[0] + red[1] + red[2] + red[3] + db[j];
}

extern "C" void kernel_launch(void* const* d_in, const int* in_sizes, int n_in,
                              void* d_out, int out_size, void* d_ws, size_t ws_size,
                              hipStream_t stream) {
    const float* imgA = (const float*)d_in[0];
    const float* imgB = (const float*)d_in[1];
    const float* w1  = (const float*)d_in[2];
    const float* b1  = (const float*)d_in[3];
    const float* w2  = (const float*)d_in[4];
    const float* b2  = (const float*)d_in[5];
    const float* w3  = (const float*)d_in[6];
    const float* b3  = (const float*)d_in[7];
    const float* cw1 = (const float*)d_in[8];
    const float* cb1 = (const float*)d_in[9];
    const float* g1  = (const float*)d_in[10];
    const float* be1 = (const float*)d_in[11];
    const float* m1  = (const float*)d_in[12];
    const float* v1  = (const float*)d_in[13];
    const float* cw2 = (const float*)d_in[14];
    const float* cb2 = (const float*)d_in[15];
    const float* g2  = (const float*)d_in[16];
    const float* be2 = (const float*)d_in[17];
    const float* m2  = (const float*)d_in[18];
    const float* v2  = (const float*)d_in[19];
    const float* dw  = (const float*)d_in[20];
    const float* db  = (const float*)d_in[21];

    // ws layout (bytes), total = 78,249,984 (<= 81,331,200 proven available)
    //  phase conv:  c1@0 (15.0MB) c2@15.7MB (7.6MB) w2t@22.5MB w3t@23MB  | feat@33MB
    //  phase cw1 :  part@0 (33MB)  Wt@33MB(reuses feat)  corr@48.8MB (29.5MB)
    //  phase tail:  r1@33MB (4.7MB, reuses Wt)  r2@37.7MB
    char* ws = (char*)d_ws;
    unsigned short* c1   = (unsigned short*)(ws + 0);
    unsigned short* c2   = (unsigned short*)(ws + 15728640);
    unsigned short* w2t  = (unsigned short*)(ws + 23592960);
    unsigned short* w3t  = (unsigned short*)(ws + 24117248);
    float*          part = (float*)(ws + 0);
    unsigned short* feat = (unsigned short*)(ws + 33030144);
    unsigned short* Wt   = (unsigned short*)(ws + 33030144);
    float*          r1   = (float*)(ws + 33030144);
    float*          r2   = (float*)(ws + 37748736);
    unsigned short* corr = (unsigned short*)(ws + 48758784);

    k_w2t<<<dim3(288), 256, 0, stream>>>(w2, w2t);
    k_w3t<<<dim3(1152), 256, 0, stream>>>(w3, w3t);

    for (int chunk = 0; chunk < 4; ++chunk) {
        const float* img = (chunk < 2) ? imgA : imgB;
        const int b0 = (chunk & 1) * 8;
        const int f0 = chunk * 8;
        k_conv1<<<dim3(30, 120, 8), 256, 0, stream>>>(img, b0, w1, b1, c1);
        k_zb1  <<<dim3(2, 8),       256, 0, stream>>>(c1);
        k_conv2<<<dim3(225),        256, 0, stream>>>(c1, w2t, b2, c2);
        k_zb2  <<<dim3(2, 8),       256, 0, stream>>>(c2);
        k_conv3<<<dim3(57, 4),      256, 0, stream>>>(c2, w3t, b3, feat, f0);
    }
    k_l2norm  <<<dim3(30720),      256, 0, stream>>>(feat);
    k_corr    <<<dim3(15, 15, 16), 256, 0, stream>>>(feat, corr);
    k_corrnorm<<<dim3(14400),      256, 0, stream>>>(corr);
    k_wt1     <<<dim3(178, 128),   256, 0, stream>>>(cw1, Wt);     // feat dead now
    k_cw1     <<<dim3(72, 7),      256, 0, stream>>>(corr, Wt, part);
    k_r1fin   <<<dim3(4608),       256, 0, stream>>>(part, cb1, g1, be1, m1, v1, r1);
    k_cw2     <<<dim3(5, 20, 16),  256, 0, stream>>>(r1, cw2, cb2, g2, be2, m2, v2, r2);
    k_dense   <<<dim3(18, 16),     256, 0, stream>>>(r2, dw, db, (float*)d_out);
}

// Round 3
// 757.723 us; speedup vs baseline: 8.8403x; 1.3838x over previous
//
#include <hip/hip_runtime.h>

#define EPSF    1e-6f
#define BN_EPSF 1e-3f

typedef __attribute__((ext_vector_type(8))) short bf16x8;   // 8 bf16 in 4 VGPRs
typedef __attribute__((ext_vector_type(4))) float f32x4;

__device__ __forceinline__ unsigned short f2bf(float f) {
    unsigned int u = __builtin_bit_cast(unsigned int, f);
    u = (u + 0x7FFFu + ((u >> 16) & 1u)) >> 16;            // RNE
    return (unsigned short)u;
}
__device__ __forceinline__ float bf2f(unsigned short h) {
    unsigned int u = ((unsigned int)h) << 16;
    return __builtin_bit_cast(float, u);
}
// async global->LDS, 16 bytes per lane; lds dest must be wave-uniform base (+lane*16 by HW)
__device__ __forceinline__ void gl16(const void* g, void* l) {
    __builtin_amdgcn_global_load_lds((const __attribute__((address_space(1))) void*)g,
                                     (__attribute__((address_space(3))) void*)l, 16, 0, 0);
}

// ======================= weight conversion kernels ===========================
// w2t[n][k], k=(ky*3+kx)*64+ci, n=128, K=576
__global__ __launch_bounds__(256) void k_w2t(const float* __restrict__ w2,
                                             unsigned short* __restrict__ w2t) {
    int idx = blockIdx.x * 256 + threadIdx.x;              // 73728
    int n = idx / 576, k = idx - n * 576;
    w2t[idx] = f2bf(w2[(size_t)k * 128 + n]);
}
// w3t[n][k], k=(ky*3+kx)*128+ci, n=256, K=1152
__global__ __launch_bounds__(256) void k_w3t(const float* __restrict__ w3,
                                             unsigned short* __restrict__ w3t) {
    int idx = blockIdx.x * 256 + threadIdx.x;              // 294912
    int n = idx / 1152, k = idx - n * 1152;
    w3t[idx] = f2bf(w3[(size_t)k * 256 + n]);
}
// Wt[n][k'], k'=s*928+q (s=ky*7+kx<49, q<928), zero for q>=900. n=128.
__global__ __launch_bounds__(256) void k_wt1(const float* __restrict__ W,
                                             unsigned short* __restrict__ Wt) {
    int kp = blockIdx.x * 256 + threadIdx.x;               // grid.x=178
    int n = blockIdx.y;                                    // 128
    if (kp >= 45472) return;
    int s = kp / 928, q = kp - s * 928;
    unsigned short v = 0;
    if (q < 900) v = f2bf(W[(size_t)(s * 900 + q) * 128 + n]);
    Wt[(size_t)n * 45472 + kp] = v;
}
// Wt2[n][k], k=(ky*5+kx)*128+ci, n=64, K=3200
__global__ __launch_bounds__(256) void k_wt2(const float* __restrict__ W,
                                             unsigned short* __restrict__ Wt2) {
    int idx = blockIdx.x * 256 + threadIdx.x;              // 204800, grid 800
    int n = idx / 3200, k = idx - n * 3200;
    Wt2[idx] = f2bf(W[(size_t)k * 64 + n]);
}

// ======================= conv1 (fp32 in -> bf16 padded out, border fused) ====
// c1: [8][121][121][64] bf16
__global__ __launch_bounds__(256) void k_conv1(
        const float* __restrict__ img, int b0,
        const float* __restrict__ w, const float* __restrict__ bias,
        unsigned short* __restrict__ c1) {
    const int co = threadIdx.x & 63, u = threadIdx.x >> 6;
    const int ox = blockIdx.x * 4 + u;                     // 120
    const int oy = blockIdx.y;                             // 120
    const int bl = blockIdx.z;                             // 8
    const int b = b0 + bl;
    float acc = bias[co];
    #pragma unroll
    for (int ky = 0; ky < 3; ++ky) {
        const int iy = 2 * oy + ky;
        if (iy >= 240) continue;
        #pragma unroll
        for (int kx = 0; kx < 3; ++kx) {
            const int ix = 2 * ox + kx;
            if (ix >= 240) continue;
            const float* ip = img + ((size_t)(b * 240 + iy) * 240 + ix) * 3;
            const float* wp = w + ((ky * 3 + kx) * 3) * 64 + co;
            acc = fmaf(ip[0], wp[0], acc);
            acc = fmaf(ip[1], wp[64], acc);
            acc = fmaf(ip[2], wp[128], acc);
        }
    }
    c1[((size_t)(bl * 121 + oy) * 121 + ox) * 64 + co] = f2bf(fmaxf(acc, 0.f));
    // fused zero-padding of row/col 120
    const bool bx = (ox == 119), by = (oy == 119);
    if (bx) c1[((size_t)(bl * 121 + oy) * 121 + 120) * 64 + co] = 0;
    if (by) c1[((size_t)(bl * 121 + 120) * 121 + ox) * 64 + co] = 0;
    if (bx && by) c1[((size_t)(bl * 121 + 120) * 121 + 120) * 64 + co] = 0;
}

// ======================= conv2 MFMA: M=28800 N=128 K=576 (border fused) ======
__global__ __launch_bounds__(256) void k_conv2(
        const unsigned short* __restrict__ c1, const unsigned short* __restrict__ w2t,
        const float* __restrict__ b2, unsigned short* __restrict__ c2) {
    __shared__ __align__(16) unsigned short As[2][128 * 32];
    __shared__ __align__(16) unsigned short Bs[2][128 * 32];
    const int t = threadIdx.x, w = t >> 6, l = t & 63;
    const int m0 = blockIdx.x * 128;
    const int ko = (l & 3) * 8;
    size_t aga[2], bga[2];
    #pragma unroll
    for (int i = 0; i < 2; ++i) {
        int r = (w * 2 + i) * 16 + (l >> 2);
        int m = m0 + r;
        int bl = m / 3600, rem = m - bl * 3600, oy = rem / 60, ox = rem - oy * 60;
        aga[i] = (size_t)((bl * 121 + 2 * oy) * 121 + 2 * ox) * 64 + ko;
        bga[i] = (size_t)r * 576 + ko;
    }
    const int wr = (w >> 1) * 64, wc = (w & 1) * 64, lr = l & 15, lk = (l >> 4) * 8;
    f32x4 acc[4][4] = {};
    auto stage = [&](int buf, int s) {
        int ky = s / 6, r6 = s - ky * 6, kx = r6 >> 1, h = r6 & 1;
        int aoff = (ky * 121 + kx) * 64 + h * 32;
        int boff = (ky * 3 + kx) * 64 + h * 32;
        #pragma unroll
        for (int i = 0; i < 2; ++i) {
            gl16(c1 + aga[i] + aoff, &As[buf][(w * 2 + i) * 512]);
            gl16(w2t + bga[i] + boff, &Bs[buf][(w * 2 + i) * 512]);
        }
    };
    stage(0, 0);
    __syncthreads();
    int cur = 0;
    for (int s = 0; s < 18; ++s) {
        if (s + 1 < 18) stage(cur ^ 1, s + 1);
        bf16x8 af[4], bfv[4];
        #pragma unroll
        for (int i = 0; i < 4; ++i) af[i] = *(const bf16x8*)&As[cur][(wr + i * 16 + lr) * 32 + lk];
        #pragma unroll
        for (int j = 0; j < 4; ++j) bfv[j] = *(const bf16x8*)&Bs[cur][(wc + j * 16 + lr) * 32 + lk];
        #pragma unroll
        for (int i = 0; i < 4; ++i)
            #pragma unroll
            for (int j = 0; j < 4; ++j)
                acc[i][j] = __builtin_amdgcn_mfma_f32_16x16x32_bf16(af[i], bfv[j], acc[i][j], 0, 0, 0);
        __syncthreads();
        cur ^= 1;
    }
    float bias[4];
    #pragma unroll
    for (int j = 0; j < 4; ++j) bias[j] = b2[wc + j * 16 + lr];
    #pragma unroll
    for (int i = 0; i < 4; ++i)
        #pragma unroll
        for (int r = 0; r < 4; ++r) {
            int m = m0 + wr + i * 16 + (l >> 4) * 4 + r;
            int bl = m / 3600, rem = m - bl * 3600, oy = rem / 60, ox = rem - oy * 60;
            size_t ob = (size_t)((bl * 61 + oy) * 61 + ox) * 128;
            #pragma unroll
            for (int j = 0; j < 4; ++j)
                c2[ob + wc + j * 16 + lr] = f2bf(fmaxf(acc[i][j][r] + bias[j], 0.f));
            // fused zero-padding of row/col 60
            const bool bx = (ox == 59), by = (oy == 59);
            if (bx) {
                size_t zb = (size_t)((bl * 61 + oy) * 61 + 60) * 128;
                #pragma unroll
                for (int j = 0; j < 4; ++j) c2[zb + wc + j * 16 + lr] = 0;
            }
            if (by) {
                size_t zb = (size_t)((bl * 61 + 60) * 61 + ox) * 128;
                #pragma unroll
                for (int j = 0; j < 4; ++j) c2[zb + wc + j * 16 + lr] = 0;
            }
            if (bx && by) {
                size_t zb = (size_t)((bl * 61 + 60) * 61 + 60) * 128;
                #pragma unroll
                for (int j = 0; j < 4; ++j) c2[zb + wc + j * 16 + lr] = 0;
            }
        }
}

// ======================= conv3 MFMA: M=7200 N=256 K=1152 =====================
__global__ __launch_bounds__(256) void k_conv3(
        const unsigned short* __restrict__ c2, const unsigned short* __restrict__ w3t,
        const float* __restrict__ b3, unsigned short* __restrict__ feat, int f0) {
    __shared__ __align__(16) unsigned short As[2][128 * 32];
    __shared__ __align__(16) unsigned short Bs[2][64 * 32];
    const int t = threadIdx.x, w = t >> 6, l = t & 63;
    const int m0 = blockIdx.x * 128, n0 = blockIdx.y * 64;   // grid (57,4)
    const int ko = (l & 3) * 8;
    size_t aga[2], bga;
    #pragma unroll
    for (int i = 0; i < 2; ++i) {
        int r = (w * 2 + i) * 16 + (l >> 2);
        int m = min(m0 + r, 7199);
        int bl = m / 900, rem = m - bl * 900, oy = rem / 30, ox = rem - oy * 30;
        aga[i] = (size_t)((bl * 61 + 2 * oy) * 61 + 2 * ox) * 128 + ko;
    }
    { int n = n0 + w * 16 + (l >> 2); bga = (size_t)n * 1152 + ko; }
    const int wr = (w >> 1) * 64, wc = (w & 1) * 32, lr = l & 15, lk = (l >> 4) * 8;
    f32x4 acc[4][2] = {};
    auto stage = [&](int buf, int s) {
        int ky = s / 12, r12 = s - ky * 12, kx = r12 >> 2, h = r12 & 3;
        int aoff = (ky * 61 + kx) * 128 + h * 32;
        int boff = (ky * 3 + kx) * 128 + h * 32;
        #pragma unroll
        for (int i = 0; i < 2; ++i)
            gl16(c2 + aga[i] + aoff, &As[buf][(w * 2 + i) * 512]);
        gl16(w3t + bga + boff, &Bs[buf][w * 512]);
    };
    stage(0, 0);
    __syncthreads();
    int cur = 0;
    for (int s = 0; s < 36; ++s) {
        if (s + 1 < 36) stage(cur ^ 1, s + 1);
        bf16x8 af[4], bfv[2];
        #pragma unroll
        for (int i = 0; i < 4; ++i) af[i] = *(const bf16x8*)&As[cur][(wr + i * 16 + lr) * 32 + lk];
        #pragma unroll
        for (int j = 0; j < 2; ++j) bfv[j] = *(const bf16x8*)&Bs[cur][(wc + j * 16 + lr) * 32 + lk];
        #pragma unroll
        for (int i = 0; i < 4; ++i)
            #pragma unroll
            for (int j = 0; j < 2; ++j)
                acc[i][j] = __builtin_amdgcn_mfma_f32_16x16x32_bf16(af[i], bfv[j], acc[i][j], 0, 0, 0);
        __syncthreads();
        cur ^= 1;
    }
    float bias[2];
    #pragma unroll
    for (int j = 0; j < 2; ++j) bias[j] = b3[n0 + wc + j * 16 + lr];
    #pragma unroll
    for (int i = 0; i < 4; ++i)
        #pragma unroll
        for (int r = 0; r < 4; ++r) {
            int m = m0 + wr + i * 16 + (l >> 4) * 4 + r;
            if (m < 7200) {
                int bl = m / 900, pos = m - bl * 900;
                size_t ob = ((size_t)(f0 + bl) * 960 + pos) * 256;
                #pragma unroll
                for (int j = 0; j < 2; ++j)
                    feat[ob + n0 + wc + j * 16 + lr] = f2bf(fmaxf(acc[i][j][r] + bias[j], 0.f));
            }
        }
}

// ======================= l2norm (bf16, zero pad rows) ========================
__global__ __launch_bounds__(256) void k_l2norm(unsigned short* __restrict__ feat) {
    const int R = blockIdx.x;                  // 32*960
    const int pos = R % 960;
    const int t = threadIdx.x;
    unsigned short* fp = feat + (size_t)R * 256;
    if (pos >= 900) { fp[t] = 0; return; }
    const float v = bf2f(fp[t]);
    float s = v * v;
    #pragma unroll
    for (int m = 1; m < 64; m <<= 1) s += __shfl_xor(s, m);
    __shared__ float red[4];
    if ((t & 63) == 0) red[t >> 6] = s;
    __syncthreads();
    const float tot = red[0] + red[1] + red[2] + red[3];
    fp[t] = f2bf(v / sqrtf(tot + EPSF));
}

// ======================= corr MFMA: per-b 960x960, relu, bf16 ================
__global__ __launch_bounds__(256) void k_corr(
        const unsigned short* __restrict__ feat, unsigned short* __restrict__ corr) {
    __shared__ __align__(16) unsigned short As[2][64 * 32];
    __shared__ __align__(16) unsigned short Bs[2][64 * 32];
    const int t = threadIdx.x, w = t >> 6, l = t & 63;
    const int b = blockIdx.z, p0 = blockIdx.y * 64, q0 = blockIdx.x * 64;
    const int ko = (l & 3) * 8;
    const unsigned short* base = feat + (size_t)((w < 2) ? b : 16 + b) * 960 * 256;
    const int r0 = (w < 2) ? p0 : q0;
    const int wi = w & 1;
    size_t ga[2];
    #pragma unroll
    for (int i = 0; i < 2; ++i) {
        int row = (wi * 2 + i) * 16 + (l >> 2);
        ga[i] = (size_t)(r0 + row) * 256 + ko;
    }
    const int wr = (w >> 1) * 32, wc = (w & 1) * 32, lr = l & 15, lk = (l >> 4) * 8;
    f32x4 acc[2][2] = {};
    auto stage = [&](int buf, int k0) {
        #pragma unroll
        for (int i = 0; i < 2; ++i) {
            unsigned short* dst = (w < 2) ? &As[buf][(wi * 2 + i) * 512]
                                          : &Bs[buf][(wi * 2 + i) * 512];
            gl16(base + ga[i] + k0, dst);
        }
    };
    stage(0, 0);
    __syncthreads();
    int cur = 0;
    for (int s = 0; s < 8; ++s) {
        if (s + 1 < 8) stage(cur ^ 1, (s + 1) * 32);
        bf16x8 af[2], bfv[2];
        #pragma unroll
        for (int i = 0; i < 2; ++i) af[i] = *(const bf16x8*)&As[cur][(wr + i * 16 + lr) * 32 + lk];
        #pragma unroll
        for (int j = 0; j < 2; ++j) bfv[j] = *(const bf16x8*)&Bs[cur][(wc + j * 16 + lr) * 32 + lk];
        #pragma unroll
        for (int i = 0; i < 2; ++i)
            #pragma unroll
            for (int j = 0; j < 2; ++j)
                acc[i][j] = __builtin_amdgcn_mfma_f32_16x16x32_bf16(af[i], bfv[j], acc[i][j], 0, 0, 0);
        __syncthreads();
        cur ^= 1;
    }
    unsigned short* cb = corr + (size_t)b * 960 * 960;
    #pragma unroll
    for (int i = 0; i < 2; ++i)
        #pragma unroll
        for (int r = 0; r < 4; ++r) {
            int row = p0 + wr + i * 16 + (l >> 4) * 4 + r;
            #pragma unroll
            for (int j = 0; j < 2; ++j)
                cb[(size_t)row * 960 + q0 + wc + j * 16 + lr] = f2bf(fmaxf(acc[i][j][r], 0.f));
        }
}

// ======================= corr L2 norm over 900 channels ======================
__global__ __launch_bounds__(256) void k_corrnorm(unsigned short* __restrict__ corr) {
    const int rb = blockIdx.x;                 // 16*900
    const int b = rb / 900, p = rb - b * 900;
    const int t = threadIdx.x;
    unsigned short* cp = corr + ((size_t)b * 960 + p) * 960;
    float v[4];
    float s = 0.f;
    #pragma unroll
    for (int i = 0; i < 4; ++i) {
        const int q = t + 256 * i;
        float x = (q < 900) ? bf2f(cp[q]) : 0.f;
        v[i] = x;
        s += x * x;
    }
    #pragma unroll
    for (int m = 1; m < 64; m <<= 1) s += __shfl_xor(s, m);
    __shared__ float red[4];
    if ((t & 63) == 0) red[t >> 6] = s;
    __syncthreads();
    const float sc = 1.f / sqrtf(red[0] + red[1] + red[2] + red[3] + EPSF);
    #pragma unroll
    for (int i = 0; i < 4; ++i) {
        const int q = t + 256 * i;
        if (q < 900) cp[q] = f2bf(v[i] * sc);
    }
}

// ======================= cw1 MFMA: M=9216 N=128, K' = 49*928, split 7 ========
__global__ __launch_bounds__(256) void k_cw1(
        const unsigned short* __restrict__ corr, const unsigned short* __restrict__ Wt,
        float* __restrict__ part) {
    __shared__ __align__(16) unsigned short As[2][128 * 32];
    __shared__ __align__(16) unsigned short Bs[2][128 * 32];
    const int t = threadIdx.x, w = t >> 6, l = t & 63;
    const int m0 = blockIdx.x * 128, ks = blockIdx.y;       // grid (72,7)
    const int ko = (l & 3) * 8;
    size_t aga[2], bga[2];
    #pragma unroll
    for (int i = 0; i < 2; ++i) {
        int r = (w * 2 + i) * 16 + (l >> 2);
        int m = m0 + r;
        int b = m / 576, rem = m - b * 576, oy = rem / 24, ox = rem - oy * 24;
        aga[i] = (size_t)(b * 960 + oy * 30 + ox) * 960 + ko;
        bga[i] = (size_t)r * 45472 + ko;
    }
    const int sg0 = ks * 7;
    const int wr = (w >> 1) * 64, wc = (w & 1) * 64, lr = l & 15, lk = (l >> 4) * 8;
    f32x4 acc[4][4] = {};
    auto stage = [&](int buf, int s) {
        int si = s / 29, qi = s - si * 29;
        int sg = sg0 + si;
        int ky = sg / 7, kx = sg - ky * 7;
        int aoff = (ky * 30 + kx) * 960 + qi * 32;
        int boff = sg * 928 + qi * 32;
        #pragma unroll
        for (int i = 0; i < 2; ++i) {
            gl16(corr + aga[i] + aoff, &As[buf][(w * 2 + i) * 512]);
            gl16(Wt + bga[i] + boff, &Bs[buf][(w * 2 + i) * 512]);
        }
    };
    stage(0, 0);
    __syncthreads();
    int cur = 0;
    for (int s = 0; s < 203; ++s) {
        if (s + 1 < 203) stage(cur ^ 1, s + 1);
        bf16x8 af[4], bfv[4];
        #pragma unroll
        for (int i = 0; i < 4; ++i) af[i] = *(const bf16x8*)&As[cur][(wr + i * 16 + lr) * 32 + lk];
        #pragma unroll
        for (int j = 0; j < 4; ++j) bfv[j] = *(const bf16x8*)&Bs[cur][(wc + j * 16 + lr) * 32 + lk];
        #pragma unroll
        for (int i = 0; i < 4; ++i)
            #pragma unroll
            for (int j = 0; j < 4; ++j)
                acc[i][j] = __builtin_amdgcn_mfma_f32_16x16x32_bf16(af[i], bfv[j], acc[i][j], 0, 0, 0);
        __syncthreads();
        cur ^= 1;
    }
    float* pb = part + ((size_t)ks * 9216 + m0) * 128;
    #pragma unroll
    for (int i = 0; i < 4; ++i)
        #pragma unroll
        for (int r = 0; r < 4; ++r) {
            int row = wr + i * 16 + (l >> 4) * 4 + r;
            #pragma unroll
            for (int j = 0; j < 4; ++j)
                pb[(size_t)row * 128 + wc + j * 16 + lr] = acc[i][j][r];
        }
}

// ======================= reduce 7 partials + bias + relu + BN -> bf16 ========
__global__ __launch_bounds__(256) void k_r1fin(
        const float* __restrict__ part, const float* __restrict__ cb1,
        const float* __restrict__ g1, const float* __restrict__ be1,
        const float* __restrict__ m1, const float* __restrict__ v1,
        unsigned short* __restrict__ r1) {
    const int idx = blockIdx.x * 256 + threadIdx.x;
    const int N = 9216 * 128;
    const int co = idx & 127;
    float s = 0.f;
    #pragma unroll
    for (int i = 0; i < 7; ++i) s += part[idx + (size_t)i * N];
    s = fmaxf(s + cb1[co], 0.f);
    s = (s - m1[co]) * (g1[co] / sqrtf(v1[co] + BN_EPSF)) + be1[co];
    r1[idx] = f2bf(s);
}

// ======================= cw2 MFMA: M=6400 N=64 K=3200, bias+relu+BN ==========
__global__ __launch_bounds__(256) void k_cw2(
        const unsigned short* __restrict__ r1, const unsigned short* __restrict__ Wt2,
        const float* __restrict__ cb2, const float* __restrict__ g2,
        const float* __restrict__ be2, const float* __restrict__ m2,
        const float* __restrict__ v2, float* __restrict__ r2) {
    __shared__ __align__(16) unsigned short As[2][64 * 32];
    __shared__ __align__(16) unsigned short Bs[2][64 * 32];
    const int t = threadIdx.x, w = t >> 6, l = t & 63;
    const int m0 = blockIdx.x * 64;                        // grid 100
    const int ko = (l & 3) * 8;
    const int wi = w & 1;
    size_t ga[2];
    #pragma unroll
    for (int i = 0; i < 2; ++i) {
        int r = (wi * 2 + i) * 16 + (l >> 2);
        if (w < 2) {
            int m = m0 + r;
            int b = m / 400, rem = m - b * 400, oy = rem / 20, ox = rem - oy * 20;
            ga[i] = (size_t)((b * 24 + oy) * 24 + ox) * 128 + ko;
        } else {
            ga[i] = (size_t)r * 3200 + ko;
        }
    }
    const int wr = (w >> 1) * 32, wc = (w & 1) * 32, lr = l & 15, lk = (l >> 4) * 8;
    f32x4 acc[2][2] = {};
    auto stage = [&](int buf, int s) {
        int kyx = s >> 2, h = s & 3;
        int ky = kyx / 5, kx = kyx - ky * 5;
        int aoff = (ky * 24 + kx) * 128 + h * 32;
        int boff = s * 32;
        #pragma unroll
        for (int i = 0; i < 2; ++i) {
            unsigned short* dst = (w < 2) ? &As[buf][(wi * 2 + i) * 512]
                                          : &Bs[buf][(wi * 2 + i) * 512];
            const unsigned short* src = (w < 2) ? r1 + ga[i] + aoff : Wt2 + ga[i] + boff;
            gl16(src, dst);
        }
    };
    stage(0, 0);
    __syncthreads();
    int cur = 0;
    for (int s = 0; s < 100; ++s) {
        if (s + 1 < 100) stage(cur ^ 1, s + 1);
        bf16x8 af[2], bfv[2];
        #pragma unroll
        for (int i = 0; i < 2; ++i) af[i] = *(const bf16x8*)&As[cur][(wr + i * 16 + lr) * 32 + lk];
        #pragma unroll
        for (int j = 0; j < 2; ++j) bfv[j] = *(const bf16x8*)&Bs[cur][(wc + j * 16 + lr) * 32 + lk];
        #pragma unroll
        for (int i = 0; i < 2; ++i)
            #pragma unroll
            for (int j = 0; j < 2; ++j)
                acc[i][j] = __builtin_amdgcn_mfma_f32_16x16x32_bf16(af[i], bfv[j], acc[i][j], 0, 0, 0);
        __syncthreads();
        cur ^= 1;
    }
    float sc[2], sh[2];
    #pragma unroll
    for (int j = 0; j < 2; ++j) {
        int co = wc + j * 16 + lr;
        sc[j] = g2[co] / sqrtf(v2[co] + BN_EPSF);
        sh[j] = be2[co] - m2[co] * sc[j];
    }
    float bias[2];
    #pragma unroll
    for (int j = 0; j < 2; ++j) bias[j] = cb2[wc + j * 16 + lr];
    #pragma unroll
    for (int i = 0; i < 2; ++i)
        #pragma unroll
        for (int r = 0; r < 4; ++r) {
            int m = m0 + wr + i * 16 + (l >> 4) * 4 + r;
            #pragma unroll
            for (int j = 0; j < 2; ++j) {
                float s = fmaxf(acc[i][j][r] + bias[j], 0.f);
                r2[(size_t)m * 64 + wc + j * 16 + lr] = s * sc[j] + sh[j];
            }
        }
}

// ======================= dense: block per batch, contiguous dw rows ==========
__global__ __launch_bounds__(256) void k_dense(
        const float* __restrict__ r2, const float* __restrict__ dw,
        const float* __restrict__ db, float* __restrict__ out) {
    const int b = blockIdx.x, t = threadIdx.x;
    const float* x = r2 + (size_t)b * 25600;
    float s[18] = {};
    for (int k = t; k < 25600; k += 256) {
        const float xv = x[k];
        const float* dr = dw + (size_t)k * 18;
        #pragma unroll
        for (int j = 0; j < 18; ++j) s[j] = fmaf(xv, dr[j], s[j]);
    }
    #pragma unroll
    for (int j = 0; j < 18; ++j)
        #pragma unroll
        for (int m = 1; m < 64; m <<= 1) s[j] += __shfl_xor(s[j], m);
    __shared__ float red[4][18];
    if ((t & 63) == 0) {
        #pragma unroll
        for (int j = 0; j < 18; ++j) red[t >> 6][j] = s[j];
    }
    __syncthreads();
    if (t < 18) out[b * 18 + t] = red[0][t] + red[1][t] + red[2][t] + red[3][t] + db[t];
}

extern "C" void kernel_launch(void* const* d_in, const int* in_sizes, int n_in,
                              void* d_out, int out_size, void* d_ws, size_t ws_size,
                              hipStream_t stream) {
    const float* imgA = (const float*)d_in[0];
    const float* imgB = (const float*)d_in[1];
    const float* w1  = (const float*)d_in[2];
    const float* b1  = (const float*)d_in[3];
    const float* w2  = (const float*)d_in[4];
    const float* b2  = (const float*)d_in[5];
    const float* w3  = (const float*)d_in[6];
    const float* b3  = (const float*)d_in[7];
    const float* cw1 = (const float*)d_in[8];
    const float* cb1 = (const float*)d_in[9];
    const float* g1  = (const float*)d_in[10];
    const float* be1 = (const float*)d_in[11];
    const float* m1  = (const float*)d_in[12];
    const float* v1  = (const float*)d_in[13];
    const float* cw2 = (const float*)d_in[14];
    const float* cb2 = (const float*)d_in[15];
    const float* g2  = (const float*)d_in[16];
    const float* be2 = (const float*)d_in[17];
    const float* m2  = (const float*)d_in[18];
    const float* v2  = (const float*)d_in[19];
    const float* dw  = (const float*)d_in[20];
    const float* db  = (const float*)d_in[21];

    // ws layout (bytes), total = 78,249,984
    //  conv phase: c1@0 c2@15.7MB w2t@23.6MB w3t@24.1MB | feat@33.0MB corr@48.8MB
    //  cw1 phase : part@0 (33.0MB)  Wt@33.0MB (reuses feat)
    //  tail      : r1@33.0MB (2.4MB, after Wt dead)  Wt2@35.4MB  r2@37.7MB
    char* ws = (char*)d_ws;
    unsigned short* c1   = (unsigned short*)(ws + 0);
    unsigned short* c2   = (unsigned short*)(ws + 15728640);
    unsigned short* w2t  = (unsigned short*)(ws + 23592960);
    unsigned short* w3t  = (unsigned short*)(ws + 24117248);
    float*          part = (float*)(ws + 0);
    unsigned short* feat = (unsigned short*)(ws + 33030144);
    unsigned short* Wt   = (unsigned short*)(ws + 33030144);
    unsigned short* r1   = (unsigned short*)(ws + 33030144);
    unsigned short* Wt2  = (unsigned short*)(ws + 35389440);
    float*          r2   = (float*)(ws + 37748736);
    unsigned short* corr = (unsigned short*)(ws + 48758784);

    k_w2t<<<dim3(288), 256, 0, stream>>>(w2, w2t);
    k_w3t<<<dim3(1152), 256, 0, stream>>>(w3, w3t);

    for (int chunk = 0; chunk < 4; ++chunk) {
        const float* img = (chunk < 2) ? imgA : imgB;
        const int b0 = (chunk & 1) * 8;
        const int f0 = chunk * 8;
        k_conv1<<<dim3(30, 120, 8), 256, 0, stream>>>(img, b0, w1, b1, c1);
        k_conv2<<<dim3(225),        256, 0, stream>>>(c1, w2t, b2, c2);
        k_conv3<<<dim3(57, 4),      256, 0, stream>>>(c2, w3t, b3, feat, f0);
    }
    k_l2norm  <<<dim3(30720),      256, 0, stream>>>(feat);
    k_corr    <<<dim3(15, 15, 16), 256, 0, stream>>>(feat, corr);
    k_corrnorm<<<dim3(14400),      256, 0, stream>>>(corr);
    k_wt1     <<<dim3(178, 128),   256, 0, stream>>>(cw1, Wt);     // feat dead now
    k_cw1     <<<dim3(72, 7),      256, 0, stream>>>(corr, Wt, part);
    k_r1fin   <<<dim3(4608),       256, 0, stream>>>(part, cb1, g1, be1, m1, v1, r1);
    k_wt2     <<<dim3(800),        256, 0, stream>>>(cw2, Wt2);
    k_cw2     <<<dim3(100),        256, 0, stream>>>(r1, Wt2, cb2, g2, be2, m2, v2, r2);
    k_dense   <<<dim3(16),         256, 0, stream>>>(r2, dw, db, (float*)d_out);
}

// Round 4
// 631.144 us; speedup vs baseline: 10.6133x; 1.2006x over previous
//
#include <hip/hip_runtime.h>

#define EPSF    1e-6f
#define BN_EPSF 1e-3f

typedef __attribute__((ext_vector_type(8))) short bf16x8;   // 8 bf16 in 4 VGPRs
typedef __attribute__((ext_vector_type(4))) float f32x4;

__device__ __forceinline__ unsigned short f2bf(float f) {
    unsigned int u = __builtin_bit_cast(unsigned int, f);
    u = (u + 0x7FFFu + ((u >> 16) & 1u)) >> 16;            // RNE
    return (unsigned short)u;
}
__device__ __forceinline__ float bf2f(unsigned short h) {
    unsigned int u = ((unsigned int)h) << 16;
    return __builtin_bit_cast(float, u);
}
__device__ __forceinline__ unsigned short f2h(float f) {
    return __builtin_bit_cast(unsigned short, (_Float16)f);
}
__device__ __forceinline__ float h2f(unsigned short h) {
    return (float)__builtin_bit_cast(_Float16, h);
}
// async global->LDS, 16 bytes per lane; lds dest is wave-uniform base + lane*16
__device__ __forceinline__ void gl16(const void* g, void* l) {
    __builtin_amdgcn_global_load_lds((const __attribute__((address_space(1))) void*)g,
                                     (__attribute__((address_space(3))) void*)l, 16, 0, 0);
}

// ======================= weight conversion kernels ===========================
__global__ __launch_bounds__(256) void k_w2t(const float* __restrict__ w2,
                                             unsigned short* __restrict__ w2t) {
    int idx = blockIdx.x * 256 + threadIdx.x;              // 73728
    int n = idx / 576, k = idx - n * 576;
    w2t[idx] = f2bf(w2[(size_t)k * 128 + n]);
}
__global__ __launch_bounds__(256) void k_w3t(const float* __restrict__ w3,
                                             unsigned short* __restrict__ w3t) {
    int idx = blockIdx.x * 256 + threadIdx.x;              // 294912
    int n = idx / 1152, k = idx - n * 1152;
    w3t[idx] = f2bf(w3[(size_t)k * 256 + n]);
}
// Wt[n][k'], k'=s*928+q (s=ky*7+kx<49, q<928), zero for q>=900. n=128.
__global__ __launch_bounds__(256) void k_wt1(const float* __restrict__ W,
                                             unsigned short* __restrict__ Wt) {
    int kp = blockIdx.x * 256 + threadIdx.x;               // grid.x=178
    int n = blockIdx.y;                                    // 128
    if (kp >= 45472) return;
    int s = kp / 928, q = kp - s * 928;
    unsigned short v = 0;
    if (q < 900) v = f2bf(W[(size_t)(s * 900 + q) * 128 + n]);
    Wt[(size_t)n * 45472 + kp] = v;
}
// Wt2[n][k], k=(ky*5+kx)*128+ci, n=64, K=3200
__global__ __launch_bounds__(256) void k_wt2(const float* __restrict__ W,
                                             unsigned short* __restrict__ Wt2) {
    int idx = blockIdx.x * 256 + threadIdx.x;              // 204800, grid 800
    int n = idx / 3200, k = idx - n * 3200;
    Wt2[idx] = f2bf(W[(size_t)k * 64 + n]);
}

// ======================= conv1 (fp32 in -> bf16 padded out, border fused) ====
// c1: [16][121][121][64] bf16
__global__ __launch_bounds__(256) void k_conv1(
        const float* __restrict__ img,
        const float* __restrict__ w, const float* __restrict__ bias,
        unsigned short* __restrict__ c1) {
    const int co = threadIdx.x & 63, u = threadIdx.x >> 6;
    const int ox = blockIdx.x * 4 + u;                     // 120
    const int oy = blockIdx.y;                             // 120
    const int b = blockIdx.z;                              // 16
    float acc = bias[co];
    #pragma unroll
    for (int ky = 0; ky < 3; ++ky) {
        const int iy = 2 * oy + ky;
        if (iy >= 240) continue;
        #pragma unroll
        for (int kx = 0; kx < 3; ++kx) {
            const int ix = 2 * ox + kx;
            if (ix >= 240) continue;
            const float* ip = img + ((size_t)(b * 240 + iy) * 240 + ix) * 3;
            const float* wp = w + ((ky * 3 + kx) * 3) * 64 + co;
            acc = fmaf(ip[0], wp[0], acc);
            acc = fmaf(ip[1], wp[64], acc);
            acc = fmaf(ip[2], wp[128], acc);
        }
    }
    c1[((size_t)(b * 121 + oy) * 121 + ox) * 64 + co] = f2bf(fmaxf(acc, 0.f));
    const bool bx = (ox == 119), by = (oy == 119);
    if (bx) c1[((size_t)(b * 121 + oy) * 121 + 120) * 64 + co] = 0;
    if (by) c1[((size_t)(b * 121 + 120) * 121 + ox) * 64 + co] = 0;
    if (bx && by) c1[((size_t)(b * 121 + 120) * 121 + 120) * 64 + co] = 0;
}

// ======================= conv2 MFMA: M=57600 N=128 K=576 (border fused) ======
__global__ __launch_bounds__(256) void k_conv2(
        const unsigned short* __restrict__ c1, const unsigned short* __restrict__ w2t,
        const float* __restrict__ b2, unsigned short* __restrict__ c2) {
    __shared__ __align__(16) unsigned short As[2][128 * 32];
    __shared__ __align__(16) unsigned short Bs[2][128 * 32];
    const int t = threadIdx.x, w = t >> 6, l = t & 63;
    const int m0 = blockIdx.x * 128;                       // grid 450
    const int ko = (l & 3) * 8;
    size_t aga[2], bga[2];
    #pragma unroll
    for (int i = 0; i < 2; ++i) {
        int r = (w * 2 + i) * 16 + (l >> 2);
        int m = m0 + r;
        int bl = m / 3600, rem = m - bl * 3600, oy = rem / 60, ox = rem - oy * 60;
        aga[i] = (size_t)((bl * 121 + 2 * oy) * 121 + 2 * ox) * 64 + ko;
        bga[i] = (size_t)r * 576 + ko;
    }
    const int wr = (w >> 1) * 64, wc = (w & 1) * 64, lr = l & 15, lk = (l >> 4) * 8;
    f32x4 acc[4][4] = {};
    auto stage = [&](int buf, int s) {
        int ky = s / 6, r6 = s - ky * 6, kx = r6 >> 1, h = r6 & 1;
        int aoff = (ky * 121 + kx) * 64 + h * 32;
        int boff = (ky * 3 + kx) * 64 + h * 32;
        #pragma unroll
        for (int i = 0; i < 2; ++i) {
            gl16(c1 + aga[i] + aoff, &As[buf][(w * 2 + i) * 512]);
            gl16(w2t + bga[i] + boff, &Bs[buf][(w * 2 + i) * 512]);
        }
    };
    stage(0, 0);
    __syncthreads();
    int cur = 0;
    for (int s = 0; s < 18; ++s) {
        if (s + 1 < 18) stage(cur ^ 1, s + 1);
        bf16x8 af[4], bfv[4];
        #pragma unroll
        for (int i = 0; i < 4; ++i) af[i] = *(const bf16x8*)&As[cur][(wr + i * 16 + lr) * 32 + lk];
        #pragma unroll
        for (int j = 0; j < 4; ++j) bfv[j] = *(const bf16x8*)&Bs[cur][(wc + j * 16 + lr) * 32 + lk];
        #pragma unroll
        for (int i = 0; i < 4; ++i)
            #pragma unroll
            for (int j = 0; j < 4; ++j)
                acc[i][j] = __builtin_amdgcn_mfma_f32_16x16x32_bf16(af[i], bfv[j], acc[i][j], 0, 0, 0);
        __syncthreads();
        cur ^= 1;
    }
    float bias[4];
    #pragma unroll
    for (int j = 0; j < 4; ++j) bias[j] = b2[wc + j * 16 + lr];
    #pragma unroll
    for (int i = 0; i < 4; ++i)
        #pragma unroll
        for (int r = 0; r < 4; ++r) {
            int m = m0 + wr + i * 16 + (l >> 4) * 4 + r;
            int bl = m / 3600, rem = m - bl * 3600, oy = rem / 60, ox = rem - oy * 60;
            size_t ob = (size_t)((bl * 61 + oy) * 61 + ox) * 128;
            #pragma unroll
            for (int j = 0; j < 4; ++j)
                c2[ob + wc + j * 16 + lr] = f2bf(fmaxf(acc[i][j][r] + bias[j], 0.f));
            const bool bx = (ox == 59), by = (oy == 59);
            if (bx) {
                size_t zb = (size_t)((bl * 61 + oy) * 61 + 60) * 128;
                #pragma unroll
                for (int j = 0; j < 4; ++j) c2[zb + wc + j * 16 + lr] = 0;
            }
            if (by) {
                size_t zb = (size_t)((bl * 61 + 60) * 61 + ox) * 128;
                #pragma unroll
                for (int j = 0; j < 4; ++j) c2[zb + wc + j * 16 + lr] = 0;
            }
            if (bx && by) {
                size_t zb = (size_t)((bl * 61 + 60) * 61 + 60) * 128;
                #pragma unroll
                for (int j = 0; j < 4; ++j) c2[zb + wc + j * 16 + lr] = 0;
            }
        }
}

// ======================= conv3 MFMA: M=14400 N=256 K=1152 ====================
__global__ __launch_bounds__(256) void k_conv3(
        const unsigned short* __restrict__ c2, const unsigned short* __restrict__ w3t,
        const float* __restrict__ b3, unsigned short* __restrict__ feat, int f0) {
    __shared__ __align__(16) unsigned short As[2][128 * 32];
    __shared__ __align__(16) unsigned short Bs[2][64 * 32];
    const int t = threadIdx.x, w = t >> 6, l = t & 63;
    const int m0 = blockIdx.x * 128, n0 = blockIdx.y * 64;   // grid (113,4)
    const int ko = (l & 3) * 8;
    size_t aga[2], bga;
    #pragma unroll
    for (int i = 0; i < 2; ++i) {
        int r = (w * 2 + i) * 16 + (l >> 2);
        int m = min(m0 + r, 14399);
        int bl = m / 900, rem = m - bl * 900, oy = rem / 30, ox = rem - oy * 30;
        aga[i] = (size_t)((bl * 61 + 2 * oy) * 61 + 2 * ox) * 128 + ko;
    }
    { int n = n0 + w * 16 + (l >> 2); bga = (size_t)n * 1152 + ko; }
    const int wr = (w >> 1) * 64, wc = (w & 1) * 32, lr = l & 15, lk = (l >> 4) * 8;
    f32x4 acc[4][2] = {};
    auto stage = [&](int buf, int s) {
        int ky = s / 12, r12 = s - ky * 12, kx = r12 >> 2, h = r12 & 3;
        int aoff = (ky * 61 + kx) * 128 + h * 32;
        int boff = (ky * 3 + kx) * 128 + h * 32;
        #pragma unroll
        for (int i = 0; i < 2; ++i)
            gl16(c2 + aga[i] + aoff, &As[buf][(w * 2 + i) * 512]);
        gl16(w3t + bga + boff, &Bs[buf][w * 512]);
    };
    stage(0, 0);
    __syncthreads();
    int cur = 0;
    for (int s = 0; s < 36; ++s) {
        if (s + 1 < 36) stage(cur ^ 1, s + 1);
        bf16x8 af[4], bfv[2];
        #pragma unroll
        for (int i = 0; i < 4; ++i) af[i] = *(const bf16x8*)&As[cur][(wr + i * 16 + lr) * 32 + lk];
        #pragma unroll
        for (int j = 0; j < 2; ++j) bfv[j] = *(const bf16x8*)&Bs[cur][(wc + j * 16 + lr) * 32 + lk];
        #pragma unroll
        for (int i = 0; i < 4; ++i)
            #pragma unroll
            for (int j = 0; j < 2; ++j)
                acc[i][j] = __builtin_amdgcn_mfma_f32_16x16x32_bf16(af[i], bfv[j], acc[i][j], 0, 0, 0);
        __syncthreads();
        cur ^= 1;
    }
    float bias[2];
    #pragma unroll
    for (int j = 0; j < 2; ++j) bias[j] = b3[n0 + wc + j * 16 + lr];
    #pragma unroll
    for (int i = 0; i < 4; ++i)
        #pragma unroll
        for (int r = 0; r < 4; ++r) {
            int m = m0 + wr + i * 16 + (l >> 4) * 4 + r;
            if (m < 14400) {
                int bl = m / 900, pos = m - bl * 900;
                size_t ob = ((size_t)(f0 + bl) * 960 + pos) * 256;
                #pragma unroll
                for (int j = 0; j < 2; ++j)
                    feat[ob + n0 + wc + j * 16 + lr] = f2bf(fmaxf(acc[i][j][r] + bias[j], 0.f));
            }
        }
}

// ======================= l2norm: wave per row, ushort4 loads =================
__global__ __launch_bounds__(256) void k_l2norm(unsigned short* __restrict__ feat) {
    const int t = threadIdx.x, wv = t >> 6, ln = t & 63;
    const int R = blockIdx.x * 4 + wv;             // 30720 rows, grid 7680
    const int pos = R % 960;
    ushort4* fp4 = (ushort4*)(feat + (size_t)R * 256);
    if (pos >= 900) { fp4[ln] = make_ushort4(0, 0, 0, 0); return; }
    ushort4 u = fp4[ln];
    float x0 = bf2f(u.x), x1 = bf2f(u.y), x2 = bf2f(u.z), x3 = bf2f(u.w);
    float s = x0 * x0 + x1 * x1 + x2 * x2 + x3 * x3;
    #pragma unroll
    for (int m = 1; m < 64; m <<= 1) s += __shfl_xor(s, m);
    const float inv = 1.f / sqrtf(s + EPSF);
    u.x = f2bf(x0 * inv); u.y = f2bf(x1 * inv);
    u.z = f2bf(x2 * inv); u.w = f2bf(x3 * inv);
    fp4[ln] = u;
}

// ======================= corr MFMA: per-b 960x960, relu, bf16 ================
__global__ __launch_bounds__(256) void k_corr(
        const unsigned short* __restrict__ feat, unsigned short* __restrict__ corr) {
    __shared__ __align__(16) unsigned short As[2][64 * 32];
    __shared__ __align__(16) unsigned short Bs[2][64 * 32];
    const int t = threadIdx.x, w = t >> 6, l = t & 63;
    const int b = blockIdx.z, p0 = blockIdx.y * 64, q0 = blockIdx.x * 64;
    const int ko = (l & 3) * 8;
    const unsigned short* base = feat + (size_t)((w < 2) ? b : 16 + b) * 960 * 256;
    const int r0 = (w < 2) ? p0 : q0;
    const int wi = w & 1;
    size_t ga[2];
    #pragma unroll
    for (int i = 0; i < 2; ++i) {
        int row = (wi * 2 + i) * 16 + (l >> 2);
        ga[i] = (size_t)(r0 + row) * 256 + ko;
    }
    const int wr = (w >> 1) * 32, wc = (w & 1) * 32, lr = l & 15, lk = (l >> 4) * 8;
    f32x4 acc[2][2] = {};
    auto stage = [&](int buf, int k0) {
        #pragma unroll
        for (int i = 0; i < 2; ++i) {
            unsigned short* dst = (w < 2) ? &As[buf][(wi * 2 + i) * 512]
                                          : &Bs[buf][(wi * 2 + i) * 512];
            gl16(base + ga[i] + k0, dst);
        }
    };
    stage(0, 0);
    __syncthreads();
    int cur = 0;
    for (int s = 0; s < 8; ++s) {
        if (s + 1 < 8) stage(cur ^ 1, (s + 1) * 32);
        bf16x8 af[2], bfv[2];
        #pragma unroll
        for (int i = 0; i < 2; ++i) af[i] = *(const bf16x8*)&As[cur][(wr + i * 16 + lr) * 32 + lk];
        #pragma unroll
        for (int j = 0; j < 2; ++j) bfv[j] = *(const bf16x8*)&Bs[cur][(wc + j * 16 + lr) * 32 + lk];
        #pragma unroll
        for (int i = 0; i < 2; ++i)
            #pragma unroll
            for (int j = 0; j < 2; ++j)
                acc[i][j] = __builtin_amdgcn_mfma_f32_16x16x32_bf16(af[i], bfv[j], acc[i][j], 0, 0, 0);
        __syncthreads();
        cur ^= 1;
    }
    unsigned short* cb = corr + (size_t)b * 960 * 960;
    #pragma unroll
    for (int i = 0; i < 2; ++i)
        #pragma unroll
        for (int r = 0; r < 4; ++r) {
            int row = p0 + wr + i * 16 + (l >> 4) * 4 + r;
            #pragma unroll
            for (int j = 0; j < 2; ++j)
                cb[(size_t)row * 960 + q0 + wc + j * 16 + lr] = f2bf(fmaxf(acc[i][j][r], 0.f));
        }
}

// ======================= corr L2 norm over 900 channels (ushort4) ============
__global__ __launch_bounds__(256) void k_corrnorm(unsigned short* __restrict__ corr) {
    const int rb = blockIdx.x;                 // 16*900
    const int b = rb / 900, p = rb - b * 900;
    const int t = threadIdx.x;
    ushort4* cp4 = (ushort4*)(corr + ((size_t)b * 960 + p) * 960);
    float x0 = 0.f, x1 = 0.f, x2 = 0.f, x3 = 0.f;
    if (t < 225) {
        ushort4 u = cp4[t];
        x0 = fmaxf(bf2f(u.x), 0.f); x1 = fmaxf(bf2f(u.y), 0.f);
        x2 = fmaxf(bf2f(u.z), 0.f); x3 = fmaxf(bf2f(u.w), 0.f);
    }
    float s = x0 * x0 + x1 * x1 + x2 * x2 + x3 * x3;
    #pragma unroll
    for (int m = 1; m < 64; m <<= 1) s += __shfl_xor(s, m);
    __shared__ float red[4];
    if ((t & 63) == 0) red[t >> 6] = s;
    __syncthreads();
    const float sc = 1.f / sqrtf(red[0] + red[1] + red[2] + red[3] + EPSF);
    if (t < 225) {
        ushort4 u;
        u.x = f2bf(x0 * sc); u.y = f2bf(x1 * sc);
        u.z = f2bf(x2 * sc); u.w = f2bf(x3 * sc);
        cp4[t] = u;
    }
}

// ======================= cw1 MFMA: M=9216 N=128, K'=49*928, split 14 =========
// 128x128 tile, fp16 partials, chunk-XOR LDS swizzle (pre-swizzled global src)
__global__ __launch_bounds__(256) void k_cw1(
        const unsigned short* __restrict__ corr, const unsigned short* __restrict__ Wt,
        unsigned short* __restrict__ part) {
    __shared__ __align__(16) unsigned short As[2][128 * 32];
    __shared__ __align__(16) unsigned short Bs[2][128 * 32];
    const int t = threadIdx.x, w = t >> 6, l = t & 63;
    const int m0 = blockIdx.x * 128, ks = blockIdx.y;       // grid (72,14)
    const int srow = l >> 2, schunk = l & 3;
    const int sk = (schunk ^ (srow & 3)) * 8;               // swizzled k-elem offset
    size_t aga[2], bga[2];
    #pragma unroll
    for (int i = 0; i < 2; ++i) {
        int r = (w * 2 + i) * 16 + srow;
        int m = m0 + r;
        int b = m / 576, rem = m - b * 576, oy = rem / 24, ox = rem - oy * 24;
        aga[i] = (size_t)(b * 960 + oy * 30 + ox) * 960 + sk;
        bga[i] = (size_t)r * 45472 + sk;
    }
    // K-step schedule: 1421 total 32-elem steps (49 squares x 29), split 14
    const int sbase = ks * 101 + min(ks, 7);
    const int scount = 101 + (ks < 7 ? 1 : 0);
    const int wr = (w >> 1) * 64, wc = (w & 1) * 64, lr = l & 15, cI = l >> 4;
    f32x4 acc[4][4] = {};
    auto stage = [&](int buf, int sidx) {
        int s = sbase + sidx;
        int sq = s / 29, qi = s - sq * 29;
        int ky = sq / 7, kx = sq - ky * 7;
        int aoff = (ky * 30 + kx) * 960 + qi * 32;
        int boff = sq * 928 + qi * 32;
        #pragma unroll
        for (int i = 0; i < 2; ++i) {
            gl16(corr + aga[i] + aoff, &As[buf][(w * 2 + i) * 512]);
            gl16(Wt + bga[i] + boff, &Bs[buf][(w * 2 + i) * 512]);
        }
    };
    stage(0, 0);
    __syncthreads();
    int cur = 0;
    for (int s = 0; s < scount; ++s) {
        if (s + 1 < scount) stage(cur ^ 1, s + 1);
        bf16x8 af[4], bfv[4];
        #pragma unroll
        for (int i = 0; i < 4; ++i) {
            int R = wr + i * 16 + lr;
            af[i] = *(const bf16x8*)&As[cur][R * 32 + ((cI ^ (R & 3)) * 8)];
        }
        #pragma unroll
        for (int j = 0; j < 4; ++j) {
            int S = wc + j * 16 + lr;
            bfv[j] = *(const bf16x8*)&Bs[cur][S * 32 + ((cI ^ (S & 3)) * 8)];
        }
        #pragma unroll
        for (int i = 0; i < 4; ++i)
            #pragma unroll
            for (int j = 0; j < 4; ++j)
                acc[i][j] = __builtin_amdgcn_mfma_f32_16x16x32_bf16(af[i], bfv[j], acc[i][j], 0, 0, 0);
        __syncthreads();
        cur ^= 1;
    }
    unsigned short* pb = part + ((size_t)ks * 9216 + m0) * 128;
    #pragma unroll
    for (int i = 0; i < 4; ++i)
        #pragma unroll
        for (int r = 0; r < 4; ++r) {
            int row = wr + i * 16 + cI * 4 + r;
            #pragma unroll
            for (int j = 0; j < 4; ++j)
                pb[(size_t)row * 128 + wc + j * 16 + lr] = f2h(acc[i][j][r]);
        }
}

// ======================= reduce 14 fp16 partials + bias + relu + BN -> bf16 ==
__global__ __launch_bounds__(256) void k_r1fin(
        const unsigned short* __restrict__ part, const float* __restrict__ cb1,
        const float* __restrict__ g1, const float* __restrict__ be1,
        const float* __restrict__ m1, const float* __restrict__ v1,
        unsigned short* __restrict__ r1) {
    const int idx = blockIdx.x * 256 + threadIdx.x;        // grid 1152
    const size_t base = (size_t)idx * 4;
    const size_t N = 9216 * 128;
    float s0 = 0.f, s1 = 0.f, s2 = 0.f, s3 = 0.f;
    #pragma unroll
    for (int i = 0; i < 14; ++i) {
        ushort4 u = *(const ushort4*)(part + i * N + base);
        s0 += h2f(u.x); s1 += h2f(u.y); s2 += h2f(u.z); s3 += h2f(u.w);
    }
    const int co = (int)(base & 127);
    float r[4] = {s0, s1, s2, s3};
    ushort4 o;
    unsigned short* op = (unsigned short*)&o;
    #pragma unroll
    for (int j = 0; j < 4; ++j) {
        int c = co + j;
        float x = fmaxf(r[j] + cb1[c], 0.f);
        x = (x - m1[c]) * (g1[c] / sqrtf(v1[c] + BN_EPSF)) + be1[c];
        op[j] = f2bf(x);
    }
    *(ushort4*)(r1 + base) = o;
}

// ======================= cw2 MFMA: M=6400 N=64 K=3200, bias+relu+BN ==========
__global__ __launch_bounds__(256) void k_cw2(
        const unsigned short* __restrict__ r1, const unsigned short* __restrict__ Wt2,
        const float* __restrict__ cb2, const float* __restrict__ g2,
        const float* __restrict__ be2, const float* __restrict__ m2,
        const float* __restrict__ v2, float* __restrict__ r2) {
    __shared__ __align__(16) unsigned short As[2][64 * 32];
    __shared__ __align__(16) unsigned short Bs[2][64 * 32];
    const int t = threadIdx.x, w = t >> 6, l = t & 63;
    const int m0 = blockIdx.x * 64;                        // grid 100
    const int ko = (l & 3) * 8;
    const int wi = w & 1;
    size_t ga[2];
    #pragma unroll
    for (int i = 0; i < 2; ++i) {
        int r = (wi * 2 + i) * 16 + (l >> 2);
        if (w < 2) {
            int m = m0 + r;
            int b = m / 400, rem = m - b * 400, oy = rem / 20, ox = rem - oy * 20;
            ga[i] = (size_t)((b * 24 + oy) * 24 + ox) * 128 + ko;
        } else {
            ga[i] = (size_t)r * 3200 + ko;
        }
    }
    const int wr = (w >> 1) * 32, wc = (w & 1) * 32, lr = l & 15, lk = (l >> 4) * 8;
    f32x4 acc[2][2] = {};
    auto stage = [&](int buf, int s) {
        int kyx = s >> 2, h = s & 3;
        int ky = kyx / 5, kx = kyx - ky * 5;
        int aoff = (ky * 24 + kx) * 128 + h * 32;
        int boff = s * 32;
        #pragma unroll
        for (int i = 0; i < 2; ++i) {
            unsigned short* dst = (w < 2) ? &As[buf][(wi * 2 + i) * 512]
                                          : &Bs[buf][(wi * 2 + i) * 512];
            const unsigned short* src = (w < 2) ? r1 + ga[i] + aoff : Wt2 + ga[i] + boff;
            gl16(src, dst);
        }
    };
    stage(0, 0);
    __syncthreads();
    int cur = 0;
    for (int s = 0; s < 100; ++s) {
        if (s + 1 < 100) stage(cur ^ 1, s + 1);
        bf16x8 af[2], bfv[2];
        #pragma unroll
        for (int i = 0; i < 2; ++i) af[i] = *(const bf16x8*)&As[cur][(wr + i * 16 + lr) * 32 + lk];
        #pragma unroll
        for (int j = 0; j < 2; ++j) bfv[j] = *(const bf16x8*)&Bs[cur][(wc + j * 16 + lr) * 32 + lk];
        #pragma unroll
        for (int i = 0; i < 2; ++i)
            #pragma unroll
            for (int j = 0; j < 2; ++j)
                acc[i][j] = __builtin_amdgcn_mfma_f32_16x16x32_bf16(af[i], bfv[j], acc[i][j], 0, 0, 0);
        __syncthreads();
        cur ^= 1;
    }
    float sc[2], sh[2], bias[2];
    #pragma unroll
    for (int j = 0; j < 2; ++j) {
        int co = wc + j * 16 + lr;
        sc[j] = g2[co] / sqrtf(v2[co] + BN_EPSF);
        sh[j] = be2[co] - m2[co] * sc[j];
        bias[j] = cb2[co];
    }
    #pragma unroll
    for (int i = 0; i < 2; ++i)
        #pragma unroll
        for (int r = 0; r < 4; ++r) {
            int m = m0 + wr + i * 16 + (l >> 4) * 4 + r;
            #pragma unroll
            for (int j = 0; j < 2; ++j) {
                float s = fmaxf(acc[i][j][r] + bias[j], 0.f);
                r2[(size_t)m * 64 + wc + j * 16 + lr] = s * sc[j] + sh[j];
            }
        }
}

// ======================= dense: K-split partials + finalize ==================
__global__ __launch_bounds__(256) void k_dense(
        const float* __restrict__ r2, const float* __restrict__ dw,
        float* __restrict__ partD) {
    const int b = blockIdx.x, kb = blockIdx.y, t = threadIdx.x;  // (16,5)
    const float* x = r2 + (size_t)b * 25600 + kb * 5120;
    const float* dwp = dw + (size_t)(kb * 5120) * 18;
    float s[18] = {};
    for (int k = t; k < 5120; k += 256) {
        const float xv = x[k];
        const float* dr = dwp + (size_t)k * 18;
        #pragma unroll
        for (int j = 0; j < 18; ++j) s[j] = fmaf(xv, dr[j], s[j]);
    }
    #pragma unroll
    for (int j = 0; j < 18; ++j)
        #pragma unroll
        for (int m = 1; m < 64; m <<= 1) s[j] += __shfl_xor(s[j], m);
    __shared__ float red[4][18];
    if ((t & 63) == 0) {
        #pragma unroll
        for (int j = 0; j < 18; ++j) red[t >> 6][j] = s[j];
    }
    __syncthreads();
    if (t < 18) partD[(b * 5 + kb) * 18 + t] = red[0][t] + red[1][t] + red[2][t] + red[3][t];
}
__global__ __launch_bounds__(288) void k_dfin(
        const float* __restrict__ partD, const float* __restrict__ db,
        float* __restrict__ out) {
    const int i = threadIdx.x;                 // 288
    const int b = i / 18, j = i - b * 18;
    float s = db[j];
    #pragma unroll
    for (int k = 0; k < 5; ++k) s += partD[(b * 5 + k) * 18 + j];
    out[i] = s;
}

extern "C" void kernel_launch(void* const* d_in, const int* in_sizes, int n_in,
                              void* d_out, int out_size, void* d_ws, size_t ws_size,
                              hipStream_t stream) {
    const float* imgA = (const float*)d_in[0];
    const float* imgB = (const float*)d_in[1];
    const float* w1  = (const float*)d_in[2];
    const float* b1  = (const float*)d_in[3];
    const float* w2  = (const float*)d_in[4];
    const float* b2  = (const float*)d_in[5];
    const float* w3  = (const float*)d_in[6];
    const float* b3  = (const float*)d_in[7];
    const float* cw1 = (const float*)d_in[8];
    const float* cb1 = (const float*)d_in[9];
    const float* g1  = (const float*)d_in[10];
    const float* be1 = (const float*)d_in[11];
    const float* m1  = (const float*)d_in[12];
    const float* v1  = (const float*)d_in[13];
    const float* cw2 = (const float*)d_in[14];
    const float* cb2 = (const float*)d_in[15];
    const float* g2  = (const float*)d_in[16];
    const float* be2 = (const float*)d_in[17];
    const float* m2  = (const float*)d_in[18];
    const float* v2  = (const float*)d_in[19];
    const float* dw  = (const float*)d_in[20];
    const float* db  = (const float*)d_in[21];

    // ws layout (bytes), max end = 76,931,072 (<= 78,249,984 proven available)
    //  conv phase : c1@0 (30.0MB,16img) c2@29,984,768 (15.2MB) w2t@45,225,984
    //               w3t@45,373,440  feat@45,963,264 (15.7MB)
    //  corr phase : corr@0 (29.5MB, c1 dead)  Wt@29,491,200 (11.6MB, c2 dead)
    //  cw1 phase  : part@41,132,032 (33.0MB fp16x14, feat/w2t/w3t dead)
    //  tail       : r1@74,162,176 (2.4MB)  Wt2@76,521,472  r2@41,132,032 (part dead)
    //               partD@42,770,432
    char* ws = (char*)d_ws;
    unsigned short* c1   = (unsigned short*)(ws + 0);
    unsigned short* c2   = (unsigned short*)(ws + 29984768);
    unsigned short* w2t  = (unsigned short*)(ws + 45225984);
    unsigned short* w3t  = (unsigned short*)(ws + 45373440);
    unsigned short* feat = (unsigned short*)(ws + 45963264);
    unsigned short* corr = (unsigned short*)(ws + 0);
    unsigned short* Wt   = (unsigned short*)(ws + 29491200);
    unsigned short* part = (unsigned short*)(ws + 41132032);
    unsigned short* r1   = (unsigned short*)(ws + 74162176);
    unsigned short* Wt2  = (unsigned short*)(ws + 76521472);
    float*          r2   = (float*)(ws + 41132032);
    float*          partD= (float*)(ws + 42770432);

    k_w2t<<<dim3(288), 256, 0, stream>>>(w2, w2t);
    k_w3t<<<dim3(1152), 256, 0, stream>>>(w3, w3t);

    for (int chunk = 0; chunk < 2; ++chunk) {
        const float* img = chunk ? imgB : imgA;
        const int f0 = chunk * 16;
        k_conv1<<<dim3(30, 120, 16), 256, 0, stream>>>(img, w1, b1, c1);
        k_conv2<<<dim3(450),         256, 0, stream>>>(c1, w2t, b2, c2);
        k_conv3<<<dim3(113, 4),      256, 0, stream>>>(c2, w3t, b3, feat, f0);
    }
    k_l2norm  <<<dim3(7680),       256, 0, stream>>>(feat);
    k_corr    <<<dim3(15, 15, 16), 256, 0, stream>>>(feat, corr);
    k_corrnorm<<<dim3(14400),      256, 0, stream>>>(corr);
    k_wt1     <<<dim3(178, 128),   256, 0, stream>>>(cw1, Wt);
    k_cw1     <<<dim3(72, 14),     256, 0, stream>>>(corr, Wt, part);
    k_r1fin   <<<dim3(1152),       256, 0, stream>>>(part, cb1, g1, be1, m1, v1, r1);
    k_wt2     <<<dim3(800),        256, 0, stream>>>(cw2, Wt2);
    k_cw2     <<<dim3(100),        256, 0, stream>>>(r1, Wt2, cb2, g2, be2, m2, v2, r2);
    k_dense   <<<dim3(16, 5),      256, 0, stream>>>(r2, dw, partD);
    k_dfin    <<<dim3(1),          288, 0, stream>>>(partD, db, (float*)d_out);
}

// Round 5
// 588.964 us; speedup vs baseline: 11.3734x; 1.0716x over previous
//
#include <hip/hip_runtime.h>

#define EPSF    1e-6f
#define BN_EPSF 1e-3f

typedef __attribute__((ext_vector_type(8))) short bf16x8;   // 8 bf16 in 4 VGPRs
typedef __attribute__((ext_vector_type(4))) float f32x4;

__device__ __forceinline__ unsigned short f2bf(float f) {
    unsigned int u = __builtin_bit_cast(unsigned int, f);
    u = (u + 0x7FFFu + ((u >> 16) & 1u)) >> 16;            // RNE
    return (unsigned short)u;
}
__device__ __forceinline__ float bf2f(unsigned short h) {
    unsigned int u = ((unsigned int)h) << 16;
    return __builtin_bit_cast(float, u);
}
__device__ __forceinline__ unsigned short f2h(float f) {
    return __builtin_bit_cast(unsigned short, (_Float16)f);
}
__device__ __forceinline__ float h2f(unsigned short h) {
    return (float)__builtin_bit_cast(_Float16, h);
}
// async global->LDS, 16 bytes per lane; lds dest is wave-uniform base + lane*16
__device__ __forceinline__ void gl16(const void* g, void* l) {
    __builtin_amdgcn_global_load_lds((const __attribute__((address_space(1))) void*)g,
                                     (__attribute__((address_space(3))) void*)l, 16, 0, 0);
}
// counted-vmcnt barrier pair: wait for all but the newest-in-flight stage, sync
#define PIPE_WAIT(N)                                        \
    asm volatile("s_waitcnt vmcnt(" #N ")" ::: "memory");   \
    __builtin_amdgcn_sched_barrier(0);                      \
    __builtin_amdgcn_s_barrier();                           \
    __builtin_amdgcn_sched_barrier(0);

// ======================= weight conversion kernels ===========================
__global__ __launch_bounds__(256) void k_w2t(const float* __restrict__ w2,
                                             unsigned short* __restrict__ w2t) {
    int idx = blockIdx.x * 256 + threadIdx.x;              // 73728
    int n = idx / 576, k = idx - n * 576;
    w2t[idx] = f2bf(w2[(size_t)k * 128 + n]);
}
__global__ __launch_bounds__(256) void k_w3t(const float* __restrict__ w3,
                                             unsigned short* __restrict__ w3t) {
    int idx = blockIdx.x * 256 + threadIdx.x;              // 294912
    int n = idx / 1152, k = idx - n * 1152;
    w3t[idx] = f2bf(w3[(size_t)k * 256 + n]);
}
// Wt[n][k'], k'=s*928+q, zero for q>=900; coalesced LDS transpose. grid (29,49)
__global__ __launch_bounds__(256) void k_wt1(const float* __restrict__ W,
                                             unsigned short* __restrict__ Wt) {
    __shared__ float tile[32][132];
    const int s = blockIdx.y;              // 49
    const int q0 = blockIdx.x * 32;        // 0..896
    const int t = threadIdx.x;
    const int n = t & 127, rr = t >> 7;
    #pragma unroll
    for (int r = rr; r < 32; r += 2) {
        int q = q0 + r;
        tile[r][n] = (q < 900) ? W[((size_t)(s * 900 + q)) * 128 + n] : 0.f;
    }
    __syncthreads();
    const int n2 = t >> 1, half = t & 1;
    unsigned short* dst = Wt + (size_t)n2 * 45472 + s * 928 + q0 + half * 16;
    #pragma unroll
    for (int u = 0; u < 16; ++u) dst[u] = f2bf(tile[half * 16 + u][n2]);
}
// Wt2[n][k], k=(ky*5+kx)*128+ci, n=64, K=3200
__global__ __launch_bounds__(256) void k_wt2(const float* __restrict__ W,
                                             unsigned short* __restrict__ Wt2) {
    int idx = blockIdx.x * 256 + threadIdx.x;              // 204800, grid 800
    int n = idx / 3200, k = idx - n * 3200;
    Wt2[idx] = f2bf(W[(size_t)k * 64 + n]);
}

// ======================= conv1 (fp32 in -> bf16 padded out, border fused) ====
__global__ __launch_bounds__(256) void k_conv1(
        const float* __restrict__ img,
        const float* __restrict__ w, const float* __restrict__ bias,
        unsigned short* __restrict__ c1) {
    const int co = threadIdx.x & 63, u = threadIdx.x >> 6;
    const int ox = blockIdx.x * 4 + u;                     // 120
    const int oy = blockIdx.y;                             // 120
    const int b = blockIdx.z;                              // 16
    float acc = bias[co];
    #pragma unroll
    for (int ky = 0; ky < 3; ++ky) {
        const int iy = 2 * oy + ky;
        if (iy >= 240) continue;
        #pragma unroll
        for (int kx = 0; kx < 3; ++kx) {
            const int ix = 2 * ox + kx;
            if (ix >= 240) continue;
            const float* ip = img + ((size_t)(b * 240 + iy) * 240 + ix) * 3;
            const float* wp = w + ((ky * 3 + kx) * 3) * 64 + co;
            acc = fmaf(ip[0], wp[0], acc);
            acc = fmaf(ip[1], wp[64], acc);
            acc = fmaf(ip[2], wp[128], acc);
        }
    }
    c1[((size_t)(b * 121 + oy) * 121 + ox) * 64 + co] = f2bf(fmaxf(acc, 0.f));
    const bool bx = (ox == 119), by = (oy == 119);
    if (bx) c1[((size_t)(b * 121 + oy) * 121 + 120) * 64 + co] = 0;
    if (by) c1[((size_t)(b * 121 + 120) * 121 + ox) * 64 + co] = 0;
    if (bx && by) c1[((size_t)(b * 121 + 120) * 121 + 120) * 64 + co] = 0;
}

// ======================= conv2 MFMA: M=57600 N=128 K=576 (3-buf pipeline) ====
__global__ __launch_bounds__(256) void k_conv2(
        const unsigned short* __restrict__ c1, const unsigned short* __restrict__ w2t,
        const float* __restrict__ b2, unsigned short* __restrict__ c2) {
    __shared__ __align__(16) unsigned short As[3][128 * 32];
    __shared__ __align__(16) unsigned short Bs[3][128 * 32];
    const int t = threadIdx.x, w = t >> 6, l = t & 63;
    const int m0 = blockIdx.x * 128;                       // grid 450
    const int ko = (l & 3) * 8;
    size_t aga[2], bga[2];
    #pragma unroll
    for (int i = 0; i < 2; ++i) {
        int r = (w * 2 + i) * 16 + (l >> 2);
        int m = m0 + r;
        int bl = m / 3600, rem = m - bl * 3600, oy = rem / 60, ox = rem - oy * 60;
        aga[i] = (size_t)((bl * 121 + 2 * oy) * 121 + 2 * ox) * 64 + ko;
        bga[i] = (size_t)r * 576 + ko;
    }
    const int wr = (w >> 1) * 64, wc = (w & 1) * 64, lr = l & 15, lk = (l >> 4) * 8;
    f32x4 acc[4][4] = {};
    auto stage = [&](int buf, int s) {
        int ky = s / 6, r6 = s - ky * 6, kx = r6 >> 1, h = r6 & 1;
        int aoff = (ky * 121 + kx) * 64 + h * 32;
        int boff = (ky * 3 + kx) * 64 + h * 32;
        #pragma unroll
        for (int i = 0; i < 2; ++i) {
            gl16(c1 + aga[i] + aoff, &As[buf][(w * 2 + i) * 512]);
            gl16(w2t + bga[i] + boff, &Bs[buf][(w * 2 + i) * 512]);
        }
    };
    stage(0, 0); stage(1, 1);
    int cur = 0, pre = 2;
    for (int s = 0; s < 18; ++s) {
        if (s + 1 < 18) { PIPE_WAIT(4) } else { PIPE_WAIT(0) }
        if (s + 2 < 18) stage(pre, s + 2);
        bf16x8 af[4], bfv[4];
        #pragma unroll
        for (int i = 0; i < 4; ++i) af[i] = *(const bf16x8*)&As[cur][(wr + i * 16 + lr) * 32 + lk];
        #pragma unroll
        for (int j = 0; j < 4; ++j) bfv[j] = *(const bf16x8*)&Bs[cur][(wc + j * 16 + lr) * 32 + lk];
        #pragma unroll
        for (int i = 0; i < 4; ++i)
            #pragma unroll
            for (int j = 0; j < 4; ++j)
                acc[i][j] = __builtin_amdgcn_mfma_f32_16x16x32_bf16(af[i], bfv[j], acc[i][j], 0, 0, 0);
        pre = cur; cur = (cur == 2) ? 0 : cur + 1;
    }
    float bias[4];
    #pragma unroll
    for (int j = 0; j < 4; ++j) bias[j] = b2[wc + j * 16 + lr];
    #pragma unroll
    for (int i = 0; i < 4; ++i)
        #pragma unroll
        for (int r = 0; r < 4; ++r) {
            int m = m0 + wr + i * 16 + (l >> 4) * 4 + r;
            int bl = m / 3600, rem = m - bl * 3600, oy = rem / 60, ox = rem - oy * 60;
            size_t ob = (size_t)((bl * 61 + oy) * 61 + ox) * 128;
            #pragma unroll
            for (int j = 0; j < 4; ++j)
                c2[ob + wc + j * 16 + lr] = f2bf(fmaxf(acc[i][j][r] + bias[j], 0.f));
            const bool bx = (ox == 59), by = (oy == 59);
            if (bx) {
                size_t zb = (size_t)((bl * 61 + oy) * 61 + 60) * 128;
                #pragma unroll
                for (int j = 0; j < 4; ++j) c2[zb + wc + j * 16 + lr] = 0;
            }
            if (by) {
                size_t zb = (size_t)((bl * 61 + 60) * 61 + ox) * 128;
                #pragma unroll
                for (int j = 0; j < 4; ++j) c2[zb + wc + j * 16 + lr] = 0;
            }
            if (bx && by) {
                size_t zb = (size_t)((bl * 61 + 60) * 61 + 60) * 128;
                #pragma unroll
                for (int j = 0; j < 4; ++j) c2[zb + wc + j * 16 + lr] = 0;
            }
        }
}

// ======================= conv3 MFMA: M=14400 N=256 K=1152 (3-buf) ============
__global__ __launch_bounds__(256) void k_conv3(
        const unsigned short* __restrict__ c2, const unsigned short* __restrict__ w3t,
        const float* __restrict__ b3, unsigned short* __restrict__ feat, int f0) {
    __shared__ __align__(16) unsigned short As[3][128 * 32];
    __shared__ __align__(16) unsigned short Bs[3][64 * 32];
    const int t = threadIdx.x, w = t >> 6, l = t & 63;
    const int m0 = blockIdx.x * 128, n0 = blockIdx.y * 64;   // grid (113,4)
    const int ko = (l & 3) * 8;
    size_t aga[2], bga;
    #pragma unroll
    for (int i = 0; i < 2; ++i) {
        int r = (w * 2 + i) * 16 + (l >> 2);
        int m = min(m0 + r, 14399);
        int bl = m / 900, rem = m - bl * 900, oy = rem / 30, ox = rem - oy * 30;
        aga[i] = (size_t)((bl * 61 + 2 * oy) * 61 + 2 * ox) * 128 + ko;
    }
    { int n = n0 + w * 16 + (l >> 2); bga = (size_t)n * 1152 + ko; }
    const int wr = (w >> 1) * 64, wc = (w & 1) * 32, lr = l & 15, lk = (l >> 4) * 8;
    f32x4 acc[4][2] = {};
    auto stage = [&](int buf, int s) {
        int ky = s / 12, r12 = s - ky * 12, kx = r12 >> 2, h = r12 & 3;
        int aoff = (ky * 61 + kx) * 128 + h * 32;
        int boff = (ky * 3 + kx) * 128 + h * 32;
        #pragma unroll
        for (int i = 0; i < 2; ++i)
            gl16(c2 + aga[i] + aoff, &As[buf][(w * 2 + i) * 512]);
        gl16(w3t + bga + boff, &Bs[buf][w * 512]);
    };
    stage(0, 0); stage(1, 1);
    int cur = 0, pre = 2;
    for (int s = 0; s < 36; ++s) {
        if (s + 1 < 36) { PIPE_WAIT(3) } else { PIPE_WAIT(0) }
        if (s + 2 < 36) stage(pre, s + 2);
        bf16x8 af[4], bfv[2];
        #pragma unroll
        for (int i = 0; i < 4; ++i) af[i] = *(const bf16x8*)&As[cur][(wr + i * 16 + lr) * 32 + lk];
        #pragma unroll
        for (int j = 0; j < 2; ++j) bfv[j] = *(const bf16x8*)&Bs[cur][(wc + j * 16 + lr) * 32 + lk];
        #pragma unroll
        for (int i = 0; i < 4; ++i)
            #pragma unroll
            for (int j = 0; j < 2; ++j)
                acc[i][j] = __builtin_amdgcn_mfma_f32_16x16x32_bf16(af[i], bfv[j], acc[i][j], 0, 0, 0);
        pre = cur; cur = (cur == 2) ? 0 : cur + 1;
    }
    float bias[2];
    #pragma unroll
    for (int j = 0; j < 2; ++j) bias[j] = b3[n0 + wc + j * 16 + lr];
    #pragma unroll
    for (int i = 0; i < 4; ++i)
        #pragma unroll
        for (int r = 0; r < 4; ++r) {
            int m = m0 + wr + i * 16 + (l >> 4) * 4 + r;
            if (m < 14400) {
                int bl = m / 900, pos = m - bl * 900;
                size_t ob = ((size_t)(f0 + bl) * 960 + pos) * 256;
                #pragma unroll
                for (int j = 0; j < 2; ++j)
                    feat[ob + n0 + wc + j * 16 + lr] = f2bf(fmaxf(acc[i][j][r] + bias[j], 0.f));
            }
        }
}

// ======================= l2norm: wave per row, ushort4 loads =================
__global__ __launch_bounds__(256) void k_l2norm(unsigned short* __restrict__ feat) {
    const int t = threadIdx.x, wv = t >> 6, ln = t & 63;
    const int R = blockIdx.x * 4 + wv;             // 30720 rows, grid 7680
    const int pos = R % 960;
    ushort4* fp4 = (ushort4*)(feat + (size_t)R * 256);
    if (pos >= 900) { fp4[ln] = make_ushort4(0, 0, 0, 0); return; }
    ushort4 u = fp4[ln];
    float x0 = bf2f(u.x), x1 = bf2f(u.y), x2 = bf2f(u.z), x3 = bf2f(u.w);
    float s = x0 * x0 + x1 * x1 + x2 * x2 + x3 * x3;
    #pragma unroll
    for (int m = 1; m < 64; m <<= 1) s += __shfl_xor(s, m);
    const float inv = 1.f / sqrtf(s + EPSF);
    u.x = f2bf(x0 * inv); u.y = f2bf(x1 * inv);
    u.z = f2bf(x2 * inv); u.w = f2bf(x3 * inv);
    fp4[ln] = u;
}

// ======================= corr MFMA: per-b 960x960, relu, bf16 (3-buf) ========
__global__ __launch_bounds__(256) void k_corr(
        const unsigned short* __restrict__ feat, unsigned short* __restrict__ corr) {
    __shared__ __align__(16) unsigned short As[3][64 * 32];
    __shared__ __align__(16) unsigned short Bs[3][64 * 32];
    const int t = threadIdx.x, w = t >> 6, l = t & 63;
    const int b = blockIdx.z, p0 = blockIdx.y * 64, q0 = blockIdx.x * 64;
    const int ko = (l & 3) * 8;
    const unsigned short* base = feat + (size_t)((w < 2) ? b : 16 + b) * 960 * 256;
    const int r0 = (w < 2) ? p0 : q0;
    const int wi = w & 1;
    size_t ga[2];
    #pragma unroll
    for (int i = 0; i < 2; ++i) {
        int row = (wi * 2 + i) * 16 + (l >> 2);
        ga[i] = (size_t)(r0 + row) * 256 + ko;
    }
    const int wr = (w >> 1) * 32, wc = (w & 1) * 32, lr = l & 15, lk = (l >> 4) * 8;
    f32x4 acc[2][2] = {};
    auto stage = [&](int buf, int s) {
        #pragma unroll
        for (int i = 0; i < 2; ++i) {
            unsigned short* dst = (w < 2) ? &As[buf][(wi * 2 + i) * 512]
                                          : &Bs[buf][(wi * 2 + i) * 512];
            gl16(base + ga[i] + s * 32, dst);
        }
    };
    stage(0, 0); stage(1, 1);
    int cur = 0, pre = 2;
    for (int s = 0; s < 8; ++s) {
        if (s + 1 < 8) { PIPE_WAIT(2) } else { PIPE_WAIT(0) }
        if (s + 2 < 8) stage(pre, s + 2);
        bf16x8 af[2], bfv[2];
        #pragma unroll
        for (int i = 0; i < 2; ++i) af[i] = *(const bf16x8*)&As[cur][(wr + i * 16 + lr) * 32 + lk];
        #pragma unroll
        for (int j = 0; j < 2; ++j) bfv[j] = *(const bf16x8*)&Bs[cur][(wc + j * 16 + lr) * 32 + lk];
        #pragma unroll
        for (int i = 0; i < 2; ++i)
            #pragma unroll
            for (int j = 0; j < 2; ++j)
                acc[i][j] = __builtin_amdgcn_mfma_f32_16x16x32_bf16(af[i], bfv[j], acc[i][j], 0, 0, 0);
        pre = cur; cur = (cur == 2) ? 0 : cur + 1;
    }
    unsigned short* cb = corr + (size_t)b * 960 * 960;
    #pragma unroll
    for (int i = 0; i < 2; ++i)
        #pragma unroll
        for (int r = 0; r < 4; ++r) {
            int row = p0 + wr + i * 16 + (l >> 4) * 4 + r;
            #pragma unroll
            for (int j = 0; j < 2; ++j)
                cb[(size_t)row * 960 + q0 + wc + j * 16 + lr] = f2bf(fmaxf(acc[i][j][r], 0.f));
        }
}

// ======================= corr L2 norm over 900 channels (ushort4) ============
__global__ __launch_bounds__(256) void k_corrnorm(unsigned short* __restrict__ corr) {
    const int rb = blockIdx.x;                 // 16*900
    const int b = rb / 900, p = rb - b * 900;
    const int t = threadIdx.x;
    ushort4* cp4 = (ushort4*)(corr + ((size_t)b * 960 + p) * 960);
    float x0 = 0.f, x1 = 0.f, x2 = 0.f, x3 = 0.f;
    if (t < 225) {
        ushort4 u = cp4[t];
        x0 = fmaxf(bf2f(u.x), 0.f); x1 = fmaxf(bf2f(u.y), 0.f);
        x2 = fmaxf(bf2f(u.z), 0.f); x3 = fmaxf(bf2f(u.w), 0.f);
    }
    float s = x0 * x0 + x1 * x1 + x2 * x2 + x3 * x3;
    #pragma unroll
    for (int m = 1; m < 64; m <<= 1) s += __shfl_xor(s, m);
    __shared__ float red[4];
    if ((t & 63) == 0) red[t >> 6] = s;
    __syncthreads();
    const float sc = 1.f / sqrtf(red[0] + red[1] + red[2] + red[3] + EPSF);
    if (t < 225) {
        ushort4 u;
        u.x = f2bf(x0 * sc); u.y = f2bf(x1 * sc);
        u.z = f2bf(x2 * sc); u.w = f2bf(x3 * sc);
        cp4[t] = u;
    }
}

// ======================= cw1 MFMA: M=9216 N=128, K'=49*928, split 14 (3-buf) =
__global__ __launch_bounds__(256) void k_cw1(
        const unsigned short* __restrict__ corr, const unsigned short* __restrict__ Wt,
        unsigned short* __restrict__ part) {
    __shared__ __align__(16) unsigned short As[3][128 * 32];
    __shared__ __align__(16) unsigned short Bs[3][128 * 32];
    const int t = threadIdx.x, w = t >> 6, l = t & 63;
    const int m0 = blockIdx.x * 128, ks = blockIdx.y;       // grid (72,14)
    const int ko = (l & 3) * 8;
    size_t aga[2], bga[2];
    #pragma unroll
    for (int i = 0; i < 2; ++i) {
        int r = (w * 2 + i) * 16 + (l >> 2);
        int m = m0 + r;
        int b = m / 576, rem = m - b * 576, oy = rem / 24, ox = rem - oy * 24;
        aga[i] = (size_t)(b * 960 + oy * 30 + ox) * 960 + ko;
        bga[i] = (size_t)r * 45472 + ko;
    }
    // K-step schedule: 1421 total 32-elem steps (49 squares x 29), split 14
    const int sbase = ks * 101 + min(ks, 7);
    const int scount = 101 + (ks < 7 ? 1 : 0);
    const int wr = (w >> 1) * 64, wc = (w & 1) * 64, lr = l & 15, lk = (l >> 4) * 8;
    f32x4 acc[4][4] = {};
    auto stage = [&](int buf, int sidx) {
        int s = sbase + sidx;
        int sq = s / 29, qi = s - sq * 29;
        int ky = sq / 7, kx = sq - ky * 7;
        int aoff = (ky * 30 + kx) * 960 + qi * 32;
        int boff = sq * 928 + qi * 32;
        #pragma unroll
        for (int i = 0; i < 2; ++i) {
            gl16(corr + aga[i] + aoff, &As[buf][(w * 2 + i) * 512]);
            gl16(Wt + bga[i] + boff, &Bs[buf][(w * 2 + i) * 512]);
        }
    };
    stage(0, 0); stage(1, 1);
    int cur = 0, pre = 2;
    for (int s = 0; s < scount; ++s) {
        if (s + 1 < scount) { PIPE_WAIT(4) } else { PIPE_WAIT(0) }
        if (s + 2 < scount) stage(pre, s + 2);
        bf16x8 af[4], bfv[4];
        #pragma unroll
        for (int i = 0; i < 4; ++i) af[i] = *(const bf16x8*)&As[cur][(wr + i * 16 + lr) * 32 + lk];
        #pragma unroll
        for (int j = 0; j < 4; ++j) bfv[j] = *(const bf16x8*)&Bs[cur][(wc + j * 16 + lr) * 32 + lk];
        #pragma unroll
        for (int i = 0; i < 4; ++i)
            #pragma unroll
            for (int j = 0; j < 4; ++j)
                acc[i][j] = __builtin_amdgcn_mfma_f32_16x16x32_bf16(af[i], bfv[j], acc[i][j], 0, 0, 0);
        pre = cur; cur = (cur == 2) ? 0 : cur + 1;
    }
    unsigned short* pb = part + ((size_t)ks * 9216 + m0) * 128;
    #pragma unroll
    for (int i = 0; i < 4; ++i)
        #pragma unroll
        for (int r = 0; r < 4; ++r) {
            int row = wr + i * 16 + (l >> 4) * 4 + r;
            #pragma unroll
            for (int j = 0; j < 4; ++j)
                pb[(size_t)row * 128 + wc + j * 16 + lr] = f2h(acc[i][j][r]);
        }
}

// ======================= reduce 14 fp16 partials + bias + relu + BN -> bf16 ==
__global__ __launch_bounds__(256) void k_r1fin(
        const unsigned short* __restrict__ part, const float* __restrict__ cb1,
        const float* __restrict__ g1, const float* __restrict__ be1,
        const float* __restrict__ m1, const float* __restrict__ v1,
        unsigned short* __restrict__ r1) {
    const int idx = blockIdx.x * 256 + threadIdx.x;        // grid 1152
    const size_t base = (size_t)idx * 4;
    const size_t N = 9216 * 128;
    float s0 = 0.f, s1 = 0.f, s2 = 0.f, s3 = 0.f;
    #pragma unroll
    for (int i = 0; i < 14; ++i) {
        ushort4 u = *(const ushort4*)(part + i * N + base);
        s0 += h2f(u.x); s1 += h2f(u.y); s2 += h2f(u.z); s3 += h2f(u.w);
    }
    const int co = (int)(base & 127);
    float r[4] = {s0, s1, s2, s3};
    ushort4 o;
    unsigned short* op = (unsigned short*)&o;
    #pragma unroll
    for (int j = 0; j < 4; ++j) {
        int c = co + j;
        float x = fmaxf(r[j] + cb1[c], 0.f);
        x = (x - m1[c]) * (g1[c] / sqrtf(v1[c] + BN_EPSF)) + be1[c];
        op[j] = f2bf(x);
    }
    *(ushort4*)(r1 + base) = o;
}

// ======================= cw2 MFMA: M=6400 N=64 K=3200 (3-buf), bias+relu+BN ==
__global__ __launch_bounds__(256) void k_cw2(
        const unsigned short* __restrict__ r1, const unsigned short* __restrict__ Wt2,
        const float* __restrict__ cb2, const float* __restrict__ g2,
        const float* __restrict__ be2, const float* __restrict__ m2,
        const float* __restrict__ v2, float* __restrict__ r2) {
    __shared__ __align__(16) unsigned short As[3][64 * 32];
    __shared__ __align__(16) unsigned short Bs[3][64 * 32];
    const int t = threadIdx.x, w = t >> 6, l = t & 63;
    const int m0 = blockIdx.x * 64;                        // grid 100
    const int ko = (l & 3) * 8;
    const int wi = w & 1;
    size_t ga[2];
    #pragma unroll
    for (int i = 0; i < 2; ++i) {
        int r = (wi * 2 + i) * 16 + (l >> 2);
        if (w < 2) {
            int m = m0 + r;
            int b = m / 400, rem = m - b * 400, oy = rem / 20, ox = rem - oy * 20;
            ga[i] = (size_t)((b * 24 + oy) * 24 + ox) * 128 + ko;
        } else {
            ga[i] = (size_t)r * 3200 + ko;
        }
    }
    const int wr = (w >> 1) * 32, wc = (w & 1) * 32, lr = l & 15, lk = (l >> 4) * 8;
    f32x4 acc[2][2] = {};
    auto stage = [&](int buf, int s) {
        int kyx = s >> 2, h = s & 3;
        int ky = kyx / 5, kx = kyx - ky * 5;
        int aoff = (ky * 24 + kx) * 128 + h * 32;
        int boff = s * 32;
        #pragma unroll
        for (int i = 0; i < 2; ++i) {
            unsigned short* dst = (w < 2) ? &As[buf][(wi * 2 + i) * 512]
                                          : &Bs[buf][(wi * 2 + i) * 512];
            const unsigned short* src = (w < 2) ? r1 + ga[i] + aoff : Wt2 + ga[i] + boff;
            gl16(src, dst);
        }
    };
    stage(0, 0); stage(1, 1);
    int cur = 0, pre = 2;
    for (int s = 0; s < 100; ++s) {
        if (s + 1 < 100) { PIPE_WAIT(2) } else { PIPE_WAIT(0) }
        if (s + 2 < 100) stage(pre, s + 2);
        bf16x8 af[2], bfv[2];
        #pragma unroll
        for (int i = 0; i < 2; ++i) af[i] = *(const bf16x8*)&As[cur][(wr + i * 16 + lr) * 32 + lk];
        #pragma unroll
        for (int j = 0; j < 2; ++j) bfv[j] = *(const bf16x8*)&Bs[cur][(wc + j * 16 + lr) * 32 + lk];
        #pragma unroll
        for (int i = 0; i < 2; ++i)
            #pragma unroll
            for (int j = 0; j < 2; ++j)
                acc[i][j] = __builtin_amdgcn_mfma_f32_16x16x32_bf16(af[i], bfv[j], acc[i][j], 0, 0, 0);
        pre = cur; cur = (cur == 2) ? 0 : cur + 1;
    }
    float sc[2], sh[2], bias[2];
    #pragma unroll
    for (int j = 0; j < 2; ++j) {
        int co = wc + j * 16 + lr;
        sc[j] = g2[co] / sqrtf(v2[co] + BN_EPSF);
        sh[j] = be2[co] - m2[co] * sc[j];
        bias[j] = cb2[co];
    }
    #pragma unroll
    for (int i = 0; i < 2; ++i)
        #pragma unroll
        for (int r = 0; r < 4; ++r) {
            int m = m0 + wr + i * 16 + (l >> 4) * 4 + r;
            #pragma unroll
            for (int j = 0; j < 2; ++j) {
                float s = fmaxf(acc[i][j][r] + bias[j], 0.f);
                r2[(size_t)m * 64 + wc + j * 16 + lr] = s * sc[j] + sh[j];
            }
        }
}

// ======================= dense: K-split partials + finalize ==================
__global__ __launch_bounds__(256) void k_dense(
        const float* __restrict__ r2, const float* __restrict__ dw,
        float* __restrict__ partD) {
    const int b = blockIdx.x, kb = blockIdx.y, t = threadIdx.x;  // (16,5)
    const float* x = r2 + (size_t)b * 25600 + kb * 5120;
    const float* dwp = dw + (size_t)(kb * 5120) * 18;
    float s[18] = {};
    for (int k = t; k < 5120; k += 256) {
        const float xv = x[k];
        const float* dr = dwp + (size_t)k * 18;
        #pragma unroll
        for (int j = 0; j < 18; ++j) s[j] = fmaf(xv, dr[j], s[j]);
    }
    #pragma unroll
    for (int j = 0; j < 18; ++j)
        #pragma unroll
        for (int m = 1; m < 64; m <<= 1) s[j] += __shfl_xor(s[j], m);
    __shared__ float red[4][18];
    if ((t & 63) == 0) {
        #pragma unroll
        for (int j = 0; j < 18; ++j) red[t >> 6][j] = s[j];
    }
    __syncthreads();
    if (t < 18) partD[(b * 5 + kb) * 18 + t] = red[0][t] + red[1][t] + red[2][t] + red[3][t];
}
__global__ __launch_bounds__(288) void k_dfin(
        const float* __restrict__ partD, const float* __restrict__ db,
        float* __restrict__ out) {
    const int i = threadIdx.x;                 // 288
    const int b = i / 18, j = i - b * 18;
    float s = db[j];
    #pragma unroll
    for (int k = 0; k < 5; ++k) s += partD[(b * 5 + k) * 18 + j];
    out[i] = s;
}

extern "C" void kernel_launch(void* const* d_in, const int* in_sizes, int n_in,
                              void* d_out, int out_size, void* d_ws, size_t ws_size,
                              hipStream_t stream) {
    const float* imgA = (const float*)d_in[0];
    const float* imgB = (const float*)d_in[1];
    const float* w1  = (const float*)d_in[2];
    const float* b1  = (const float*)d_in[3];
    const float* w2  = (const float*)d_in[4];
    const float* b2  = (const float*)d_in[5];
    const float* w3  = (const float*)d_in[6];
    const float* b3  = (const float*)d_in[7];
    const float* cw1 = (const float*)d_in[8];
    const float* cb1 = (const float*)d_in[9];
    const float* g1  = (const float*)d_in[10];
    const float* be1 = (const float*)d_in[11];
    const float* m1  = (const float*)d_in[12];
    const float* v1  = (const float*)d_in[13];
    const float* cw2 = (const float*)d_in[14];
    const float* cb2 = (const float*)d_in[15];
    const float* g2  = (const float*)d_in[16];
    const float* be2 = (const float*)d_in[17];
    const float* m2  = (const float*)d_in[18];
    const float* v2  = (const float*)d_in[19];
    const float* dw  = (const float*)d_in[20];
    const float* db  = (const float*)d_in[21];

    // ws layout (bytes), max end = 76,931,072
    //  conv phase : c1@0 (30.0MB,16img) c2@29,984,768 (15.2MB) w2t@45,225,984
    //               w3t@45,373,440  feat@45,963,264 (15.7MB)
    //  corr phase : corr@0 (29.5MB, c1 dead)  Wt@29,491,200 (11.6MB, c2 dead)
    //  cw1 phase  : part@41,132,032 (33.0MB fp16x14, feat/w2t/w3t dead)
    //  tail       : r1@74,162,176 (2.4MB)  Wt2@76,521,472  r2@41,132,032 (part dead)
    //               partD@42,770,432
    char* ws = (char*)d_ws;
    unsigned short* c1   = (unsigned short*)(ws + 0);
    unsigned short* c2   = (unsigned short*)(ws + 29984768);
    unsigned short* w2t  = (unsigned short*)(ws + 45225984);
    unsigned short* w3t  = (unsigned short*)(ws + 45373440);
    unsigned short* feat = (unsigned short*)(ws + 45963264);
    unsigned short* corr = (unsigned short*)(ws + 0);
    unsigned short* Wt   = (unsigned short*)(ws + 29491200);
    unsigned short* part = (unsigned short*)(ws + 41132032);
    unsigned short* r1   = (unsigned short*)(ws + 74162176);
    unsigned short* Wt2  = (unsigned short*)(ws + 76521472);
    float*          r2   = (float*)(ws + 41132032);
    float*          partD= (float*)(ws + 42770432);

    k_w2t<<<dim3(288), 256, 0, stream>>>(w2, w2t);
    k_w3t<<<dim3(1152), 256, 0, stream>>>(w3, w3t);

    for (int chunk = 0; chunk < 2; ++chunk) {
        const float* img = chunk ? imgB : imgA;
        const int f0 = chunk * 16;
        k_conv1<<<dim3(30, 120, 16), 256, 0, stream>>>(img, w1, b1, c1);
        k_conv2<<<dim3(450),         256, 0, stream>>>(c1, w2t, b2, c2);
        k_conv3<<<dim3(113, 4),      256, 0, stream>>>(c2, w3t, b3, feat, f0);
    }
    k_l2norm  <<<dim3(7680),       256, 0, stream>>>(feat);
    k_corr    <<<dim3(15, 15, 16), 256, 0, stream>>>(feat, corr);
    k_corrnorm<<<dim3(14400),      256, 0, stream>>>(corr);
    k_wt1     <<<dim3(29, 49),     256, 0, stream>>>(cw1, Wt);
    k_cw1     <<<dim3(72, 14),     256, 0, stream>>>(corr, Wt, part);
    k_r1fin   <<<dim3(1152),       256, 0, stream>>>(part, cb1, g1, be1, m1, v1, r1);
    k_wt2     <<<dim3(800),        256, 0, stream>>>(cw2, Wt2);
    k_cw2     <<<dim3(100),        256, 0, stream>>>(r1, Wt2, cb2, g2, be2, m2, v2, r2);
    k_dense   <<<dim3(16, 5),      256, 0, stream>>>(r2, dw, partD);
    k_dfin    <<<dim3(1),          288, 0, stream>>>(partD, db, (float*)d_out);
}

// Round 6
// 566.680 us; speedup vs baseline: 11.8206x; 1.0393x over previous
//
#include <hip/hip_runtime.h>

#define EPSF    1e-6f
#define BN_EPSF 1e-3f

typedef __attribute__((ext_vector_type(8))) short bf16x8;   // 8 bf16 in 4 VGPRs
typedef __attribute__((ext_vector_type(4))) float f32x4;

__device__ __forceinline__ unsigned short f2bf(float f) {
    unsigned int u = __builtin_bit_cast(unsigned int, f);
    u = (u + 0x7FFFu + ((u >> 16) & 1u)) >> 16;            // RNE
    return (unsigned short)u;
}
__device__ __forceinline__ float bf2f(unsigned short h) {
    unsigned int u = ((unsigned int)h) << 16;
    return __builtin_bit_cast(float, u);
}
__device__ __forceinline__ unsigned short f2h(float f) {
    return __builtin_bit_cast(unsigned short, (_Float16)f);
}
__device__ __forceinline__ float h2f(unsigned short h) {
    return (float)__builtin_bit_cast(_Float16, h);
}
// async global->LDS, 16 bytes per lane; lds dest is wave-uniform base + lane*16
__device__ __forceinline__ void gl16(const void* g, void* l) {
    __builtin_amdgcn_global_load_lds((const __attribute__((address_space(1))) void*)g,
                                     (__attribute__((address_space(3))) void*)l, 16, 0, 0);
}
// counted-vmcnt barrier pair: wait own stage-N-ago loads, then block barrier
#define PIPE_WAIT(N)                                        \
    asm volatile("s_waitcnt vmcnt(" #N ")" ::: "memory");   \
    __builtin_amdgcn_sched_barrier(0);                      \
    __builtin_amdgcn_s_barrier();                           \
    __builtin_amdgcn_sched_barrier(0);

// ======================= merged weight conversions (w2t | w3t | wt2) =========
__global__ __launch_bounds__(256) void k_wx(
        const float* __restrict__ w2, const float* __restrict__ w3,
        const float* __restrict__ cw2w,
        unsigned short* __restrict__ w2t, unsigned short* __restrict__ w3t,
        unsigned short* __restrict__ wt2) {
    const int bid = blockIdx.x;                            // 2240
    if (bid < 288) {
        int idx = bid * 256 + threadIdx.x;                 // 73728
        int n = idx / 576, k = idx - n * 576;
        w2t[idx] = f2bf(w2[(size_t)k * 128 + n]);
    } else if (bid < 1440) {
        int idx = (bid - 288) * 256 + threadIdx.x;         // 294912
        int n = idx / 1152, k = idx - n * 1152;
        w3t[idx] = f2bf(w3[(size_t)k * 256 + n]);
    } else {
        int idx = (bid - 1440) * 256 + threadIdx.x;        // 204800
        int n = idx / 3200, k = idx - n * 3200;
        wt2[idx] = f2bf(cw2w[(size_t)k * 64 + n]);
    }
}
// Wt[n][k'], k'=s*928+q, zero for q>=900; coalesced LDS transpose. grid (29,49)
__global__ __launch_bounds__(256) void k_wt1(const float* __restrict__ W,
                                             unsigned short* __restrict__ Wt) {
    __shared__ float tile[32][132];
    const int s = blockIdx.y;              // 49
    const int q0 = blockIdx.x * 32;        // 0..896
    const int t = threadIdx.x;
    const int n = t & 127, rr = t >> 7;
    #pragma unroll
    for (int r = rr; r < 32; r += 2) {
        int q = q0 + r;
        tile[r][n] = (q < 900) ? W[((size_t)(s * 900 + q)) * 128 + n] : 0.f;
    }
    __syncthreads();
    const int n2 = t >> 1, half = t & 1;
    unsigned short* dst = Wt + (size_t)n2 * 45472 + s * 928 + q0 + half * 16;
    #pragma unroll
    for (int u = 0; u < 16; ++u) dst[u] = f2bf(tile[half * 16 + u][n2]);
}

// ======================= conv1 (fp32 in -> bf16 padded out, border fused) ====
__global__ __launch_bounds__(256) void k_conv1(
        const float* __restrict__ img,
        const float* __restrict__ w, const float* __restrict__ bias,
        unsigned short* __restrict__ c1) {
    const int co = threadIdx.x & 63, u = threadIdx.x >> 6;
    const int ox = blockIdx.x * 4 + u;                     // 120
    const int oy = blockIdx.y;                             // 120
    const int b = blockIdx.z;                              // 16
    float acc = bias[co];
    #pragma unroll
    for (int ky = 0; ky < 3; ++ky) {
        const int iy = 2 * oy + ky;
        if (iy >= 240) continue;
        #pragma unroll
        for (int kx = 0; kx < 3; ++kx) {
            const int ix = 2 * ox + kx;
            if (ix >= 240) continue;
            const float* ip = img + ((size_t)(b * 240 + iy) * 240 + ix) * 3;
            const float* wp = w + ((ky * 3 + kx) * 3) * 64 + co;
            acc = fmaf(ip[0], wp[0], acc);
            acc = fmaf(ip[1], wp[64], acc);
            acc = fmaf(ip[2], wp[128], acc);
        }
    }
    c1[((size_t)(b * 121 + oy) * 121 + ox) * 64 + co] = f2bf(fmaxf(acc, 0.f));
    const bool bx = (ox == 119), by = (oy == 119);
    if (bx) c1[((size_t)(b * 121 + oy) * 121 + 120) * 64 + co] = 0;
    if (by) c1[((size_t)(b * 121 + 120) * 121 + ox) * 64 + co] = 0;
    if (bx && by) c1[((size_t)(b * 121 + 120) * 121 + 120) * 64 + co] = 0;
}

// ======================= conv2 MFMA: M=57600 N=128 K=576 (3-buf pipeline) ====
__global__ __launch_bounds__(256) void k_conv2(
        const unsigned short* __restrict__ c1, const unsigned short* __restrict__ w2t,
        const float* __restrict__ b2, unsigned short* __restrict__ c2) {
    __shared__ __align__(16) unsigned short As[3][128 * 32];
    __shared__ __align__(16) unsigned short Bs[3][128 * 32];
    const int t = threadIdx.x, w = t >> 6, l = t & 63;
    const int m0 = blockIdx.x * 128;                       // grid 450
    const int ko = (l & 3) * 8;
    size_t aga[2], bga[2];
    #pragma unroll
    for (int i = 0; i < 2; ++i) {
        int r = (w * 2 + i) * 16 + (l >> 2);
        int m = m0 + r;
        int bl = m / 3600, rem = m - bl * 3600, oy = rem / 60, ox = rem - oy * 60;
        aga[i] = (size_t)((bl * 121 + 2 * oy) * 121 + 2 * ox) * 64 + ko;
        bga[i] = (size_t)r * 576 + ko;
    }
    const int wr = (w >> 1) * 64, wc = (w & 1) * 64, lr = l & 15, lk = (l >> 4) * 8;
    f32x4 acc[4][4] = {};
    auto stage = [&](int buf, int s) {
        int ky = s / 6, r6 = s - ky * 6, kx = r6 >> 1, h = r6 & 1;
        int aoff = (ky * 121 + kx) * 64 + h * 32;
        int boff = (ky * 3 + kx) * 64 + h * 32;
        #pragma unroll
        for (int i = 0; i < 2; ++i) {
            gl16(c1 + aga[i] + aoff, &As[buf][(w * 2 + i) * 512]);
            gl16(w2t + bga[i] + boff, &Bs[buf][(w * 2 + i) * 512]);
        }
    };
    stage(0, 0); stage(1, 1);
    int cur = 0, pre = 2;
    for (int s = 0; s < 18; ++s) {
        if (s + 1 < 18) { PIPE_WAIT(4) } else { PIPE_WAIT(0) }
        if (s + 2 < 18) stage(pre, s + 2);
        bf16x8 af[4], bfv[4];
        #pragma unroll
        for (int i = 0; i < 4; ++i) af[i] = *(const bf16x8*)&As[cur][(wr + i * 16 + lr) * 32 + lk];
        #pragma unroll
        for (int j = 0; j < 4; ++j) bfv[j] = *(const bf16x8*)&Bs[cur][(wc + j * 16 + lr) * 32 + lk];
        #pragma unroll
        for (int i = 0; i < 4; ++i)
            #pragma unroll
            for (int j = 0; j < 4; ++j)
                acc[i][j] = __builtin_amdgcn_mfma_f32_16x16x32_bf16(af[i], bfv[j], acc[i][j], 0, 0, 0);
        pre = cur; cur = (cur == 2) ? 0 : cur + 1;
    }
    float bias[4];
    #pragma unroll
    for (int j = 0; j < 4; ++j) bias[j] = b2[wc + j * 16 + lr];
    #pragma unroll
    for (int i = 0; i < 4; ++i)
        #pragma unroll
        for (int r = 0; r < 4; ++r) {
            int m = m0 + wr + i * 16 + (l >> 4) * 4 + r;
            int bl = m / 3600, rem = m - bl * 3600, oy = rem / 60, ox = rem - oy * 60;
            size_t ob = (size_t)((bl * 61 + oy) * 61 + ox) * 128;
            #pragma unroll
            for (int j = 0; j < 4; ++j)
                c2[ob + wc + j * 16 + lr] = f2bf(fmaxf(acc[i][j][r] + bias[j], 0.f));
            const bool bx = (ox == 59), by = (oy == 59);
            if (bx) {
                size_t zb = (size_t)((bl * 61 + oy) * 61 + 60) * 128;
                #pragma unroll
                for (int j = 0; j < 4; ++j) c2[zb + wc + j * 16 + lr] = 0;
            }
            if (by) {
                size_t zb = (size_t)((bl * 61 + 60) * 61 + ox) * 128;
                #pragma unroll
                for (int j = 0; j < 4; ++j) c2[zb + wc + j * 16 + lr] = 0;
            }
            if (bx && by) {
                size_t zb = (size_t)((bl * 61 + 60) * 61 + 60) * 128;
                #pragma unroll
                for (int j = 0; j < 4; ++j) c2[zb + wc + j * 16 + lr] = 0;
            }
        }
}

// ======================= conv3 MFMA: M=14400 N=256 K=1152 (3-buf) ============
// feat padded to [32][1024][256]
__global__ __launch_bounds__(256) void k_conv3(
        const unsigned short* __restrict__ c2, const unsigned short* __restrict__ w3t,
        const float* __restrict__ b3, unsigned short* __restrict__ feat, int f0) {
    __shared__ __align__(16) unsigned short As[3][128 * 32];
    __shared__ __align__(16) unsigned short Bs[3][64 * 32];
    const int t = threadIdx.x, w = t >> 6, l = t & 63;
    const int m0 = blockIdx.x * 128, n0 = blockIdx.y * 64;   // grid (113,4)
    const int ko = (l & 3) * 8;
    size_t aga[2], bga;
    #pragma unroll
    for (int i = 0; i < 2; ++i) {
        int r = (w * 2 + i) * 16 + (l >> 2);
        int m = min(m0 + r, 14399);
        int bl = m / 900, rem = m - bl * 900, oy = rem / 30, ox = rem - oy * 30;
        aga[i] = (size_t)((bl * 61 + 2 * oy) * 61 + 2 * ox) * 128 + ko;
    }
    { int n = n0 + w * 16 + (l >> 2); bga = (size_t)n * 1152 + ko; }
    const int wr = (w >> 1) * 64, wc = (w & 1) * 32, lr = l & 15, lk = (l >> 4) * 8;
    f32x4 acc[4][2] = {};
    auto stage = [&](int buf, int s) {
        int ky = s / 12, r12 = s - ky * 12, kx = r12 >> 2, h = r12 & 3;
        int aoff = (ky * 61 + kx) * 128 + h * 32;
        int boff = (ky * 3 + kx) * 128 + h * 32;
        #pragma unroll
        for (int i = 0; i < 2; ++i)
            gl16(c2 + aga[i] + aoff, &As[buf][(w * 2 + i) * 512]);
        gl16(w3t + bga + boff, &Bs[buf][w * 512]);
    };
    stage(0, 0); stage(1, 1);
    int cur = 0, pre = 2;
    for (int s = 0; s < 36; ++s) {
        if (s + 1 < 36) { PIPE_WAIT(3) } else { PIPE_WAIT(0) }
        if (s + 2 < 36) stage(pre, s + 2);
        bf16x8 af[4], bfv[2];
        #pragma unroll
        for (int i = 0; i < 4; ++i) af[i] = *(const bf16x8*)&As[cur][(wr + i * 16 + lr) * 32 + lk];
        #pragma unroll
        for (int j = 0; j < 2; ++j) bfv[j] = *(const bf16x8*)&Bs[cur][(wc + j * 16 + lr) * 32 + lk];
        #pragma unroll
        for (int i = 0; i < 4; ++i)
            #pragma unroll
            for (int j = 0; j < 2; ++j)
                acc[i][j] = __builtin_amdgcn_mfma_f32_16x16x32_bf16(af[i], bfv[j], acc[i][j], 0, 0, 0);
        pre = cur; cur = (cur == 2) ? 0 : cur + 1;
    }
    float bias[2];
    #pragma unroll
    for (int j = 0; j < 2; ++j) bias[j] = b3[n0 + wc + j * 16 + lr];
    #pragma unroll
    for (int i = 0; i < 4; ++i)
        #pragma unroll
        for (int r = 0; r < 4; ++r) {
            int m = m0 + wr + i * 16 + (l >> 4) * 4 + r;
            if (m < 14400) {
                int bl = m / 900, pos = m - bl * 900;
                size_t ob = ((size_t)(f0 + bl) * 1024 + pos) * 256;
                #pragma unroll
                for (int j = 0; j < 2; ++j)
                    feat[ob + n0 + wc + j * 16 + lr] = f2bf(fmaxf(acc[i][j][r] + bias[j], 0.f));
            }
        }
}

// ======================= l2norm: wave per row, rows 900..1023 zeroed =========
__global__ __launch_bounds__(256) void k_l2norm(unsigned short* __restrict__ feat) {
    const int t = threadIdx.x, wv = t >> 6, ln = t & 63;
    const int R = blockIdx.x * 4 + wv;             // 32768 rows, grid 8192
    const int pos = R & 1023;
    ushort4* fp4 = (ushort4*)(feat + (size_t)R * 256);
    if (pos >= 900) { fp4[ln] = make_ushort4(0, 0, 0, 0); return; }
    ushort4 u = fp4[ln];
    float x0 = bf2f(u.x), x1 = bf2f(u.y), x2 = bf2f(u.z), x3 = bf2f(u.w);
    float s = x0 * x0 + x1 * x1 + x2 * x2 + x3 * x3;
    #pragma unroll
    for (int m = 1; m < 64; m <<= 1) s += __shfl_xor(s, m);
    const float inv = 1.f / sqrtf(s + EPSF);
    u.x = f2bf(x0 * inv); u.y = f2bf(x1 * inv);
    u.z = f2bf(x2 * inv); u.w = f2bf(x3 * inv);
    fp4[ln] = u;
}

// ======================= corr MFMA: per-b 1024x1024 padded, 128-tile =========
// grid 1024 flat, XCD-swizzled; guarded stores into corr[16][960][960]
__global__ __launch_bounds__(256) void k_corr(
        const unsigned short* __restrict__ feat, unsigned short* __restrict__ corr) {
    __shared__ __align__(16) unsigned short As[3][128 * 32];
    __shared__ __align__(16) unsigned short Bs[3][128 * 32];
    const int t = threadIdx.x, w = t >> 6, l = t & 63;
    const int id0 = blockIdx.x;                            // 1024
    const int sw = (id0 & 7) * 128 + (id0 >> 3);           // bijective XCD swizzle
    const int b = sw >> 6, rem = sw & 63;
    const int p0 = (rem >> 3) * 128, q0 = (rem & 7) * 128;
    const int ko = (l & 3) * 8;
    const unsigned short* fA = feat + (size_t)b * 1024 * 256;
    const unsigned short* fB = feat + (size_t)(16 + b) * 1024 * 256;
    size_t aga[2], bga[2];
    #pragma unroll
    for (int i = 0; i < 2; ++i) {
        int r = (w * 2 + i) * 16 + (l >> 2);
        aga[i] = (size_t)(p0 + r) * 256 + ko;
        bga[i] = (size_t)(q0 + r) * 256 + ko;
    }
    const int wr = (w >> 1) * 64, wc = (w & 1) * 64, lr = l & 15, lk = (l >> 4) * 8;
    f32x4 acc[4][4] = {};
    auto stage = [&](int buf, int s) {
        #pragma unroll
        for (int i = 0; i < 2; ++i) {
            gl16(fA + aga[i] + s * 32, &As[buf][(w * 2 + i) * 512]);
            gl16(fB + bga[i] + s * 32, &Bs[buf][(w * 2 + i) * 512]);
        }
    };
    stage(0, 0); stage(1, 1);
    int cur = 0, pre = 2;
    for (int s = 0; s < 8; ++s) {
        if (s + 1 < 8) { PIPE_WAIT(4) } else { PIPE_WAIT(0) }
        if (s + 2 < 8) stage(pre, s + 2);
        bf16x8 af[4], bfv[4];
        #pragma unroll
        for (int i = 0; i < 4; ++i) af[i] = *(const bf16x8*)&As[cur][(wr + i * 16 + lr) * 32 + lk];
        #pragma unroll
        for (int j = 0; j < 4; ++j) bfv[j] = *(const bf16x8*)&Bs[cur][(wc + j * 16 + lr) * 32 + lk];
        #pragma unroll
        for (int i = 0; i < 4; ++i)
            #pragma unroll
            for (int j = 0; j < 4; ++j)
                acc[i][j] = __builtin_amdgcn_mfma_f32_16x16x32_bf16(af[i], bfv[j], acc[i][j], 0, 0, 0);
        pre = cur; cur = (cur == 2) ? 0 : cur + 1;
    }
    unsigned short* cb = corr + (size_t)b * 960 * 960;
    #pragma unroll
    for (int i = 0; i < 4; ++i)
        #pragma unroll
        for (int r = 0; r < 4; ++r) {
            int row = p0 + wr + i * 16 + (l >> 4) * 4 + r;
            if (row < 960) {
                #pragma unroll
                for (int j = 0; j < 4; ++j) {
                    int col = q0 + wc + j * 16 + lr;
                    if (col < 960)
                        cb[(size_t)row * 960 + col] = f2bf(fmaxf(acc[i][j][r], 0.f));
                }
            }
        }
}

// ======================= corr L2 norm: one wave per row ======================
__global__ __launch_bounds__(256) void k_corrnorm(unsigned short* __restrict__ corr) {
    const int t = threadIdx.x, wv = t >> 6, ln = t & 63;
    const int row = blockIdx.x * 4 + wv;       // 14400 rows, grid 3600
    const int b = row / 900, p = row - b * 900;
    ushort4* cp4 = (ushort4*)(corr + ((size_t)b * 960 + p) * 960);
    float x[16];
    float s = 0.f;
    #pragma unroll
    for (int i = 0; i < 4; ++i) {
        const int idx = ln + 64 * i;
        float v0 = 0.f, v1 = 0.f, v2 = 0.f, v3 = 0.f;
        if (idx < 225) {
            ushort4 u = cp4[idx];
            v0 = fmaxf(bf2f(u.x), 0.f); v1 = fmaxf(bf2f(u.y), 0.f);
            v2 = fmaxf(bf2f(u.z), 0.f); v3 = fmaxf(bf2f(u.w), 0.f);
        }
        x[i * 4 + 0] = v0; x[i * 4 + 1] = v1; x[i * 4 + 2] = v2; x[i * 4 + 3] = v3;
        s += v0 * v0 + v1 * v1 + v2 * v2 + v3 * v3;
    }
    #pragma unroll
    for (int m = 1; m < 64; m <<= 1) s += __shfl_xor(s, m);
    const float sc = 1.f / sqrtf(s + EPSF);
    #pragma unroll
    for (int i = 0; i < 4; ++i) {
        const int idx = ln + 64 * i;
        if (idx < 225) {
            ushort4 u;
            u.x = f2bf(x[i * 4 + 0] * sc); u.y = f2bf(x[i * 4 + 1] * sc);
            u.z = f2bf(x[i * 4 + 2] * sc); u.w = f2bf(x[i * 4 + 3] * sc);
            cp4[idx] = u;
        }
    }
}

// ======================= cw1 MFMA: M=9216 N=128, K'=49*928, split 10 =========
// grid 720 flat (single fully-resident phase), XCD-swizzled m-contiguity
__global__ __launch_bounds__(256) void k_cw1(
        const unsigned short* __restrict__ corr, const unsigned short* __restrict__ Wt,
        unsigned short* __restrict__ part) {
    __shared__ __align__(16) unsigned short As[3][128 * 32];
    __shared__ __align__(16) unsigned short Bs[3][128 * 32];
    const int t = threadIdx.x, w = t >> 6, l = t & 63;
    const int id0 = blockIdx.x;                            // 720
    const int sw = (id0 & 7) * 90 + (id0 >> 3);            // bijective XCD swizzle
    const int mt = sw % 72, ks = sw / 72;
    const int m0 = mt * 128;
    const int ko = (l & 3) * 8;
    size_t aga[2], bga[2];
    #pragma unroll
    for (int i = 0; i < 2; ++i) {
        int r = (w * 2 + i) * 16 + (l >> 2);
        int m = m0 + r;
        int b = m / 576, rem = m - b * 576, oy = rem / 24, ox = rem - oy * 24;
        aga[i] = (size_t)(b * 960 + oy * 30 + ox) * 960 + ko;
        bga[i] = (size_t)r * 45472 + ko;
    }
    // 1421 total 32-elem K-steps (49 windows x 29), split 10: ks0 gets 143
    const int sbase = ks * 142 + (ks > 0 ? 1 : 0);
    const int scount = 142 + (ks == 0 ? 1 : 0);
    const int wr = (w >> 1) * 64, wc = (w & 1) * 64, lr = l & 15, lk = (l >> 4) * 8;
    f32x4 acc[4][4] = {};
    auto stage = [&](int buf, int sidx) {
        int s = sbase + sidx;
        int sq = s / 29, qi = s - sq * 29;
        int ky = sq / 7, kx = sq - ky * 7;
        int aoff = (ky * 30 + kx) * 960 + qi * 32;
        int boff = sq * 928 + qi * 32;
        #pragma unroll
        for (int i = 0; i < 2; ++i) {
            gl16(corr + aga[i] + aoff, &As[buf][(w * 2 + i) * 512]);
            gl16(Wt + bga[i] + boff, &Bs[buf][(w * 2 + i) * 512]);
        }
    };
    stage(0, 0); stage(1, 1);
    int cur = 0, pre = 2;
    for (int s = 0; s < scount; ++s) {
        if (s + 1 < scount) { PIPE_WAIT(4) } else { PIPE_WAIT(0) }
        if (s + 2 < scount) stage(pre, s + 2);
        bf16x8 af[4], bfv[4];
        #pragma unroll
        for (int i = 0; i < 4; ++i) af[i] = *(const bf16x8*)&As[cur][(wr + i * 16 + lr) * 32 + lk];
        #pragma unroll
        for (int j = 0; j < 4; ++j) bfv[j] = *(const bf16x8*)&Bs[cur][(wc + j * 16 + lr) * 32 + lk];
        #pragma unroll
        for (int i = 0; i < 4; ++i)
            #pragma unroll
            for (int j = 0; j < 4; ++j)
                acc[i][j] = __builtin_amdgcn_mfma_f32_16x16x32_bf16(af[i], bfv[j], acc[i][j], 0, 0, 0);
        pre = cur; cur = (cur == 2) ? 0 : cur + 1;
    }
    unsigned short* pb = part + ((size_t)ks * 9216 + m0) * 128;
    #pragma unroll
    for (int i = 0; i < 4; ++i)
        #pragma unroll
        for (int r = 0; r < 4; ++r) {
            int row = wr + i * 16 + (l >> 4) * 4 + r;
            #pragma unroll
            for (int j = 0; j < 4; ++j)
                pb[(size_t)row * 128 + wc + j * 16 + lr] = f2h(acc[i][j][r]);
        }
}

// ======================= reduce 10 fp16 partials + bias + relu + BN -> bf16 ==
__global__ __launch_bounds__(256) void k_r1fin(
        const unsigned short* __restrict__ part, const float* __restrict__ cb1,
        const float* __restrict__ g1, const float* __restrict__ be1,
        const float* __restrict__ m1, const float* __restrict__ v1,
        unsigned short* __restrict__ r1) {
    const int idx = blockIdx.x * 256 + threadIdx.x;        // grid 1152
    const size_t base = (size_t)idx * 4;
    const size_t N = 9216 * 128;
    float s0 = 0.f, s1 = 0.f, s2 = 0.f, s3 = 0.f;
    #pragma unroll
    for (int i = 0; i < 10; ++i) {
        ushort4 u = *(const ushort4*)(part + i * N + base);
        s0 += h2f(u.x); s1 += h2f(u.y); s2 += h2f(u.z); s3 += h2f(u.w);
    }
    const int co = (int)(base & 127);
    float r[4] = {s0, s1, s2, s3};
    ushort4 o;
    unsigned short* op = (unsigned short*)&o;
    #pragma unroll
    for (int j = 0; j < 4; ++j) {
        int c = co + j;
        float x = fmaxf(r[j] + cb1[c], 0.f);
        x = (x - m1[c]) * (g1[c] / sqrtf(v1[c] + BN_EPSF)) + be1[c];
        op[j] = f2bf(x);
    }
    *(ushort4*)(r1 + base) = o;
}

// ======================= cw2 MFMA: M=6400 N=64 K=3200 (3-buf), bias+relu+BN ==
__global__ __launch_bounds__(256) void k_cw2(
        const unsigned short* __restrict__ r1, const unsigned short* __restrict__ Wt2,
        const float* __restrict__ cb2, const float* __restrict__ g2,
        const float* __restrict__ be2, const float* __restrict__ m2,
        const float* __restrict__ v2, float* __restrict__ r2) {
    __shared__ __align__(16) unsigned short As[3][64 * 32];
    __shared__ __align__(16) unsigned short Bs[3][64 * 32];
    const int t = threadIdx.x, w = t >> 6, l = t & 63;
    const int m0 = blockIdx.x * 64;                        // grid 100
    const int ko = (l & 3) * 8;
    const int wi = w & 1;
    size_t ga[2];
    #pragma unroll
    for (int i = 0; i < 2; ++i) {
        int r = (wi * 2 + i) * 16 + (l >> 2);
        if (w < 2) {
            int m = m0 + r;
            int b = m / 400, rem = m - b * 400, oy = rem / 20, ox = rem - oy * 20;
            ga[i] = (size_t)((b * 24 + oy) * 24 + ox) * 128 + ko;
        } else {
            ga[i] = (size_t)r * 3200 + ko;
        }
    }
    const int wr = (w >> 1) * 32, wc = (w & 1) * 32, lr = l & 15, lk = (l >> 4) * 8;
    f32x4 acc[2][2] = {};
    auto stage = [&](int buf, int s) {
        int kyx = s >> 2, h = s & 3;
        int ky = kyx / 5, kx = kyx - ky * 5;
        int aoff = (ky * 24 + kx) * 128 + h * 32;
        int boff = s * 32;
        #pragma unroll
        for (int i = 0; i < 2; ++i) {
            unsigned short* dst = (w < 2) ? &As[buf][(wi * 2 + i) * 512]
                                          : &Bs[buf][(wi * 2 + i) * 512];
            const unsigned short* src = (w < 2) ? r1 + ga[i] + aoff : Wt2 + ga[i] + boff;
            gl16(src, dst);
        }
    };
    stage(0, 0); stage(1, 1);
    int cur = 0, pre = 2;
    for (int s = 0; s < 100; ++s) {
        if (s + 1 < 100) { PIPE_WAIT(2) } else { PIPE_WAIT(0) }
        if (s + 2 < 100) stage(pre, s + 2);
        bf16x8 af[2], bfv[2];
        #pragma unroll
        for (int i = 0; i < 2; ++i) af[i] = *(const bf16x8*)&As[cur][(wr + i * 16 + lr) * 32 + lk];
        #pragma unroll
        for (int j = 0; j < 2; ++j) bfv[j] = *(const bf16x8*)&Bs[cur][(wc + j * 16 + lr) * 32 + lk];
        #pragma unroll
        for (int i = 0; i < 2; ++i)
            #pragma unroll
            for (int j = 0; j < 2; ++j)
                acc[i][j] = __builtin_amdgcn_mfma_f32_16x16x32_bf16(af[i], bfv[j], acc[i][j], 0, 0, 0);
        pre = cur; cur = (cur == 2) ? 0 : cur + 1;
    }
    float sc[2], sh[2], bias[2];
    #pragma unroll
    for (int j = 0; j < 2; ++j) {
        int co = wc + j * 16 + lr;
        sc[j] = g2[co] / sqrtf(v2[co] + BN_EPSF);
        sh[j] = be2[co] - m2[co] * sc[j];
        bias[j] = cb2[co];
    }
    #pragma unroll
    for (int i = 0; i < 2; ++i)
        #pragma unroll
        for (int r = 0; r < 4; ++r) {
            int m = m0 + wr + i * 16 + (l >> 4) * 4 + r;
            #pragma unroll
            for (int j = 0; j < 2; ++j) {
                float s = fmaxf(acc[i][j][r] + bias[j], 0.f);
                r2[(size_t)m * 64 + wc + j * 16 + lr] = s * sc[j] + sh[j];
            }
        }
}

// ======================= dense: K-split partials + finalize ==================
__global__ __launch_bounds__(256) void k_dense(
        const float* __restrict__ r2, const float* __restrict__ dw,
        float* __restrict__ partD) {
    const int b = blockIdx.x, kb = blockIdx.y, t = threadIdx.x;  // (16,5)
    const float* x = r2 + (size_t)b * 25600 + kb * 5120;
    const float* dwp = dw + (size_t)(kb * 5120) * 18;
    float s[18] = {};
    for (int k = t; k < 5120; k += 256) {
        const float xv = x[k];
        const float* dr = dwp + (size_t)k * 18;
        #pragma unroll
        for (int j = 0; j < 18; ++j) s[j] = fmaf(xv, dr[j], s[j]);
    }
    #pragma unroll
    for (int j = 0; j < 18; ++j)
        #pragma unroll
        for (int m = 1; m < 64; m <<= 1) s[j] += __shfl_xor(s[j], m);
    __shared__ float red[4][18];
    if ((t & 63) == 0) {
        #pragma unroll
        for (int j = 0; j < 18; ++j) red[t >> 6][j] = s[j];
    }
    __syncthreads();
    if (t < 18) partD[(b * 5 + kb) * 18 + t] = red[0][t] + red[1][t] + red[2][t] + red[3][t];
}
__global__ __launch_bounds__(288) void k_dfin(
        const float* __restrict__ partD, const float* __restrict__ db,
        float* __restrict__ out) {
    const int i = threadIdx.x;                 // 288
    const int b = i / 18, j = i - b * 18;
    float s = db[j];
    #pragma unroll
    for (int k = 0; k < 5; ++k) s += partD[(b * 5 + k) * 18 + j];
    out[i] = s;
}

extern "C" void kernel_launch(void* const* d_in, const int* in_sizes, int n_in,
                              void* d_out, int out_size, void* d_ws, size_t ws_size,
                              hipStream_t stream) {
    const float* imgA = (const float*)d_in[0];
    const float* imgB = (const float*)d_in[1];
    const float* w1  = (const float*)d_in[2];
    const float* b1  = (const float*)d_in[3];
    const float* w2  = (const float*)d_in[4];
    const float* b2  = (const float*)d_in[5];
    const float* w3  = (const float*)d_in[6];
    const float* b3  = (const float*)d_in[7];
    const float* cw1 = (const float*)d_in[8];
    const float* cb1 = (const float*)d_in[9];
    const float* g1  = (const float*)d_in[10];
    const float* be1 = (const float*)d_in[11];
    const float* m1  = (const float*)d_in[12];
    const float* v1  = (const float*)d_in[13];
    const float* cw2 = (const float*)d_in[14];
    const float* cb2 = (const float*)d_in[15];
    const float* g2  = (const float*)d_in[16];
    const float* be2 = (const float*)d_in[17];
    const float* m2  = (const float*)d_in[18];
    const float* v2  = (const float*)d_in[19];
    const float* dw  = (const float*)d_in[20];
    const float* db  = (const float*)d_in[21];

    // ws layout (bytes), max end = 76,931,072 (ws >= 81,331,200 proven in R2)
    //  conv phase : c1@0 (30.0MB) c2@29,984,768 (15.2MB) w2t@45,225,984
    //               w3t@45,373,440  feat@45,963,264 (16.8MB, [32][1024][256])
    //  corr phase : corr@0 (29.5MB, c1 dead)  Wt@29,491,200 (11.6MB, c2 dead)
    //  cw1 phase  : part@41,132,032 (23.6MB fp16x10, feat/w2t/w3t dead)
    //  tail       : r1@74,162,176 (2.4MB)  Wt2@76,521,472  r2@41,132,032
    //               partD@42,770,432
    char* ws = (char*)d_ws;
    unsigned short* c1   = (unsigned short*)(ws + 0);
    unsigned short* c2   = (unsigned short*)(ws + 29984768);
    unsigned short* w2t  = (unsigned short*)(ws + 45225984);
    unsigned short* w3t  = (unsigned short*)(ws + 45373440);
    unsigned short* feat = (unsigned short*)(ws + 45963264);
    unsigned short* corr = (unsigned short*)(ws + 0);
    unsigned short* Wt   = (unsigned short*)(ws + 29491200);
    unsigned short* part = (unsigned short*)(ws + 41132032);
    unsigned short* r1   = (unsigned short*)(ws + 74162176);
    unsigned short* Wt2  = (unsigned short*)(ws + 76521472);
    float*          r2   = (float*)(ws + 41132032);
    float*          partD= (float*)(ws + 42770432);

    k_wx<<<dim3(2240), 256, 0, stream>>>(w2, w3, cw2, w2t, w3t, Wt2);

    for (int chunk = 0; chunk < 2; ++chunk) {
        const float* img = chunk ? imgB : imgA;
        const int f0 = chunk * 16;
        k_conv1<<<dim3(30, 120, 16), 256, 0, stream>>>(img, w1, b1, c1);
        k_conv2<<<dim3(450),         256, 0, stream>>>(c1, w2t, b2, c2);
        k_conv3<<<dim3(113, 4),      256, 0, stream>>>(c2, w3t, b3, feat, f0);
    }
    k_l2norm  <<<dim3(8192),  256, 0, stream>>>(feat);
    k_corr    <<<dim3(1024),  256, 0, stream>>>(feat, corr);
    k_corrnorm<<<dim3(3600),  256, 0, stream>>>(corr);
    k_wt1     <<<dim3(29, 49),256, 0, stream>>>(cw1, Wt);
    k_cw1     <<<dim3(720),   256, 0, stream>>>(corr, Wt, part);
    k_r1fin   <<<dim3(1152),  256, 0, stream>>>(part, cb1, g1, be1, m1, v1, r1);
    k_cw2     <<<dim3(100),   256, 0, stream>>>(r1, Wt2, cb2, g2, be2, m2, v2, r2);
    k_dense   <<<dim3(16, 5), 256, 0, stream>>>(r2, dw, partD);
    k_dfin    <<<dim3(1),     288, 0, stream>>>(partD, db, (float*)d_out);
}

// Round 7
// 562.786 us; speedup vs baseline: 11.9024x; 1.0069x over previous
//
#include <hip/hip_runtime.h>

#define EPSF    1e-6f
#define BN_EPSF 1e-3f

typedef __attribute__((ext_vector_type(8))) short bf16x8;   // 8 bf16 in 4 VGPRs
typedef __attribute__((ext_vector_type(4))) float f32x4;

__device__ __forceinline__ unsigned short f2bf(float f) {
    unsigned int u = __builtin_bit_cast(unsigned int, f);
    u = (u + 0x7FFFu + ((u >> 16) & 1u)) >> 16;            // RNE
    return (unsigned short)u;
}
__device__ __forceinline__ float bf2f(unsigned short h) {
    unsigned int u = ((unsigned int)h) << 16;
    return __builtin_bit_cast(float, u);
}
__device__ __forceinline__ unsigned short f2h(float f) {
    return __builtin_bit_cast(unsigned short, (_Float16)f);
}
__device__ __forceinline__ float h2f(unsigned short h) {
    return (float)__builtin_bit_cast(_Float16, h);
}
// async global->LDS, 16 bytes per lane; lds dest is wave-uniform base + lane*16
__device__ __forceinline__ void gl16(const void* g, void* l) {
    __builtin_amdgcn_global_load_lds((const __attribute__((address_space(1))) void*)g,
                                     (__attribute__((address_space(3))) void*)l, 16, 0, 0);
}
// counted-vmcnt barrier pair: wait own stage-N-ago loads, then block barrier
#define PIPE_WAIT(N)                                        \
    asm volatile("s_waitcnt vmcnt(" #N ")" ::: "memory");   \
    __builtin_amdgcn_sched_barrier(0);                      \
    __builtin_amdgcn_s_barrier();                           \
    __builtin_amdgcn_sched_barrier(0);

// ======================= merged weight conversions (w2t | w3t | wt2) =========
__global__ __launch_bounds__(256) void k_wx(
        const float* __restrict__ w2, const float* __restrict__ w3,
        const float* __restrict__ cw2w,
        unsigned short* __restrict__ w2t, unsigned short* __restrict__ w3t,
        unsigned short* __restrict__ wt2) {
    const int bid = blockIdx.x;                            // 2240
    if (bid < 288) {
        int idx = bid * 256 + threadIdx.x;                 // 73728
        int n = idx / 576, k = idx - n * 576;
        w2t[idx] = f2bf(w2[(size_t)k * 128 + n]);
    } else if (bid < 1440) {
        int idx = (bid - 288) * 256 + threadIdx.x;         // 294912
        int n = idx / 1152, k = idx - n * 1152;
        w3t[idx] = f2bf(w3[(size_t)k * 256 + n]);
    } else {
        int idx = (bid - 1440) * 256 + threadIdx.x;        // 204800
        int n = idx / 3200, k = idx - n * 3200;
        wt2[idx] = f2bf(cw2w[(size_t)k * 64 + n]);
    }
}
// Wt[n][k'], k'=s*928+q, zero for q>=900; coalesced LDS transpose. grid (29,49)
__global__ __launch_bounds__(256) void k_wt1(const float* __restrict__ W,
                                             unsigned short* __restrict__ Wt) {
    __shared__ float tile[32][132];
    const int s = blockIdx.y;              // 49
    const int q0 = blockIdx.x * 32;        // 0..896
    const int t = threadIdx.x;
    const int n = t & 127, rr = t >> 7;
    #pragma unroll
    for (int r = rr; r < 32; r += 2) {
        int q = q0 + r;
        tile[r][n] = (q < 900) ? W[((size_t)(s * 900 + q)) * 128 + n] : 0.f;
    }
    __syncthreads();
    const int n2 = t >> 1, half = t & 1;
    unsigned short* dst = Wt + (size_t)n2 * 45472 + s * 928 + q0 + half * 16;
    #pragma unroll
    for (int u = 0; u < 16; ++u) dst[u] = f2bf(tile[half * 16 + u][n2]);
}

// ======================= conv1 (fp32 in -> bf16 padded out, border fused) ====
__global__ __launch_bounds__(256) void k_conv1(
        const float* __restrict__ img,
        const float* __restrict__ w, const float* __restrict__ bias,
        unsigned short* __restrict__ c1) {
    const int co = threadIdx.x & 63, u = threadIdx.x >> 6;
    const int ox = blockIdx.x * 4 + u;                     // 120
    const int oy = blockIdx.y;                             // 120
    const int b = blockIdx.z;                              // 16
    float acc = bias[co];
    #pragma unroll
    for (int ky = 0; ky < 3; ++ky) {
        const int iy = 2 * oy + ky;
        if (iy >= 240) continue;
        #pragma unroll
        for (int kx = 0; kx < 3; ++kx) {
            const int ix = 2 * ox + kx;
            if (ix >= 240) continue;
            const float* ip = img + ((size_t)(b * 240 + iy) * 240 + ix) * 3;
            const float* wp = w + ((ky * 3 + kx) * 3) * 64 + co;
            acc = fmaf(ip[0], wp[0], acc);
            acc = fmaf(ip[1], wp[64], acc);
            acc = fmaf(ip[2], wp[128], acc);
        }
    }
    c1[((size_t)(b * 121 + oy) * 121 + ox) * 64 + co] = f2bf(fmaxf(acc, 0.f));
    const bool bx = (ox == 119), by = (oy == 119);
    if (bx) c1[((size_t)(b * 121 + oy) * 121 + 120) * 64 + co] = 0;
    if (by) c1[((size_t)(b * 121 + 120) * 121 + ox) * 64 + co] = 0;
    if (bx && by) c1[((size_t)(b * 121 + 120) * 121 + 120) * 64 + co] = 0;
}

// ======================= conv2 MFMA: M=57600 N=128 K=576 (3-buf pipeline) ====
__global__ __launch_bounds__(256) void k_conv2(
        const unsigned short* __restrict__ c1, const unsigned short* __restrict__ w2t,
        const float* __restrict__ b2, unsigned short* __restrict__ c2) {
    __shared__ __align__(16) unsigned short As[3][128 * 32];
    __shared__ __align__(16) unsigned short Bs[3][128 * 32];
    const int t = threadIdx.x, w = t >> 6, l = t & 63;
    const int m0 = blockIdx.x * 128;                       // grid 450
    const int ko = (l & 3) * 8;
    size_t aga[2], bga[2];
    #pragma unroll
    for (int i = 0; i < 2; ++i) {
        int r = (w * 2 + i) * 16 + (l >> 2);
        int m = m0 + r;
        int bl = m / 3600, rem = m - bl * 3600, oy = rem / 60, ox = rem - oy * 60;
        aga[i] = (size_t)((bl * 121 + 2 * oy) * 121 + 2 * ox) * 64 + ko;
        bga[i] = (size_t)r * 576 + ko;
    }
    const int wr = (w >> 1) * 64, wc = (w & 1) * 64, lr = l & 15, lk = (l >> 4) * 8;
    f32x4 acc[4][4] = {};
    auto stage = [&](int buf, int s) {
        int ky = s / 6, r6 = s - ky * 6, kx = r6 >> 1, h = r6 & 1;
        int aoff = (ky * 121 + kx) * 64 + h * 32;
        int boff = (ky * 3 + kx) * 64 + h * 32;
        #pragma unroll
        for (int i = 0; i < 2; ++i) {
            gl16(c1 + aga[i] + aoff, &As[buf][(w * 2 + i) * 512]);
            gl16(w2t + bga[i] + boff, &Bs[buf][(w * 2 + i) * 512]);
        }
    };
    stage(0, 0); stage(1, 1);
    int cur = 0, pre = 2;
    for (int s = 0; s < 18; ++s) {
        if (s + 1 < 18) { PIPE_WAIT(4) } else { PIPE_WAIT(0) }
        if (s + 2 < 18) stage(pre, s + 2);
        bf16x8 af[4], bfv[4];
        #pragma unroll
        for (int i = 0; i < 4; ++i) af[i] = *(const bf16x8*)&As[cur][(wr + i * 16 + lr) * 32 + lk];
        #pragma unroll
        for (int j = 0; j < 4; ++j) bfv[j] = *(const bf16x8*)&Bs[cur][(wc + j * 16 + lr) * 32 + lk];
        #pragma unroll
        for (int i = 0; i < 4; ++i)
            #pragma unroll
            for (int j = 0; j < 4; ++j)
                acc[i][j] = __builtin_amdgcn_mfma_f32_16x16x32_bf16(af[i], bfv[j], acc[i][j], 0, 0, 0);
        pre = cur; cur = (cur == 2) ? 0 : cur + 1;
    }
    float bias[4];
    #pragma unroll
    for (int j = 0; j < 4; ++j) bias[j] = b2[wc + j * 16 + lr];
    #pragma unroll
    for (int i = 0; i < 4; ++i)
        #pragma unroll
        for (int r = 0; r < 4; ++r) {
            int m = m0 + wr + i * 16 + (l >> 4) * 4 + r;
            int bl = m / 3600, rem = m - bl * 3600, oy = rem / 60, ox = rem - oy * 60;
            size_t ob = (size_t)((bl * 61 + oy) * 61 + ox) * 128;
            #pragma unroll
            for (int j = 0; j < 4; ++j)
                c2[ob + wc + j * 16 + lr] = f2bf(fmaxf(acc[i][j][r] + bias[j], 0.f));
            const bool bx = (ox == 59), by = (oy == 59);
            if (bx) {
                size_t zb = (size_t)((bl * 61 + oy) * 61 + 60) * 128;
                #pragma unroll
                for (int j = 0; j < 4; ++j) c2[zb + wc + j * 16 + lr] = 0;
            }
            if (by) {
                size_t zb = (size_t)((bl * 61 + 60) * 61 + ox) * 128;
                #pragma unroll
                for (int j = 0; j < 4; ++j) c2[zb + wc + j * 16 + lr] = 0;
            }
            if (bx && by) {
                size_t zb = (size_t)((bl * 61 + 60) * 61 + 60) * 128;
                #pragma unroll
                for (int j = 0; j < 4; ++j) c2[zb + wc + j * 16 + lr] = 0;
            }
        }
}

// ======================= conv3 MFMA: M=14400 N=256 K=1152 (3-buf) ============
// feat padded to [32][1024][256]
__global__ __launch_bounds__(256) void k_conv3(
        const unsigned short* __restrict__ c2, const unsigned short* __restrict__ w3t,
        const float* __restrict__ b3, unsigned short* __restrict__ feat, int f0) {
    __shared__ __align__(16) unsigned short As[3][128 * 32];
    __shared__ __align__(16) unsigned short Bs[3][64 * 32];
    const int t = threadIdx.x, w = t >> 6, l = t & 63;
    const int m0 = blockIdx.x * 128, n0 = blockIdx.y * 64;   // grid (113,4)
    const int ko = (l & 3) * 8;
    size_t aga[2], bga;
    #pragma unroll
    for (int i = 0; i < 2; ++i) {
        int r = (w * 2 + i) * 16 + (l >> 2);
        int m = min(m0 + r, 14399);
        int bl = m / 900, rem = m - bl * 900, oy = rem / 30, ox = rem - oy * 30;
        aga[i] = (size_t)((bl * 61 + 2 * oy) * 61 + 2 * ox) * 128 + ko;
    }
    { int n = n0 + w * 16 + (l >> 2); bga = (size_t)n * 1152 + ko; }
    const int wr = (w >> 1) * 64, wc = (w & 1) * 32, lr = l & 15, lk = (l >> 4) * 8;
    f32x4 acc[4][2] = {};
    auto stage = [&](int buf, int s) {
        int ky = s / 12, r12 = s - ky * 12, kx = r12 >> 2, h = r12 & 3;
        int aoff = (ky * 61 + kx) * 128 + h * 32;
        int boff = (ky * 3 + kx) * 128 + h * 32;
        #pragma unroll
        for (int i = 0; i < 2; ++i)
            gl16(c2 + aga[i] + aoff, &As[buf][(w * 2 + i) * 512]);
        gl16(w3t + bga + boff, &Bs[buf][w * 512]);
    };
    stage(0, 0); stage(1, 1);
    int cur = 0, pre = 2;
    for (int s = 0; s < 36; ++s) {
        if (s + 1 < 36) { PIPE_WAIT(3) } else { PIPE_WAIT(0) }
        if (s + 2 < 36) stage(pre, s + 2);
        bf16x8 af[4], bfv[2];
        #pragma unroll
        for (int i = 0; i < 4; ++i) af[i] = *(const bf16x8*)&As[cur][(wr + i * 16 + lr) * 32 + lk];
        #pragma unroll
        for (int j = 0; j < 2; ++j) bfv[j] = *(const bf16x8*)&Bs[cur][(wc + j * 16 + lr) * 32 + lk];
        #pragma unroll
        for (int i = 0; i < 4; ++i)
            #pragma unroll
            for (int j = 0; j < 2; ++j)
                acc[i][j] = __builtin_amdgcn_mfma_f32_16x16x32_bf16(af[i], bfv[j], acc[i][j], 0, 0, 0);
        pre = cur; cur = (cur == 2) ? 0 : cur + 1;
    }
    float bias[2];
    #pragma unroll
    for (int j = 0; j < 2; ++j) bias[j] = b3[n0 + wc + j * 16 + lr];
    #pragma unroll
    for (int i = 0; i < 4; ++i)
        #pragma unroll
        for (int r = 0; r < 4; ++r) {
            int m = m0 + wr + i * 16 + (l >> 4) * 4 + r;
            if (m < 14400) {
                int bl = m / 900, pos = m - bl * 900;
                size_t ob = ((size_t)(f0 + bl) * 1024 + pos) * 256;
                #pragma unroll
                for (int j = 0; j < 2; ++j)
                    feat[ob + n0 + wc + j * 16 + lr] = f2bf(fmaxf(acc[i][j][r] + bias[j], 0.f));
            }
        }
}

// ======================= l2norm: wave per row, rows 900..1023 zeroed =========
__global__ __launch_bounds__(256) void k_l2norm(unsigned short* __restrict__ feat) {
    const int t = threadIdx.x, wv = t >> 6, ln = t & 63;
    const int R = blockIdx.x * 4 + wv;             // 32768 rows, grid 8192
    const int pos = R & 1023;
    ushort4* fp4 = (ushort4*)(feat + (size_t)R * 256);
    if (pos >= 900) { fp4[ln] = make_ushort4(0, 0, 0, 0); return; }
    ushort4 u = fp4[ln];
    float x0 = bf2f(u.x), x1 = bf2f(u.y), x2 = bf2f(u.z), x3 = bf2f(u.w);
    float s = x0 * x0 + x1 * x1 + x2 * x2 + x3 * x3;
    #pragma unroll
    for (int m = 1; m < 64; m <<= 1) s += __shfl_xor(s, m);
    const float inv = 1.f / sqrtf(s + EPSF);
    u.x = f2bf(x0 * inv); u.y = f2bf(x1 * inv);
    u.z = f2bf(x2 * inv); u.w = f2bf(x3 * inv);
    fp4[ln] = u;
}

// ======================= corr MFMA: per-b 1024x1024 padded, 128-tile =========
__global__ __launch_bounds__(256) void k_corr(
        const unsigned short* __restrict__ feat, unsigned short* __restrict__ corr) {
    __shared__ __align__(16) unsigned short As[3][128 * 32];
    __shared__ __align__(16) unsigned short Bs[3][128 * 32];
    const int t = threadIdx.x, w = t >> 6, l = t & 63;
    const int id0 = blockIdx.x;                            // 1024
    const int sw = (id0 & 7) * 128 + (id0 >> 3);           // bijective XCD swizzle
    const int b = sw >> 6, rem = sw & 63;
    const int p0 = (rem >> 3) * 128, q0 = (rem & 7) * 128;
    const int ko = (l & 3) * 8;
    const unsigned short* fA = feat + (size_t)b * 1024 * 256;
    const unsigned short* fB = feat + (size_t)(16 + b) * 1024 * 256;
    size_t aga[2], bga[2];
    #pragma unroll
    for (int i = 0; i < 2; ++i) {
        int r = (w * 2 + i) * 16 + (l >> 2);
        aga[i] = (size_t)(p0 + r) * 256 + ko;
        bga[i] = (size_t)(q0 + r) * 256 + ko;
    }
    const int wr = (w >> 1) * 64, wc = (w & 1) * 64, lr = l & 15, lk = (l >> 4) * 8;
    f32x4 acc[4][4] = {};
    auto stage = [&](int buf, int s) {
        #pragma unroll
        for (int i = 0; i < 2; ++i) {
            gl16(fA + aga[i] + s * 32, &As[buf][(w * 2 + i) * 512]);
            gl16(fB + bga[i] + s * 32, &Bs[buf][(w * 2 + i) * 512]);
        }
    };
    stage(0, 0); stage(1, 1);
    int cur = 0, pre = 2;
    for (int s = 0; s < 8; ++s) {
        if (s + 1 < 8) { PIPE_WAIT(4) } else { PIPE_WAIT(0) }
        if (s + 2 < 8) stage(pre, s + 2);
        bf16x8 af[4], bfv[4];
        #pragma unroll
        for (int i = 0; i < 4; ++i) af[i] = *(const bf16x8*)&As[cur][(wr + i * 16 + lr) * 32 + lk];
        #pragma unroll
        for (int j = 0; j < 4; ++j) bfv[j] = *(const bf16x8*)&Bs[cur][(wc + j * 16 + lr) * 32 + lk];
        #pragma unroll
        for (int i = 0; i < 4; ++i)
            #pragma unroll
            for (int j = 0; j < 4; ++j)
                acc[i][j] = __builtin_amdgcn_mfma_f32_16x16x32_bf16(af[i], bfv[j], acc[i][j], 0, 0, 0);
        pre = cur; cur = (cur == 2) ? 0 : cur + 1;
    }
    unsigned short* cb = corr + (size_t)b * 960 * 960;
    #pragma unroll
    for (int i = 0; i < 4; ++i)
        #pragma unroll
        for (int r = 0; r < 4; ++r) {
            int row = p0 + wr + i * 16 + (l >> 4) * 4 + r;
            if (row < 960) {
                #pragma unroll
                for (int j = 0; j < 4; ++j) {
                    int col = q0 + wc + j * 16 + lr;
                    if (col < 960)
                        cb[(size_t)row * 960 + col] = f2bf(fmaxf(acc[i][j][r], 0.f));
                }
            }
        }
}

// ======================= corr L2 norm: one wave per row ======================
__global__ __launch_bounds__(256) void k_corrnorm(unsigned short* __restrict__ corr) {
    const int t = threadIdx.x, wv = t >> 6, ln = t & 63;
    const int row = blockIdx.x * 4 + wv;       // 14400 rows, grid 3600
    const int b = row / 900, p = row - b * 900;
    ushort4* cp4 = (ushort4*)(corr + ((size_t)b * 960 + p) * 960);
    float x[16];
    float s = 0.f;
    #pragma unroll
    for (int i = 0; i < 4; ++i) {
        const int idx = ln + 64 * i;
        float v0 = 0.f, v1 = 0.f, v2 = 0.f, v3 = 0.f;
        if (idx < 225) {
            ushort4 u = cp4[idx];
            v0 = fmaxf(bf2f(u.x), 0.f); v1 = fmaxf(bf2f(u.y), 0.f);
            v2 = fmaxf(bf2f(u.z), 0.f); v3 = fmaxf(bf2f(u.w), 0.f);
        }
        x[i * 4 + 0] = v0; x[i * 4 + 1] = v1; x[i * 4 + 2] = v2; x[i * 4 + 3] = v3;
        s += v0 * v0 + v1 * v1 + v2 * v2 + v3 * v3;
    }
    #pragma unroll
    for (int m = 1; m < 64; m <<= 1) s += __shfl_xor(s, m);
    const float sc = 1.f / sqrtf(s + EPSF);
    #pragma unroll
    for (int i = 0; i < 4; ++i) {
        const int idx = ln + 64 * i;
        if (idx < 225) {
            ushort4 u;
            u.x = f2bf(x[i * 4 + 0] * sc); u.y = f2bf(x[i * 4 + 1] * sc);
            u.z = f2bf(x[i * 4 + 2] * sc); u.w = f2bf(x[i * 4 + 3] * sc);
            cp4[idx] = u;
        }
    }
}

// ======================= cw1 MFMA v3: 256x128 block, q-major K, split 14 =====
// M=9216 N=128 K'=29qi x 49sq; wave = 64x128 (acc 4x8); grid 504 = 36mt x 14ks
__global__ __launch_bounds__(256, 2) void k_cw1(
        const unsigned short* __restrict__ corr, const unsigned short* __restrict__ Wt,
        unsigned short* __restrict__ part) {
    __shared__ __align__(16) unsigned short As[3][256 * 32];   // 16 KB each
    __shared__ __align__(16) unsigned short Bs[3][128 * 32];   // 8 KB each
    const int t = threadIdx.x, w = t >> 6, l = t & 63;
    const int id0 = blockIdx.x;                            // 504, mt-fast
    const int mt = id0 % 36, ks = id0 / 36;
    const int m0 = mt * 256;
    // A: 4 staging loads/thread; load i covers rows i*64 + w*16 + (l>>2)
    size_t aga[4];
    #pragma unroll
    for (int i = 0; i < 4; ++i) {
        int r = i * 64 + w * 16 + (l >> 2);
        int m = m0 + r;
        int b = m / 576, rem = m - b * 576, oy = rem / 24, ox = rem - oy * 24;
        aga[i] = (size_t)(b * 960 + oy * 30 + ox) * 960 + (l & 3) * 8;
    }
    // B: 2 staging loads/thread; rows i*64 + w*16 + (l>>2) of Wt[128][45472]
    size_t bga[2];
    #pragma unroll
    for (int i = 0; i < 2; ++i) {
        int r = i * 64 + w * 16 + (l >> 2);
        bga[i] = (size_t)r * 45472 + (l & 3) * 8;
    }
    // q-major schedule: step s -> qi = s/49 (q-slice), sq = s%49 (window)
    // 1421 steps total, split 14: ks<7 get 102, else 101
    const int sbase = ks * 101 + min(ks, 7);
    const int scount = 101 + (ks < 7 ? 1 : 0);
    f32x4 acc[4][8] = {};
    auto stage = [&](int buf, int sidx) {
        int s = sbase + sidx;
        int qi = s / 49, sq = s - qi * 49;
        int ky = sq / 7, kx = sq - ky * 7;
        int aoff = (ky * 30 + kx) * 960 + qi * 32;
        int boff = sq * 928 + qi * 32;
        #pragma unroll
        for (int i = 0; i < 4; ++i)
            gl16(corr + aga[i] + aoff, &As[buf][(i * 256 + w * 64) * 8]);
        #pragma unroll
        for (int i = 0; i < 2; ++i)
            gl16(Wt + bga[i] + boff, &Bs[buf][(i * 256 + w * 64) * 8]);
    };
    stage(0, 0); stage(1, 1);
    int cur = 0, pre = 2;
    const int lr = l & 15, lk = (l >> 4) * 8;
    for (int s = 0; s < scount; ++s) {
        if (s + 1 < scount) { PIPE_WAIT(6) } else { PIPE_WAIT(0) }
        if (s + 2 < scount) stage(pre, s + 2);
        bf16x8 af[4], bfv[8];
        #pragma unroll
        for (int i = 0; i < 4; ++i)
            af[i] = *(const bf16x8*)&As[cur][(w * 64 + i * 16 + lr) * 32 + lk];
        #pragma unroll
        for (int j = 0; j < 8; ++j)
            bfv[j] = *(const bf16x8*)&Bs[cur][(j * 16 + lr) * 32 + lk];
        #pragma unroll
        for (int i = 0; i < 4; ++i)
            #pragma unroll
            for (int j = 0; j < 8; ++j)
                acc[i][j] = __builtin_amdgcn_mfma_f32_16x16x32_bf16(af[i], bfv[j], acc[i][j], 0, 0, 0);
        pre = cur; cur = (cur == 2) ? 0 : cur + 1;
    }
    unsigned short* pb = part + ((size_t)ks * 9216 + m0) * 128;
    #pragma unroll
    for (int i = 0; i < 4; ++i)
        #pragma unroll
        for (int r = 0; r < 4; ++r) {
            int row = w * 64 + i * 16 + (l >> 4) * 4 + r;
            #pragma unroll
            for (int j = 0; j < 8; ++j)
                pb[(size_t)row * 128 + j * 16 + lr] = f2h(acc[i][j][r]);
        }
}

// ======================= reduce 14 fp16 partials + bias + relu + BN -> bf16 ==
__global__ __launch_bounds__(256) void k_r1fin(
        const unsigned short* __restrict__ part, const float* __restrict__ cb1,
        const float* __restrict__ g1, const float* __restrict__ be1,
        const float* __restrict__ m1, const float* __restrict__ v1,
        unsigned short* __restrict__ r1) {
    const int idx = blockIdx.x * 256 + threadIdx.x;        // grid 1152
    const size_t base = (size_t)idx * 4;
    const size_t N = 9216 * 128;
    float s0 = 0.f, s1 = 0.f, s2 = 0.f, s3 = 0.f;
    #pragma unroll
    for (int i = 0; i < 14; ++i) {
        ushort4 u = *(const ushort4*)(part + i * N + base);
        s0 += h2f(u.x); s1 += h2f(u.y); s2 += h2f(u.z); s3 += h2f(u.w);
    }
    const int co = (int)(base & 127);
    float r[4] = {s0, s1, s2, s3};
    ushort4 o;
    unsigned short* op = (unsigned short*)&o;
    #pragma unroll
    for (int j = 0; j < 4; ++j) {
        int c = co + j;
        float x = fmaxf(r[j] + cb1[c], 0.f);
        x = (x - m1[c]) * (g1[c] / sqrtf(v1[c] + BN_EPSF)) + be1[c];
        op[j] = f2bf(x);
    }
    *(ushort4*)(r1 + base) = o;
}

// ======================= cw2 MFMA: M=6400 N=64 K=3200 (3-buf), bias+relu+BN ==
__global__ __launch_bounds__(256) void k_cw2(
        const unsigned short* __restrict__ r1, const unsigned short* __restrict__ Wt2,
        const float* __restrict__ cb2, const float* __restrict__ g2,
        const float* __restrict__ be2, const float* __restrict__ m2,
        const float* __restrict__ v2, float* __restrict__ r2) {
    __shared__ __align__(16) unsigned short As[3][64 * 32];
    __shared__ __align__(16) unsigned short Bs[3][64 * 32];
    const int t = threadIdx.x, w = t >> 6, l = t & 63;
    const int m0 = blockIdx.x * 64;                        // grid 100
    const int ko = (l & 3) * 8;
    const int wi = w & 1;
    size_t ga[2];
    #pragma unroll
    for (int i = 0; i < 2; ++i) {
        int r = (wi * 2 + i) * 16 + (l >> 2);
        if (w < 2) {
            int m = m0 + r;
            int b = m / 400, rem = m - b * 400, oy = rem / 20, ox = rem - oy * 20;
            ga[i] = (size_t)((b * 24 + oy) * 24 + ox) * 128 + ko;
        } else {
            ga[i] = (size_t)r * 3200 + ko;
        }
    }
    const int wr = (w >> 1) * 32, wc = (w & 1) * 32, lr = l & 15, lk = (l >> 4) * 8;
    f32x4 acc[2][2] = {};
    auto stage = [&](int buf, int s) {
        int kyx = s >> 2, h = s & 3;
        int ky = kyx / 5, kx = kyx - ky * 5;
        int aoff = (ky * 24 + kx) * 128 + h * 32;
        int boff = s * 32;
        #pragma unroll
        for (int i = 0; i < 2; ++i) {
            unsigned short* dst = (w < 2) ? &As[buf][(wi * 2 + i) * 512]
                                          : &Bs[buf][(wi * 2 + i) * 512];
            const unsigned short* src = (w < 2) ? r1 + ga[i] + aoff : Wt2 + ga[i] + boff;
            gl16(src, dst);
        }
    };
    stage(0, 0); stage(1, 1);
    int cur = 0, pre = 2;
    for (int s = 0; s < 100; ++s) {
        if (s + 1 < 100) { PIPE_WAIT(2) } else { PIPE_WAIT(0) }
        if (s + 2 < 100) stage(pre, s + 2);
        bf16x8 af[2], bfv[2];
        #pragma unroll
        for (int i = 0; i < 2; ++i) af[i] = *(const bf16x8*)&As[cur][(wr + i * 16 + lr) * 32 + lk];
        #pragma unroll
        for (int j = 0; j < 2; ++j) bfv[j] = *(const bf16x8*)&Bs[cur][(wc + j * 16 + lr) * 32 + lk];
        #pragma unroll
        for (int i = 0; i < 2; ++i)
            #pragma unroll
            for (int j = 0; j < 2; ++j)
                acc[i][j] = __builtin_amdgcn_mfma_f32_16x16x32_bf16(af[i], bfv[j], acc[i][j], 0, 0, 0);
        pre = cur; cur = (cur == 2) ? 0 : cur + 1;
    }
    float sc[2], sh[2], bias[2];
    #pragma unroll
    for (int j = 0; j < 2; ++j) {
        int co = wc + j * 16 + lr;
        sc[j] = g2[co] / sqrtf(v2[co] + BN_EPSF);
        sh[j] = be2[co] - m2[co] * sc[j];
        bias[j] = cb2[co];
    }
    #pragma unroll
    for (int i = 0; i < 2; ++i)
        #pragma unroll
        for (int r = 0; r < 4; ++r) {
            int m = m0 + wr + i * 16 + (l >> 4) * 4 + r;
            #pragma unroll
            for (int j = 0; j < 2; ++j) {
                float s = fmaxf(acc[i][j][r] + bias[j], 0.f);
                r2[(size_t)m * 64 + wc + j * 16 + lr] = s * sc[j] + sh[j];
            }
        }
}

// ======================= dense: K-split partials + finalize ==================
__global__ __launch_bounds__(256) void k_dense(
        const float* __restrict__ r2, const float* __restrict__ dw,
        float* __restrict__ partD) {
    const int b = blockIdx.x, kb = blockIdx.y, t = threadIdx.x;  // (16,5)
    const float* x = r2 + (size_t)b * 25600 + kb * 5120;
    const float* dwp = dw + (size_t)(kb * 5120) * 18;
    float s[18] = {};
    for (int k = t; k < 5120; k += 256) {
        const float xv = x[k];
        const float* dr = dwp + (size_t)k * 18;
        #pragma unroll
        for (int j = 0; j < 18; ++j) s[j] = fmaf(xv, dr[j], s[j]);
    }
    #pragma unroll
    for (int j = 0; j < 18; ++j)
        #pragma unroll
        for (int m = 1; m < 64; m <<= 1) s[j] += __shfl_xor(s[j], m);
    __shared__ float red[4][18];
    if ((t & 63) == 0) {
        #pragma unroll
        for (int j = 0; j < 18; ++j) red[t >> 6][j] = s[j];
    }
    __syncthreads();
    if (t < 18) partD[(b * 5 + kb) * 18 + t] = red[0][t] + red[1][t] + red[2][t] + red[3][t];
}
__global__ __launch_bounds__(288) void k_dfin(
        const float* __restrict__ partD, const float* __restrict__ db,
        float* __restrict__ out) {
    const int i = threadIdx.x;                 // 288
    const int b = i / 18, j = i - b * 18;
    float s = db[j];
    #pragma unroll
    for (int k = 0; k < 5; ++k) s += partD[(b * 5 + k) * 18 + j];
    out[i] = s;
}

extern "C" void kernel_launch(void* const* d_in, const int* in_sizes, int n_in,
                              void* d_out, int out_size, void* d_ws, size_t ws_size,
                              hipStream_t stream) {
    const float* imgA = (const float*)d_in[0];
    const float* imgB = (const float*)d_in[1];
    const float* w1  = (const float*)d_in[2];
    const float* b1  = (const float*)d_in[3];
    const float* w2  = (const float*)d_in[4];
    const float* b2  = (const float*)d_in[5];
    const float* w3  = (const float*)d_in[6];
    const float* b3  = (const float*)d_in[7];
    const float* cw1 = (const float*)d_in[8];
    const float* cb1 = (const float*)d_in[9];
    const float* g1  = (const float*)d_in[10];
    const float* be1 = (const float*)d_in[11];
    const float* m1  = (const float*)d_in[12];
    const float* v1  = (const float*)d_in[13];
    const float* cw2 = (const float*)d_in[14];
    const float* cb2 = (const float*)d_in[15];
    const float* g2  = (const float*)d_in[16];
    const float* be2 = (const float*)d_in[17];
    const float* m2  = (const float*)d_in[18];
    const float* v2  = (const float*)d_in[19];
    const float* dw  = (const float*)d_in[20];
    const float* db  = (const float*)d_in[21];

    // ws layout (bytes), max end = 76,931,072
    //  conv phase : c1@0 (30.0MB) c2@29,984,768 (15.2MB) w2t@45,225,984
    //               w3t@45,373,440  feat@45,963,264 (16.8MB, [32][1024][256])
    //  corr phase : corr@0 (29.5MB, c1 dead)  Wt@29,491,200 (11.6MB, c2 dead)
    //  cw1 phase  : part@41,132,032 (33.0MB fp16x14, feat/w2t/w3t dead)
    //  tail       : r1@74,162,176 (2.4MB)  Wt2@76,521,472  r2@41,132,032
    //               partD@42,770,432
    char* ws = (char*)d_ws;
    unsigned short* c1   = (unsigned short*)(ws + 0);
    unsigned short* c2   = (unsigned short*)(ws + 29984768);
    unsigned short* w2t  = (unsigned short*)(ws + 45225984);
    unsigned short* w3t  = (unsigned short*)(ws + 45373440);
    unsigned short* feat = (unsigned short*)(ws + 45963264);
    unsigned short* corr = (unsigned short*)(ws + 0);
    unsigned short* Wt   = (unsigned short*)(ws + 29491200);
    unsigned short* part = (unsigned short*)(ws + 41132032);
    unsigned short* r1   = (unsigned short*)(ws + 74162176);
    unsigned short* Wt2  = (unsigned short*)(ws + 76521472);
    float*          r2   = (float*)(ws + 41132032);
    float*          partD= (float*)(ws + 42770432);

    k_wx<<<dim3(2240), 256, 0, stream>>>(w2, w3, cw2, w2t, w3t, Wt2);

    for (int chunk = 0; chunk < 2; ++chunk) {
        const float* img = chunk ? imgB : imgA;
        const int f0 = chunk * 16;
        k_conv1<<<dim3(30, 120, 16), 256, 0, stream>>>(img, w1, b1, c1);
        k_conv2<<<dim3(450),         256, 0, stream>>>(c1, w2t, b2, c2);
        k_conv3<<<dim3(113, 4),      256, 0, stream>>>(c2, w3t, b3, feat, f0);
    }
    k_l2norm  <<<dim3(8192),  256, 0, stream>>>(feat);
    k_corr    <<<dim3(1024),  256, 0, stream>>>(feat, corr);
    k_corrnorm<<<dim3(3600),  256, 0, stream>>>(corr);
    k_wt1     <<<dim3(29, 49),256, 0, stream>>>(cw1, Wt);
    k_cw1     <<<dim3(504),   256, 0, stream>>>(corr, Wt, part);
    k_r1fin   <<<dim3(1152),  256, 0, stream>>>(part, cb1, g1, be1, m1, v1, r1);
    k_cw2     <<<dim3(100),   256, 0, stream>>>(r1, Wt2, cb2, g2, be2, m2, v2, r2);
    k_dense   <<<dim3(16, 5), 256, 0, stream>>>(r2, dw, partD);
    k_dfin    <<<dim3(1),     288, 0, stream>>>(partD, db, (float*)d_out);
}

// Round 8
// 487.081 us; speedup vs baseline: 13.7523x; 1.1554x over previous
//
#include <hip/hip_runtime.h>

#define EPSF    1e-6f
#define BN_EPSF 1e-3f

typedef __attribute__((ext_vector_type(8))) short bf16x8;   // 8 bf16 in 4 VGPRs
typedef __attribute__((ext_vector_type(4))) float f32x4;

__device__ __forceinline__ unsigned short f2bf(float f) {
    unsigned int u = __builtin_bit_cast(unsigned int, f);
    u = (u + 0x7FFFu + ((u >> 16) & 1u)) >> 16;            // RNE
    return (unsigned short)u;
}
__device__ __forceinline__ float bf2f(unsigned short h) {
    unsigned int u = ((unsigned int)h) << 16;
    return __builtin_bit_cast(float, u);
}
__device__ __forceinline__ unsigned short f2h(float f) {
    return __builtin_bit_cast(unsigned short, (_Float16)f);
}
__device__ __forceinline__ float h2f(unsigned short h) {
    return (float)__builtin_bit_cast(_Float16, h);
}
// async global->LDS, 16 bytes per lane; lds dest is wave-uniform base + lane*16
__device__ __forceinline__ void gl16(const void* g, void* l) {
    __builtin_amdgcn_global_load_lds((const __attribute__((address_space(1))) void*)g,
                                     (__attribute__((address_space(3))) void*)l, 16, 0, 0);
}
// counted-vmcnt barrier pair (2-phase kernels)
#define PIPE_WAIT(N)                                        \
    asm volatile("s_waitcnt vmcnt(" #N ")" ::: "memory");   \
    __builtin_amdgcn_sched_barrier(0);                      \
    __builtin_amdgcn_s_barrier();                           \
    __builtin_amdgcn_sched_barrier(0);

// ======================= merged weight conversions (w2t | w3t | wt2) =========
__global__ __launch_bounds__(256) void k_wx(
        const float* __restrict__ w2, const float* __restrict__ w3,
        const float* __restrict__ cw2w,
        unsigned short* __restrict__ w2t, unsigned short* __restrict__ w3t,
        unsigned short* __restrict__ wt2) {
    const int bid = blockIdx.x;                            // 2240
    if (bid < 288) {
        int idx = bid * 256 + threadIdx.x;                 // 73728
        int n = idx / 576, k = idx - n * 576;
        w2t[idx] = f2bf(w2[(size_t)k * 128 + n]);
    } else if (bid < 1440) {
        int idx = (bid - 288) * 256 + threadIdx.x;         // 294912
        int n = idx / 1152, k = idx - n * 1152;
        w3t[idx] = f2bf(w3[(size_t)k * 256 + n]);
    } else {
        int idx = (bid - 1440) * 256 + threadIdx.x;        // 204800
        int n = idx / 3200, k = idx - n * 3200;
        wt2[idx] = f2bf(cw2w[(size_t)k * 64 + n]);
    }
}
// Wt[n][k'], k'=s*928+q, zero for q>=900; coalesced LDS transpose. grid (29,49)
__global__ __launch_bounds__(256) void k_wt1(const float* __restrict__ W,
                                             unsigned short* __restrict__ Wt) {
    __shared__ float tile[32][132];
    const int s = blockIdx.y;              // 49
    const int q0 = blockIdx.x * 32;        // 0..896
    const int t = threadIdx.x;
    const int n = t & 127, rr = t >> 7;
    #pragma unroll
    for (int r = rr; r < 32; r += 2) {
        int q = q0 + r;
        tile[r][n] = (q < 900) ? W[((size_t)(s * 900 + q)) * 128 + n] : 0.f;
    }
    __syncthreads();
    const int n2 = t >> 1, half = t & 1;
    unsigned short* dst = Wt + (size_t)n2 * 45472 + s * 928 + q0 + half * 16;
    #pragma unroll
    for (int u = 0; u < 16; ++u) dst[u] = f2bf(tile[half * 16 + u][n2]);
}

// ======================= conv1 (fp32 in -> bf16 padded out, border fused) ====
__global__ __launch_bounds__(256) void k_conv1(
        const float* __restrict__ img,
        const float* __restrict__ w, const float* __restrict__ bias,
        unsigned short* __restrict__ c1) {
    const int co = threadIdx.x & 63, u = threadIdx.x >> 6;
    const int ox = blockIdx.x * 4 + u;                     // 120
    const int oy = blockIdx.y;                             // 120
    const int b = blockIdx.z;                              // 16
    float acc = bias[co];
    #pragma unroll
    for (int ky = 0; ky < 3; ++ky) {
        const int iy = 2 * oy + ky;
        if (iy >= 240) continue;
        #pragma unroll
        for (int kx = 0; kx < 3; ++kx) {
            const int ix = 2 * ox + kx;
            if (ix >= 240) continue;
            const float* ip = img + ((size_t)(b * 240 + iy) * 240 + ix) * 3;
            const float* wp = w + ((ky * 3 + kx) * 3) * 64 + co;
            acc = fmaf(ip[0], wp[0], acc);
            acc = fmaf(ip[1], wp[64], acc);
            acc = fmaf(ip[2], wp[128], acc);
        }
    }
    c1[((size_t)(b * 121 + oy) * 121 + ox) * 64 + co] = f2bf(fmaxf(acc, 0.f));
    const bool bx = (ox == 119), by = (oy == 119);
    if (bx) c1[((size_t)(b * 121 + oy) * 121 + 120) * 64 + co] = 0;
    if (by) c1[((size_t)(b * 121 + 120) * 121 + ox) * 64 + co] = 0;
    if (bx && by) c1[((size_t)(b * 121 + 120) * 121 + 120) * 64 + co] = 0;
}

// ======================= conv2 MFMA: M=57600 N=128 K=576 (3-buf pipeline) ====
__global__ __launch_bounds__(256) void k_conv2(
        const unsigned short* __restrict__ c1, const unsigned short* __restrict__ w2t,
        const float* __restrict__ b2, unsigned short* __restrict__ c2) {
    __shared__ __align__(16) unsigned short As[3][128 * 32];
    __shared__ __align__(16) unsigned short Bs[3][128 * 32];
    const int t = threadIdx.x, w = t >> 6, l = t & 63;
    const int m0 = blockIdx.x * 128;                       // grid 450
    const int ko = (l & 3) * 8;
    size_t aga[2], bga[2];
    #pragma unroll
    for (int i = 0; i < 2; ++i) {
        int r = (w * 2 + i) * 16 + (l >> 2);
        int m = m0 + r;
        int bl = m / 3600, rem = m - bl * 3600, oy = rem / 60, ox = rem - oy * 60;
        aga[i] = (size_t)((bl * 121 + 2 * oy) * 121 + 2 * ox) * 64 + ko;
        bga[i] = (size_t)r * 576 + ko;
    }
    const int wr = (w >> 1) * 64, wc = (w & 1) * 64, lr = l & 15, lk = (l >> 4) * 8;
    f32x4 acc[4][4] = {};
    auto stage = [&](int buf, int s) {
        int ky = s / 6, r6 = s - ky * 6, kx = r6 >> 1, h = r6 & 1;
        int aoff = (ky * 121 + kx) * 64 + h * 32;
        int boff = (ky * 3 + kx) * 64 + h * 32;
        #pragma unroll
        for (int i = 0; i < 2; ++i) {
            gl16(c1 + aga[i] + aoff, &As[buf][(w * 2 + i) * 512]);
            gl16(w2t + bga[i] + boff, &Bs[buf][(w * 2 + i) * 512]);
        }
    };
    stage(0, 0); stage(1, 1);
    int cur = 0, pre = 2;
    for (int s = 0; s < 18; ++s) {
        if (s + 1 < 18) { PIPE_WAIT(4) } else { PIPE_WAIT(0) }
        if (s + 2 < 18) stage(pre, s + 2);
        bf16x8 af[4], bfv[4];
        #pragma unroll
        for (int i = 0; i < 4; ++i) af[i] = *(const bf16x8*)&As[cur][(wr + i * 16 + lr) * 32 + lk];
        #pragma unroll
        for (int j = 0; j < 4; ++j) bfv[j] = *(const bf16x8*)&Bs[cur][(wc + j * 16 + lr) * 32 + lk];
        #pragma unroll
        for (int i = 0; i < 4; ++i)
            #pragma unroll
            for (int j = 0; j < 4; ++j)
                acc[i][j] = __builtin_amdgcn_mfma_f32_16x16x32_bf16(af[i], bfv[j], acc[i][j], 0, 0, 0);
        pre = cur; cur = (cur == 2) ? 0 : cur + 1;
    }
    float bias[4];
    #pragma unroll
    for (int j = 0; j < 4; ++j) bias[j] = b2[wc + j * 16 + lr];
    #pragma unroll
    for (int i = 0; i < 4; ++i)
        #pragma unroll
        for (int r = 0; r < 4; ++r) {
            int m = m0 + wr + i * 16 + (l >> 4) * 4 + r;
            int bl = m / 3600, rem = m - bl * 3600, oy = rem / 60, ox = rem - oy * 60;
            size_t ob = (size_t)((bl * 61 + oy) * 61 + ox) * 128;
            #pragma unroll
            for (int j = 0; j < 4; ++j)
                c2[ob + wc + j * 16 + lr] = f2bf(fmaxf(acc[i][j][r] + bias[j], 0.f));
            const bool bx = (ox == 59), by = (oy == 59);
            if (bx) {
                size_t zb = (size_t)((bl * 61 + oy) * 61 + 60) * 128;
                #pragma unroll
                for (int j = 0; j < 4; ++j) c2[zb + wc + j * 16 + lr] = 0;
            }
            if (by) {
                size_t zb = (size_t)((bl * 61 + 60) * 61 + ox) * 128;
                #pragma unroll
                for (int j = 0; j < 4; ++j) c2[zb + wc + j * 16 + lr] = 0;
            }
            if (bx && by) {
                size_t zb = (size_t)((bl * 61 + 60) * 61 + 60) * 128;
                #pragma unroll
                for (int j = 0; j < 4; ++j) c2[zb + wc + j * 16 + lr] = 0;
            }
        }
}

// ======================= conv3 MFMA: M=14400 N=256 K=1152 (3-buf) ============
// feat padded to [32][1024][256]
__global__ __launch_bounds__(256) void k_conv3(
        const unsigned short* __restrict__ c2, const unsigned short* __restrict__ w3t,
        const float* __restrict__ b3, unsigned short* __restrict__ feat, int f0) {
    __shared__ __align__(16) unsigned short As[3][128 * 32];
    __shared__ __align__(16) unsigned short Bs[3][64 * 32];
    const int t = threadIdx.x, w = t >> 6, l = t & 63;
    const int m0 = blockIdx.x * 128, n0 = blockIdx.y * 64;   // grid (113,4)
    const int ko = (l & 3) * 8;
    size_t aga[2], bga;
    #pragma unroll
    for (int i = 0; i < 2; ++i) {
        int r = (w * 2 + i) * 16 + (l >> 2);
        int m = min(m0 + r, 14399);
        int bl = m / 900, rem = m - bl * 900, oy = rem / 30, ox = rem - oy * 30;
        aga[i] = (size_t)((bl * 61 + 2 * oy) * 61 + 2 * ox) * 128 + ko;
    }
    { int n = n0 + w * 16 + (l >> 2); bga = (size_t)n * 1152 + ko; }
    const int wr = (w >> 1) * 64, wc = (w & 1) * 32, lr = l & 15, lk = (l >> 4) * 8;
    f32x4 acc[4][2] = {};
    auto stage = [&](int buf, int s) {
        int ky = s / 12, r12 = s - ky * 12, kx = r12 >> 2, h = r12 & 3;
        int aoff = (ky * 61 + kx) * 128 + h * 32;
        int boff = (ky * 3 + kx) * 128 + h * 32;
        #pragma unroll
        for (int i = 0; i < 2; ++i)
            gl16(c2 + aga[i] + aoff, &As[buf][(w * 2 + i) * 512]);
        gl16(w3t + bga + boff, &Bs[buf][w * 512]);
    };
    stage(0, 0); stage(1, 1);
    int cur = 0, pre = 2;
    for (int s = 0; s < 36; ++s) {
        if (s + 1 < 36) { PIPE_WAIT(3) } else { PIPE_WAIT(0) }
        if (s + 2 < 36) stage(pre, s + 2);
        bf16x8 af[4], bfv[2];
        #pragma unroll
        for (int i = 0; i < 4; ++i) af[i] = *(const bf16x8*)&As[cur][(wr + i * 16 + lr) * 32 + lk];
        #pragma unroll
        for (int j = 0; j < 2; ++j) bfv[j] = *(const bf16x8*)&Bs[cur][(wc + j * 16 + lr) * 32 + lk];
        #pragma unroll
        for (int i = 0; i < 4; ++i)
            #pragma unroll
            for (int j = 0; j < 2; ++j)
                acc[i][j] = __builtin_amdgcn_mfma_f32_16x16x32_bf16(af[i], bfv[j], acc[i][j], 0, 0, 0);
        pre = cur; cur = (cur == 2) ? 0 : cur + 1;
    }
    float bias[2];
    #pragma unroll
    for (int j = 0; j < 2; ++j) bias[j] = b3[n0 + wc + j * 16 + lr];
    #pragma unroll
    for (int i = 0; i < 4; ++i)
        #pragma unroll
        for (int r = 0; r < 4; ++r) {
            int m = m0 + wr + i * 16 + (l >> 4) * 4 + r;
            if (m < 14400) {
                int bl = m / 900, pos = m - bl * 900;
                size_t ob = ((size_t)(f0 + bl) * 1024 + pos) * 256;
                #pragma unroll
                for (int j = 0; j < 2; ++j)
                    feat[ob + n0 + wc + j * 16 + lr] = f2bf(fmaxf(acc[i][j][r] + bias[j], 0.f));
            }
        }
}

// ======================= l2norm: wave per row, rows 900..1023 zeroed =========
__global__ __launch_bounds__(256) void k_l2norm(unsigned short* __restrict__ feat) {
    const int t = threadIdx.x, wv = t >> 6, ln = t & 63;
    const int R = blockIdx.x * 4 + wv;             // 32768 rows, grid 8192
    const int pos = R & 1023;
    ushort4* fp4 = (ushort4*)(feat + (size_t)R * 256);
    if (pos >= 900) { fp4[ln] = make_ushort4(0, 0, 0, 0); return; }
    ushort4 u = fp4[ln];
    float x0 = bf2f(u.x), x1 = bf2f(u.y), x2 = bf2f(u.z), x3 = bf2f(u.w);
    float s = x0 * x0 + x1 * x1 + x2 * x2 + x3 * x3;
    #pragma unroll
    for (int m = 1; m < 64; m <<= 1) s += __shfl_xor(s, m);
    const float inv = 1.f / sqrtf(s + EPSF);
    u.x = f2bf(x0 * inv); u.y = f2bf(x1 * inv);
    u.z = f2bf(x2 * inv); u.w = f2bf(x3 * inv);
    fp4[ln] = u;
}

// ======================= corr MFMA: per-b 1024x1024 padded, 128-tile =========
__global__ __launch_bounds__(256) void k_corr(
        const unsigned short* __restrict__ feat, unsigned short* __restrict__ corr) {
    __shared__ __align__(16) unsigned short As[3][128 * 32];
    __shared__ __align__(16) unsigned short Bs[3][128 * 32];
    const int t = threadIdx.x, w = t >> 6, l = t & 63;
    const int id0 = blockIdx.x;                            // 1024
    const int sw = (id0 & 7) * 128 + (id0 >> 3);           // bijective XCD swizzle
    const int b = sw >> 6, rem = sw & 63;
    const int p0 = (rem >> 3) * 128, q0 = (rem & 7) * 128;
    const int ko = (l & 3) * 8;
    const unsigned short* fA = feat + (size_t)b * 1024 * 256;
    const unsigned short* fB = feat + (size_t)(16 + b) * 1024 * 256;
    size_t aga[2], bga[2];
    #pragma unroll
    for (int i = 0; i < 2; ++i) {
        int r = (w * 2 + i) * 16 + (l >> 2);
        aga[i] = (size_t)(p0 + r) * 256 + ko;
        bga[i] = (size_t)(q0 + r) * 256 + ko;
    }
    const int wr = (w >> 1) * 64, wc = (w & 1) * 64, lr = l & 15, lk = (l >> 4) * 8;
    f32x4 acc[4][4] = {};
    auto stage = [&](int buf, int s) {
        #pragma unroll
        for (int i = 0; i < 2; ++i) {
            gl16(fA + aga[i] + s * 32, &As[buf][(w * 2 + i) * 512]);
            gl16(fB + bga[i] + s * 32, &Bs[buf][(w * 2 + i) * 512]);
        }
    };
    stage(0, 0); stage(1, 1);
    int cur = 0, pre = 2;
    for (int s = 0; s < 8; ++s) {
        if (s + 1 < 8) { PIPE_WAIT(4) } else { PIPE_WAIT(0) }
        if (s + 2 < 8) stage(pre, s + 2);
        bf16x8 af[4], bfv[4];
        #pragma unroll
        for (int i = 0; i < 4; ++i) af[i] = *(const bf16x8*)&As[cur][(wr + i * 16 + lr) * 32 + lk];
        #pragma unroll
        for (int j = 0; j < 4; ++j) bfv[j] = *(const bf16x8*)&Bs[cur][(wc + j * 16 + lr) * 32 + lk];
        #pragma unroll
        for (int i = 0; i < 4; ++i)
            #pragma unroll
            for (int j = 0; j < 4; ++j)
                acc[i][j] = __builtin_amdgcn_mfma_f32_16x16x32_bf16(af[i], bfv[j], acc[i][j], 0, 0, 0);
        pre = cur; cur = (cur == 2) ? 0 : cur + 1;
    }
    unsigned short* cb = corr + (size_t)b * 960 * 960;
    #pragma unroll
    for (int i = 0; i < 4; ++i)
        #pragma unroll
        for (int r = 0; r < 4; ++r) {
            int row = p0 + wr + i * 16 + (l >> 4) * 4 + r;
            if (row < 960) {
                #pragma unroll
                for (int j = 0; j < 4; ++j) {
                    int col = q0 + wc + j * 16 + lr;
                    if (col < 960)
                        cb[(size_t)row * 960 + col] = f2bf(fmaxf(acc[i][j][r], 0.f));
                }
            }
        }
}

// ======================= corr L2 norm: one wave per row ======================
__global__ __launch_bounds__(256) void k_corrnorm(unsigned short* __restrict__ corr) {
    const int t = threadIdx.x, wv = t >> 6, ln = t & 63;
    const int row = blockIdx.x * 4 + wv;       // 14400 rows, grid 3600
    const int b = row / 900, p = row - b * 900;
    ushort4* cp4 = (ushort4*)(corr + ((size_t)b * 960 + p) * 960);
    float x[16];
    float s = 0.f;
    #pragma unroll
    for (int i = 0; i < 4; ++i) {
        const int idx = ln + 64 * i;
        float v0 = 0.f, v1 = 0.f, v2 = 0.f, v3 = 0.f;
        if (idx < 225) {
            ushort4 u = cp4[idx];
            v0 = fmaxf(bf2f(u.x), 0.f); v1 = fmaxf(bf2f(u.y), 0.f);
            v2 = fmaxf(bf2f(u.z), 0.f); v3 = fmaxf(bf2f(u.w), 0.f);
        }
        x[i * 4 + 0] = v0; x[i * 4 + 1] = v1; x[i * 4 + 2] = v2; x[i * 4 + 3] = v3;
        s += v0 * v0 + v1 * v1 + v2 * v2 + v3 * v3;
    }
    #pragma unroll
    for (int m = 1; m < 64; m <<= 1) s += __shfl_xor(s, m);
    const float sc = 1.f / sqrtf(s + EPSF);
    #pragma unroll
    for (int i = 0; i < 4; ++i) {
        const int idx = ln + 64 * i;
        if (idx < 225) {
            ushort4 u;
            u.x = f2bf(x[i * 4 + 0] * sc); u.y = f2bf(x[i * 4 + 1] * sc);
            u.z = f2bf(x[i * 4 + 2] * sc); u.w = f2bf(x[i * 4 + 3] * sc);
            cp4[idx] = u;
        }
    }
}

// ======================= cw1 MFMA v4: phased schedule, 512x128 block =========
// M=9216 N=128; 8 waves of 128x64; BK=32/phase; 3-seg LDS ring; T2 swizzle;
// counted vmcnt(5); setprio around MFMA cluster. grid 252 = 18mt x 14ks.
__global__ __launch_bounds__(512, 2) void k_cw1(
        const unsigned short* __restrict__ corr, const unsigned short* __restrict__ Wt,
        unsigned short* __restrict__ part) {
    __shared__ __align__(16) unsigned short As[3 * 512 * 32];   // 96 KB
    __shared__ __align__(16) unsigned short Bs[3 * 128 * 32];   // 24 KB
    const int t = threadIdx.x, w = t >> 6, l = t & 63;
    const int bid = blockIdx.x;
    const int mt = bid % 18, ks = bid / 18;
    const int m0 = mt * 512;
    // staging: row = t>>2, phys chunk = t&3; fetch global chunk = (t&3)^((row>>1)&3)
    const int kswz = ((t & 3) ^ ((t >> 3) & 3)) * 8;
    size_t aga[4];
    #pragma unroll
    for (int i = 0; i < 4; ++i) {
        int r = i * 128 + (t >> 2);
        int m = m0 + r;
        int b = m / 576, rem = m - b * 576, oy = rem / 24, ox = rem - oy * 24;
        aga[i] = (size_t)(b * 960 + oy * 30 + ox) * 960 + kswz;
    }
    const size_t bga = (size_t)(t >> 2) * 45472 + kswz;
    // q-major K schedule: 1421 steps of 32; ks<7 get 102, else 101
    const int sbase = ks * 101 + min(ks, 7);
    const int nt = 101 + (ks < 7 ? 1 : 0);
    const int wm = (w >> 1) * 128, wn = (w & 1) * 64;
    const int lr = l & 15, cI = l >> 4;
    const int rsw = (cI ^ ((lr >> 1) & 3)) * 8;     // swizzled read chunk (elems)
    f32x4 acc[8][4] = {};
    auto stage = [&](int sidx) {
        const int seg = sidx % 3;
        const int s = sbase + sidx;
        const int qi = s / 49, sq = s - qi * 49;
        const int ky = sq / 7, kx = sq - ky * 7;
        const int aoff = (ky * 30 + kx) * 960 + qi * 32;
        const int boff = sq * 928 + qi * 32;
        #pragma unroll
        for (int i = 0; i < 4; ++i)
            gl16(corr + aga[i] + aoff, &As[seg * 16384 + i * 4096 + w * 512]);
        gl16(Wt + bga + boff, &Bs[seg * 4096 + w * 512]);
    };
    stage(0); stage(1);
    for (int s = 0; s < nt; ++s) {
        if (s + 1 < nt) {
            asm volatile("s_waitcnt vmcnt(5)" ::: "memory");
        } else {
            asm volatile("s_waitcnt vmcnt(0)" ::: "memory");
        }
        __builtin_amdgcn_sched_barrier(0);
        __builtin_amdgcn_s_barrier();
        __builtin_amdgcn_sched_barrier(0);
        const int seg = s % 3;
        bf16x8 af[8], bfv[4];
        #pragma unroll
        for (int i = 0; i < 8; ++i)
            af[i] = *(const bf16x8*)&As[seg * 16384 + (wm + i * 16 + lr) * 32 + rsw];
        #pragma unroll
        for (int j = 0; j < 4; ++j)
            bfv[j] = *(const bf16x8*)&Bs[seg * 4096 + (wn + j * 16 + lr) * 32 + rsw];
        if (s + 2 < nt) stage(s + 2);
        asm volatile("s_waitcnt lgkmcnt(0)" ::: "memory");
        __builtin_amdgcn_sched_barrier(0);
        __builtin_amdgcn_s_setprio(1);
        #pragma unroll
        for (int i = 0; i < 8; ++i)
            #pragma unroll
            for (int j = 0; j < 4; ++j)
                acc[i][j] = __builtin_amdgcn_mfma_f32_16x16x32_bf16(af[i], bfv[j], acc[i][j], 0, 0, 0);
        __builtin_amdgcn_s_setprio(0);
        __builtin_amdgcn_sched_barrier(0);
        __builtin_amdgcn_s_barrier();
        __builtin_amdgcn_sched_barrier(0);
    }
    unsigned short* pb = part + ((size_t)ks * 9216 + m0) * 128;
    #pragma unroll
    for (int i = 0; i < 8; ++i)
        #pragma unroll
        for (int r = 0; r < 4; ++r) {
            int row = wm + i * 16 + (l >> 4) * 4 + r;
            #pragma unroll
            for (int j = 0; j < 4; ++j)
                pb[(size_t)row * 128 + wn + j * 16 + lr] = f2h(acc[i][j][r]);
        }
}

// ======================= reduce 14 fp16 partials + bias + relu + BN -> bf16 ==
__global__ __launch_bounds__(256) void k_r1fin(
        const unsigned short* __restrict__ part, const float* __restrict__ cb1,
        const float* __restrict__ g1, const float* __restrict__ be1,
        const float* __restrict__ m1, const float* __restrict__ v1,
        unsigned short* __restrict__ r1) {
    const int idx = blockIdx.x * 256 + threadIdx.x;        // grid 1152
    const size_t base = (size_t)idx * 4;
    const size_t N = 9216 * 128;
    float s0 = 0.f, s1 = 0.f, s2 = 0.f, s3 = 0.f;
    #pragma unroll
    for (int i = 0; i < 14; ++i) {
        ushort4 u = *(const ushort4*)(part + i * N + base);
        s0 += h2f(u.x); s1 += h2f(u.y); s2 += h2f(u.z); s3 += h2f(u.w);
    }
    const int co = (int)(base & 127);
    float r[4] = {s0, s1, s2, s3};
    ushort4 o;
    unsigned short* op = (unsigned short*)&o;
    #pragma unroll
    for (int j = 0; j < 4; ++j) {
        int c = co + j;
        float x = fmaxf(r[j] + cb1[c], 0.f);
        x = (x - m1[c]) * (g1[c] / sqrtf(v1[c] + BN_EPSF)) + be1[c];
        op[j] = f2bf(x);
    }
    *(ushort4*)(r1 + base) = o;
}

// ======================= cw2 MFMA: M=6400 N=64 K=3200, K-split 4, fp32 part ==
__global__ __launch_bounds__(256) void k_cw2(
        const unsigned short* __restrict__ r1, const unsigned short* __restrict__ Wt2,
        float* __restrict__ partC) {
    __shared__ __align__(16) unsigned short As[3][64 * 32];
    __shared__ __align__(16) unsigned short Bs[3][64 * 32];
    const int t = threadIdx.x, w = t >> 6, l = t & 63;
    const int bid = blockIdx.x;                            // 400
    const int mtb = bid % 100, ks = bid / 100;
    const int m0 = mtb * 64;
    const int sbase = ks * 25;
    const int ko = (l & 3) * 8;
    const int wi = w & 1;
    size_t ga[2];
    #pragma unroll
    for (int i = 0; i < 2; ++i) {
        int r = (wi * 2 + i) * 16 + (l >> 2);
        if (w < 2) {
            int m = m0 + r;
            int b = m / 400, rem = m - b * 400, oy = rem / 20, ox = rem - oy * 20;
            ga[i] = (size_t)((b * 24 + oy) * 24 + ox) * 128 + ko;
        } else {
            ga[i] = (size_t)r * 3200 + ko;
        }
    }
    const int wr = (w >> 1) * 32, wc = (w & 1) * 32, lr = l & 15, lk = (l >> 4) * 8;
    f32x4 acc[2][2] = {};
    auto stage = [&](int buf, int sidx) {
        int s = sbase + sidx;
        int kyx = s >> 2, h = s & 3;
        int ky = kyx / 5, kx = kyx - ky * 5;
        int aoff = (ky * 24 + kx) * 128 + h * 32;
        int boff = s * 32;
        #pragma unroll
        for (int i = 0; i < 2; ++i) {
            unsigned short* dst = (w < 2) ? &As[buf][(wi * 2 + i) * 512]
                                          : &Bs[buf][(wi * 2 + i) * 512];
            const unsigned short* src = (w < 2) ? r1 + ga[i] + aoff : Wt2 + ga[i] + boff;
            gl16(src, dst);
        }
    };
    stage(0, 0); stage(1, 1);
    int cur = 0, pre = 2;
    for (int s = 0; s < 25; ++s) {
        if (s + 1 < 25) { PIPE_WAIT(2) } else { PIPE_WAIT(0) }
        if (s + 2 < 25) stage(pre, s + 2);
        bf16x8 af[2], bfv[2];
        #pragma unroll
        for (int i = 0; i < 2; ++i) af[i] = *(const bf16x8*)&As[cur][(wr + i * 16 + lr) * 32 + lk];
        #pragma unroll
        for (int j = 0; j < 2; ++j) bfv[j] = *(const bf16x8*)&Bs[cur][(wc + j * 16 + lr) * 32 + lk];
        #pragma unroll
        for (int i = 0; i < 2; ++i)
            #pragma unroll
            for (int j = 0; j < 2; ++j)
                acc[i][j] = __builtin_amdgcn_mfma_f32_16x16x32_bf16(af[i], bfv[j], acc[i][j], 0, 0, 0);
        pre = cur; cur = (cur == 2) ? 0 : cur + 1;
    }
    float* pc = partC + (size_t)ks * 409600;
    #pragma unroll
    for (int i = 0; i < 2; ++i)
        #pragma unroll
        for (int r = 0; r < 4; ++r) {
            int m = m0 + wr + i * 16 + (l >> 4) * 4 + r;
            #pragma unroll
            for (int j = 0; j < 2; ++j)
                pc[(size_t)m * 64 + wc + j * 16 + lr] = acc[i][j][r];
        }
}

// ======================= dense: fold cw2 finalize (bias/relu/BN) + matvec ====
__global__ __launch_bounds__(256) void k_dense(
        const float* __restrict__ partC, const float* __restrict__ cb2,
        const float* __restrict__ g2, const float* __restrict__ be2,
        const float* __restrict__ m2, const float* __restrict__ v2,
        const float* __restrict__ dw, float* __restrict__ partD) {
    const int b = blockIdx.x, kb = blockIdx.y, t = threadIdx.x;  // (16,5)
    const int co = t & 63;
    const float sc2 = g2[co] / sqrtf(v2[co] + BN_EPSF);
    const float sh2 = be2[co] - m2[co] * sc2;
    const float bb = cb2[co];
    float s[18] = {};
    for (int k = t; k < 5120; k += 256) {
        const int kk = kb * 5120 + k;
        const size_t pi = (size_t)(b * 400 + (kk >> 6)) * 64 + co;
        float p = partC[pi] + partC[pi + 409600] + partC[pi + 819200] + partC[pi + 1228800];
        p = fmaxf(p + bb, 0.f) * sc2 + sh2;
        const float* dr = dw + (size_t)kk * 18;
        #pragma unroll
        for (int j = 0; j < 18; ++j) s[j] = fmaf(p, dr[j], s[j]);
    }
    #pragma unroll
    for (int j = 0; j < 18; ++j)
        #pragma unroll
        for (int m = 1; m < 64; m <<= 1) s[j] += __shfl_xor(s[j], m);
    __shared__ float red[4][18];
    if ((t & 63) == 0) {
        #pragma unroll
        for (int j = 0; j < 18; ++j) red[t >> 6][j] = s[j];
    }
    __syncthreads();
    if (t < 18) partD[(b * 5 + kb) * 18 + t] = red[0][t] + red[1][t] + red[2][t] + red[3][t];
}
__global__ __launch_bounds__(288) void k_dfin(
        const float* __restrict__ partD, const float* __restrict__ db,
        float* __restrict__ out) {
    const int i = threadIdx.x;                 // 288
    const int b = i / 18, j = i - b * 18;
    float s = db[j];
    #pragma unroll
    for (int k = 0; k < 5; ++k) s += partD[(b * 5 + k) * 18 + j];
    out[i] = s;
}

extern "C" void kernel_launch(void* const* d_in, const int* in_sizes, int n_in,
                              void* d_out, int out_size, void* d_ws, size_t ws_size,
                              hipStream_t stream) {
    const float* imgA = (const float*)d_in[0];
    const float* imgB = (const float*)d_in[1];
    const float* w1  = (const float*)d_in[2];
    const float* b1  = (const float*)d_in[3];
    const float* w2  = (const float*)d_in[4];
    const float* b2  = (const float*)d_in[5];
    const float* w3  = (const float*)d_in[6];
    const float* b3  = (const float*)d_in[7];
    const float* cw1 = (const float*)d_in[8];
    const float* cb1 = (const float*)d_in[9];
    const float* g1  = (const float*)d_in[10];
    const float* be1 = (const float*)d_in[11];
    const float* m1  = (const float*)d_in[12];
    const float* v1  = (const float*)d_in[13];
    const float* cw2 = (const float*)d_in[14];
    const float* cb2 = (const float*)d_in[15];
    const float* g2  = (const float*)d_in[16];
    const float* be2 = (const float*)d_in[17];
    const float* m2  = (const float*)d_in[18];
    const float* v2  = (const float*)d_in[19];
    const float* dw  = (const float*)d_in[20];
    const float* db  = (const float*)d_in[21];

    // ws layout (bytes):
    //  conv phase : c1@0 (30.0MB) c2@29,984,768 (15.2MB) w2t@45,225,984
    //               w3t@45,373,440  feat@45,963,264 (16.8MB, [32][1024][256])
    //  corr phase : corr@0 (29.5MB)  Wt@29,491,200 (11.6MB)
    //  cw1 phase  : part@41,132,032 (33.0MB fp16 x14)
    //  tail       : r1@74,162,176 (2.4MB)  Wt2@76,521,472
    //               partC@41,132,032 (6.6MB, part dead)  partD@48,000,000
    char* ws = (char*)d_ws;
    unsigned short* c1   = (unsigned short*)(ws + 0);
    unsigned short* c2   = (unsigned short*)(ws + 29984768);
    unsigned short* w2t  = (unsigned short*)(ws + 45225984);
    unsigned short* w3t  = (unsigned short*)(ws + 45373440);
    unsigned short* feat = (unsigned short*)(ws + 45963264);
    unsigned short* corr = (unsigned short*)(ws + 0);
    unsigned short* Wt   = (unsigned short*)(ws + 29491200);
    unsigned short* part = (unsigned short*)(ws + 41132032);
    unsigned short* r1   = (unsigned short*)(ws + 74162176);
    unsigned short* Wt2  = (unsigned short*)(ws + 76521472);
    float*          partC= (float*)(ws + 41132032);
    float*          partD= (float*)(ws + 48000000);

    k_wx<<<dim3(2240), 256, 0, stream>>>(w2, w3, cw2, w2t, w3t, Wt2);

    for (int chunk = 0; chunk < 2; ++chunk) {
        const float* img = chunk ? imgB : imgA;
        const int f0 = chunk * 16;
        k_conv1<<<dim3(30, 120, 16), 256, 0, stream>>>(img, w1, b1, c1);
        k_conv2<<<dim3(450),         256, 0, stream>>>(c1, w2t, b2, c2);
        k_conv3<<<dim3(113, 4),      256, 0, stream>>>(c2, w3t, b3, feat, f0);
    }
    k_l2norm  <<<dim3(8192),  256, 0, stream>>>(feat);
    k_corr    <<<dim3(1024),  256, 0, stream>>>(feat, corr);
    k_corrnorm<<<dim3(3600),  256, 0, stream>>>(corr);
    k_wt1     <<<dim3(29, 49),256, 0, stream>>>(cw1, Wt);
    k_cw1     <<<dim3(252),   512, 0, stream>>>(corr, Wt, part);
    k_r1fin   <<<dim3(1152),  256, 0, stream>>>(part, cb1, g1, be1, m1, v1, r1);
    k_cw2     <<<dim3(400),   256, 0, stream>>>(r1, Wt2, partC);
    k_dense   <<<dim3(16, 5), 256, 0, stream>>>(partC, cb2, g2, be2, m2, v2, dw, partD);
    k_dfin    <<<dim3(1),     288, 0, stream>>>(partD, db, (float*)d_out);
}

// Round 9
// 435.985 us; speedup vs baseline: 15.3641x; 1.1172x over previous
//
#include <hip/hip_runtime.h>

#define EPSF    1e-6f
#define BN_EPSF 1e-3f

typedef __attribute__((ext_vector_type(8))) short bf16x8;   // 8 bf16 in 4 VGPRs
typedef __attribute__((ext_vector_type(4))) float f32x4;

__device__ __forceinline__ unsigned short f2bf(float f) {
    unsigned int u = __builtin_bit_cast(unsigned int, f);
    u = (u + 0x7FFFu + ((u >> 16) & 1u)) >> 16;            // RNE
    return (unsigned short)u;
}
__device__ __forceinline__ float bf2f(unsigned short h) {
    unsigned int u = ((unsigned int)h) << 16;
    return __builtin_bit_cast(float, u);
}
__device__ __forceinline__ unsigned short f2h(float f) {
    return __builtin_bit_cast(unsigned short, (_Float16)f);
}
__device__ __forceinline__ float h2f(unsigned short h) {
    return (float)__builtin_bit_cast(_Float16, h);
}
// async global->LDS, 16 bytes per lane; lds dest is wave-uniform base + lane*16
__device__ __forceinline__ void gl16(const void* g, void* l) {
    __builtin_amdgcn_global_load_lds((const __attribute__((address_space(1))) void*)g,
                                     (__attribute__((address_space(3))) void*)l, 16, 0, 0);
}
// counted-vmcnt barrier pair (2-phase kernels)
#define PIPE_WAIT(N)                                        \
    asm volatile("s_waitcnt vmcnt(" #N ")" ::: "memory");   \
    __builtin_amdgcn_sched_barrier(0);                      \
    __builtin_amdgcn_s_barrier();                           \
    __builtin_amdgcn_sched_barrier(0);

// ======================= merged weight conversions (w2t | w3t | wt2) =========
__global__ __launch_bounds__(256) void k_wx(
        const float* __restrict__ w2, const float* __restrict__ w3,
        const float* __restrict__ cw2w,
        unsigned short* __restrict__ w2t, unsigned short* __restrict__ w3t,
        unsigned short* __restrict__ wt2) {
    const int bid = blockIdx.x;                            // 2240
    if (bid < 288) {
        int idx = bid * 256 + threadIdx.x;                 // 73728
        int n = idx / 576, k = idx - n * 576;
        w2t[idx] = f2bf(w2[(size_t)k * 128 + n]);
    } else if (bid < 1440) {
        int idx = (bid - 288) * 256 + threadIdx.x;         // 294912
        int n = idx / 1152, k = idx - n * 1152;
        w3t[idx] = f2bf(w3[(size_t)k * 256 + n]);
    } else {
        int idx = (bid - 1440) * 256 + threadIdx.x;        // 204800
        int n = idx / 3200, k = idx - n * 3200;
        wt2[idx] = f2bf(cw2w[(size_t)k * 64 + n]);
    }
}
// Wt[n][k'], k'=s*928+q, zero for q>=900; coalesced LDS transpose. grid (29,49)
__global__ __launch_bounds__(256) void k_wt1(const float* __restrict__ W,
                                             unsigned short* __restrict__ Wt) {
    __shared__ float tile[32][132];
    const int s = blockIdx.y;              // 49
    const int q0 = blockIdx.x * 32;        // 0..896
    const int t = threadIdx.x;
    const int n = t & 127, rr = t >> 7;
    #pragma unroll
    for (int r = rr; r < 32; r += 2) {
        int q = q0 + r;
        tile[r][n] = (q < 900) ? W[((size_t)(s * 900 + q)) * 128 + n] : 0.f;
    }
    __syncthreads();
    const int n2 = t >> 1, half = t & 1;
    unsigned short* dst = Wt + (size_t)n2 * 45472 + s * 928 + q0 + half * 16;
    #pragma unroll
    for (int u = 0; u < 16; ++u) dst[u] = f2bf(tile[half * 16 + u][n2]);
}

// ======================= conv1 v2: reg-tiled 8-wide strip, weights in regs ===
// grid (15, 30, 16) x 256 thr; wave wv handles row oy = by*4+wv, lanes = co
__global__ __launch_bounds__(256) void k_conv1(
        const float* __restrict__ img,
        const float* __restrict__ w, const float* __restrict__ bias,
        unsigned short* __restrict__ c1) {
    const int co = threadIdx.x & 63, wv = threadIdx.x >> 6;
    const int x0 = blockIdx.x * 8;                         // 0..112
    const int oy = blockIdx.y * 4 + wv;                    // 0..119
    const int b  = blockIdx.z;                             // 16
    // 27 weights in registers (coalesced over co, L1-hot after first block)
    float wr[9][3];
    #pragma unroll
    for (int s = 0; s < 9; ++s)
        #pragma unroll
        for (int c = 0; c < 3; ++c)
            wr[s][c] = w[(s * 3 + c) * 64 + co];
    float acc[8];
    const float bb = bias[co];
    #pragma unroll
    for (int u = 0; u < 8; ++u) acc[u] = bb;
    #pragma unroll
    for (int ky = 0; ky < 3; ++ky) {
        const int iy = 2 * oy + ky;
        if (iy >= 240) continue;
        const float* row = img + (size_t)(b * 240 + iy) * 240 * 3;
        float iv[17][3];
        #pragma unroll
        for (int p = 0; p < 17; ++p) {
            const int ix = 2 * x0 + p;
            if (ix < 240) {
                iv[p][0] = row[ix * 3 + 0];
                iv[p][1] = row[ix * 3 + 1];
                iv[p][2] = row[ix * 3 + 2];
            } else {
                iv[p][0] = 0.f; iv[p][1] = 0.f; iv[p][2] = 0.f;
            }
        }
        #pragma unroll
        for (int u = 0; u < 8; ++u)
            #pragma unroll
            for (int kx = 0; kx < 3; ++kx)
                #pragma unroll
                for (int c = 0; c < 3; ++c)
                    acc[u] = fmaf(iv[2 * u + kx][c], wr[ky * 3 + kx][c], acc[u]);
    }
    unsigned short* orow = c1 + ((size_t)(b * 121 + oy) * 121 + x0) * 64 + co;
    #pragma unroll
    for (int u = 0; u < 8; ++u)
        orow[(size_t)u * 64] = f2bf(fmaxf(acc[u], 0.f));
    // fused zero-padding of row/col 120
    if (x0 == 112)                                         // this block owns ox=119
        c1[((size_t)(b * 121 + oy) * 121 + 120) * 64 + co] = 0;
    if (oy == 119) {
        #pragma unroll
        for (int u = 0; u < 8; ++u)
            c1[((size_t)(b * 121 + 120) * 121 + x0 + u) * 64 + co] = 0;
        if (x0 == 112)
            c1[((size_t)(b * 121 + 120) * 121 + 120) * 64 + co] = 0;
    }
}

// ======================= conv2 MFMA: M=57600 N=128 K=576 (3-buf pipeline) ====
__global__ __launch_bounds__(256) void k_conv2(
        const unsigned short* __restrict__ c1, const unsigned short* __restrict__ w2t,
        const float* __restrict__ b2, unsigned short* __restrict__ c2) {
    __shared__ __align__(16) unsigned short As[3][128 * 32];
    __shared__ __align__(16) unsigned short Bs[3][128 * 32];
    const int t = threadIdx.x, w = t >> 6, l = t & 63;
    const int m0 = blockIdx.x * 128;                       // grid 450
    const int ko = (l & 3) * 8;
    size_t aga[2], bga[2];
    #pragma unroll
    for (int i = 0; i < 2; ++i) {
        int r = (w * 2 + i) * 16 + (l >> 2);
        int m = m0 + r;
        int bl = m / 3600, rem = m - bl * 3600, oy = rem / 60, ox = rem - oy * 60;
        aga[i] = (size_t)((bl * 121 + 2 * oy) * 121 + 2 * ox) * 64 + ko;
        bga[i] = (size_t)r * 576 + ko;
    }
    const int wr = (w >> 1) * 64, wc = (w & 1) * 64, lr = l & 15, lk = (l >> 4) * 8;
    f32x4 acc[4][4] = {};
    auto stage = [&](int buf, int s) {
        int ky = s / 6, r6 = s - ky * 6, kx = r6 >> 1, h = r6 & 1;
        int aoff = (ky * 121 + kx) * 64 + h * 32;
        int boff = (ky * 3 + kx) * 64 + h * 32;
        #pragma unroll
        for (int i = 0; i < 2; ++i) {
            gl16(c1 + aga[i] + aoff, &As[buf][(w * 2 + i) * 512]);
            gl16(w2t + bga[i] + boff, &Bs[buf][(w * 2 + i) * 512]);
        }
    };
    stage(0, 0); stage(1, 1);
    int cur = 0, pre = 2;
    for (int s = 0; s < 18; ++s) {
        if (s + 1 < 18) { PIPE_WAIT(4) } else { PIPE_WAIT(0) }
        if (s + 2 < 18) stage(pre, s + 2);
        bf16x8 af[4], bfv[4];
        #pragma unroll
        for (int i = 0; i < 4; ++i) af[i] = *(const bf16x8*)&As[cur][(wr + i * 16 + lr) * 32 + lk];
        #pragma unroll
        for (int j = 0; j < 4; ++j) bfv[j] = *(const bf16x8*)&Bs[cur][(wc + j * 16 + lr) * 32 + lk];
        #pragma unroll
        for (int i = 0; i < 4; ++i)
            #pragma unroll
            for (int j = 0; j < 4; ++j)
                acc[i][j] = __builtin_amdgcn_mfma_f32_16x16x32_bf16(af[i], bfv[j], acc[i][j], 0, 0, 0);
        pre = cur; cur = (cur == 2) ? 0 : cur + 1;
    }
    float bias[4];
    #pragma unroll
    for (int j = 0; j < 4; ++j) bias[j] = b2[wc + j * 16 + lr];
    #pragma unroll
    for (int i = 0; i < 4; ++i)
        #pragma unroll
        for (int r = 0; r < 4; ++r) {
            int m = m0 + wr + i * 16 + (l >> 4) * 4 + r;
            int bl = m / 3600, rem = m - bl * 3600, oy = rem / 60, ox = rem - oy * 60;
            size_t ob = (size_t)((bl * 61 + oy) * 61 + ox) * 128;
            #pragma unroll
            for (int j = 0; j < 4; ++j)
                c2[ob + wc + j * 16 + lr] = f2bf(fmaxf(acc[i][j][r] + bias[j], 0.f));
            const bool bx = (ox == 59), by = (oy == 59);
            if (bx) {
                size_t zb = (size_t)((bl * 61 + oy) * 61 + 60) * 128;
                #pragma unroll
                for (int j = 0; j < 4; ++j) c2[zb + wc + j * 16 + lr] = 0;
            }
            if (by) {
                size_t zb = (size_t)((bl * 61 + 60) * 61 + ox) * 128;
                #pragma unroll
                for (int j = 0; j < 4; ++j) c2[zb + wc + j * 16 + lr] = 0;
            }
            if (bx && by) {
                size_t zb = (size_t)((bl * 61 + 60) * 61 + 60) * 128;
                #pragma unroll
                for (int j = 0; j < 4; ++j) c2[zb + wc + j * 16 + lr] = 0;
            }
        }
}

// ======================= conv3 MFMA: M=14400 N=256 K=1152 (3-buf) ============
// feat padded to [32][1024][256]
__global__ __launch_bounds__(256) void k_conv3(
        const unsigned short* __restrict__ c2, const unsigned short* __restrict__ w3t,
        const float* __restrict__ b3, unsigned short* __restrict__ feat, int f0) {
    __shared__ __align__(16) unsigned short As[3][128 * 32];
    __shared__ __align__(16) unsigned short Bs[3][64 * 32];
    const int t = threadIdx.x, w = t >> 6, l = t & 63;
    const int m0 = blockIdx.x * 128, n0 = blockIdx.y * 64;   // grid (113,4)
    const int ko = (l & 3) * 8;
    size_t aga[2], bga;
    #pragma unroll
    for (int i = 0; i < 2; ++i) {
        int r = (w * 2 + i) * 16 + (l >> 2);
        int m = min(m0 + r, 14399);
        int bl = m / 900, rem = m - bl * 900, oy = rem / 30, ox = rem - oy * 30;
        aga[i] = (size_t)((bl * 61 + 2 * oy) * 61 + 2 * ox) * 128 + ko;
    }
    { int n = n0 + w * 16 + (l >> 2); bga = (size_t)n * 1152 + ko; }
    const int wr = (w >> 1) * 64, wc = (w & 1) * 32, lr = l & 15, lk = (l >> 4) * 8;
    f32x4 acc[4][2] = {};
    auto stage = [&](int buf, int s) {
        int ky = s / 12, r12 = s - ky * 12, kx = r12 >> 2, h = r12 & 3;
        int aoff = (ky * 61 + kx) * 128 + h * 32;
        int boff = (ky * 3 + kx) * 128 + h * 32;
        #pragma unroll
        for (int i = 0; i < 2; ++i)
            gl16(c2 + aga[i] + aoff, &As[buf][(w * 2 + i) * 512]);
        gl16(w3t + bga + boff, &Bs[buf][w * 512]);
    };
    stage(0, 0); stage(1, 1);
    int cur = 0, pre = 2;
    for (int s = 0; s < 36; ++s) {
        if (s + 1 < 36) { PIPE_WAIT(3) } else { PIPE_WAIT(0) }
        if (s + 2 < 36) stage(pre, s + 2);
        bf16x8 af[4], bfv[2];
        #pragma unroll
        for (int i = 0; i < 4; ++i) af[i] = *(const bf16x8*)&As[cur][(wr + i * 16 + lr) * 32 + lk];
        #pragma unroll
        for (int j = 0; j < 2; ++j) bfv[j] = *(const bf16x8*)&Bs[cur][(wc + j * 16 + lr) * 32 + lk];
        #pragma unroll
        for (int i = 0; i < 4; ++i)
            #pragma unroll
            for (int j = 0; j < 2; ++j)
                acc[i][j] = __builtin_amdgcn_mfma_f32_16x16x32_bf16(af[i], bfv[j], acc[i][j], 0, 0, 0);
        pre = cur; cur = (cur == 2) ? 0 : cur + 1;
    }
    float bias[2];
    #pragma unroll
    for (int j = 0; j < 2; ++j) bias[j] = b3[n0 + wc + j * 16 + lr];
    #pragma unroll
    for (int i = 0; i < 4; ++i)
        #pragma unroll
        for (int r = 0; r < 4; ++r) {
            int m = m0 + wr + i * 16 + (l >> 4) * 4 + r;
            if (m < 14400) {
                int bl = m / 900, pos = m - bl * 900;
                size_t ob = ((size_t)(f0 + bl) * 1024 + pos) * 256;
                #pragma unroll
                for (int j = 0; j < 2; ++j)
                    feat[ob + n0 + wc + j * 16 + lr] = f2bf(fmaxf(acc[i][j][r] + bias[j], 0.f));
            }
        }
}

// ======================= l2norm: wave per row, rows 900..1023 zeroed =========
__global__ __launch_bounds__(256) void k_l2norm(unsigned short* __restrict__ feat) {
    const int t = threadIdx.x, wv = t >> 6, ln = t & 63;
    const int R = blockIdx.x * 4 + wv;             // 32768 rows, grid 8192
    const int pos = R & 1023;
    ushort4* fp4 = (ushort4*)(feat + (size_t)R * 256);
    if (pos >= 900) { fp4[ln] = make_ushort4(0, 0, 0, 0); return; }
    ushort4 u = fp4[ln];
    float x0 = bf2f(u.x), x1 = bf2f(u.y), x2 = bf2f(u.z), x3 = bf2f(u.w);
    float s = x0 * x0 + x1 * x1 + x2 * x2 + x3 * x3;
    #pragma unroll
    for (int m = 1; m < 64; m <<= 1) s += __shfl_xor(s, m);
    const float inv = 1.f / sqrtf(s + EPSF);
    u.x = f2bf(x0 * inv); u.y = f2bf(x1 * inv);
    u.z = f2bf(x2 * inv); u.w = f2bf(x3 * inv);
    fp4[ln] = u;
}

// ======================= corr MFMA: per-b 1024x1024 padded, 128-tile =========
__global__ __launch_bounds__(256) void k_corr(
        const unsigned short* __restrict__ feat, unsigned short* __restrict__ corr) {
    __shared__ __align__(16) unsigned short As[3][128 * 32];
    __shared__ __align__(16) unsigned short Bs[3][128 * 32];
    const int t = threadIdx.x, w = t >> 6, l = t & 63;
    const int id0 = blockIdx.x;                            // 1024
    const int sw = (id0 & 7) * 128 + (id0 >> 3);           // bijective XCD swizzle
    const int b = sw >> 6, rem = sw & 63;
    const int p0 = (rem >> 3) * 128, q0 = (rem & 7) * 128;
    const int ko = (l & 3) * 8;
    const unsigned short* fA = feat + (size_t)b * 1024 * 256;
    const unsigned short* fB = feat + (size_t)(16 + b) * 1024 * 256;
    size_t aga[2], bga[2];
    #pragma unroll
    for (int i = 0; i < 2; ++i) {
        int r = (w * 2 + i) * 16 + (l >> 2);
        aga[i] = (size_t)(p0 + r) * 256 + ko;
        bga[i] = (size_t)(q0 + r) * 256 + ko;
    }
    const int wr = (w >> 1) * 64, wc = (w & 1) * 64, lr = l & 15, lk = (l >> 4) * 8;
    f32x4 acc[4][4] = {};
    auto stage = [&](int buf, int s) {
        #pragma unroll
        for (int i = 0; i < 2; ++i) {
            gl16(fA + aga[i] + s * 32, &As[buf][(w * 2 + i) * 512]);
            gl16(fB + bga[i] + s * 32, &Bs[buf][(w * 2 + i) * 512]);
        }
    };
    stage(0, 0); stage(1, 1);
    int cur = 0, pre = 2;
    for (int s = 0; s < 8; ++s) {
        if (s + 1 < 8) { PIPE_WAIT(4) } else { PIPE_WAIT(0) }
        if (s + 2 < 8) stage(pre, s + 2);
        bf16x8 af[4], bfv[4];
        #pragma unroll
        for (int i = 0; i < 4; ++i) af[i] = *(const bf16x8*)&As[cur][(wr + i * 16 + lr) * 32 + lk];
        #pragma unroll
        for (int j = 0; j < 4; ++j) bfv[j] = *(const bf16x8*)&Bs[cur][(wc + j * 16 + lr) * 32 + lk];
        #pragma unroll
        for (int i = 0; i < 4; ++i)
            #pragma unroll
            for (int j = 0; j < 4; ++j)
                acc[i][j] = __builtin_amdgcn_mfma_f32_16x16x32_bf16(af[i], bfv[j], acc[i][j], 0, 0, 0);
        pre = cur; cur = (cur == 2) ? 0 : cur + 1;
    }
    unsigned short* cb = corr + (size_t)b * 960 * 960;
    #pragma unroll
    for (int i = 0; i < 4; ++i)
        #pragma unroll
        for (int r = 0; r < 4; ++r) {
            int row = p0 + wr + i * 16 + (l >> 4) * 4 + r;
            if (row < 960) {
                #pragma unroll
                for (int j = 0; j < 4; ++j) {
                    int col = q0 + wc + j * 16 + lr;
                    if (col < 960)
                        cb[(size_t)row * 960 + col] = f2bf(fmaxf(acc[i][j][r], 0.f));
                }
            }
        }
}

// ======================= corr L2 norm: one wave per row ======================
__global__ __launch_bounds__(256) void k_corrnorm(unsigned short* __restrict__ corr) {
    const int t = threadIdx.x, wv = t >> 6, ln = t & 63;
    const int row = blockIdx.x * 4 + wv;       // 14400 rows, grid 3600
    const int b = row / 900, p = row - b * 900;
    ushort4* cp4 = (ushort4*)(corr + ((size_t)b * 960 + p) * 960);
    float x[16];
    float s = 0.f;
    #pragma unroll
    for (int i = 0; i < 4; ++i) {
        const int idx = ln + 64 * i;
        float v0 = 0.f, v1 = 0.f, v2 = 0.f, v3 = 0.f;
        if (idx < 225) {
            ushort4 u = cp4[idx];
            v0 = fmaxf(bf2f(u.x), 0.f); v1 = fmaxf(bf2f(u.y), 0.f);
            v2 = fmaxf(bf2f(u.z), 0.f); v3 = fmaxf(bf2f(u.w), 0.f);
        }
        x[i * 4 + 0] = v0; x[i * 4 + 1] = v1; x[i * 4 + 2] = v2; x[i * 4 + 3] = v3;
        s += v0 * v0 + v1 * v1 + v2 * v2 + v3 * v3;
    }
    #pragma unroll
    for (int m = 1; m < 64; m <<= 1) s += __shfl_xor(s, m);
    const float sc = 1.f / sqrtf(s + EPSF);
    #pragma unroll
    for (int i = 0; i < 4; ++i) {
        const int idx = ln + 64 * i;
        if (idx < 225) {
            ushort4 u;
            u.x = f2bf(x[i * 4 + 0] * sc); u.y = f2bf(x[i * 4 + 1] * sc);
            u.z = f2bf(x[i * 4 + 2] * sc); u.w = f2bf(x[i * 4 + 3] * sc);
            cp4[idx] = u;
        }
    }
}

// ======================= cw1 MFMA v4: phased schedule, 512x128 block =========
// M=9216 N=128; 8 waves of 128x64; BK=32/phase; 3-seg LDS ring; T2 swizzle;
// counted vmcnt(5); setprio around MFMA cluster. grid 252 = 18mt x 14ks.
__global__ __launch_bounds__(512, 2) void k_cw1(
        const unsigned short* __restrict__ corr, const unsigned short* __restrict__ Wt,
        unsigned short* __restrict__ part) {
    __shared__ __align__(16) unsigned short As[3 * 512 * 32];   // 96 KB
    __shared__ __align__(16) unsigned short Bs[3 * 128 * 32];   // 24 KB
    const int t = threadIdx.x, w = t >> 6, l = t & 63;
    const int bid = blockIdx.x;
    const int mt = bid % 18, ks = bid / 18;
    const int m0 = mt * 512;
    // staging: row = t>>2, phys chunk = t&3; fetch global chunk = (t&3)^((row>>1)&3)
    const int kswz = ((t & 3) ^ ((t >> 3) & 3)) * 8;
    size_t aga[4];
    #pragma unroll
    for (int i = 0; i < 4; ++i) {
        int r = i * 128 + (t >> 2);
        int m = m0 + r;
        int b = m / 576, rem = m - b * 576, oy = rem / 24, ox = rem - oy * 24;
        aga[i] = (size_t)(b * 960 + oy * 30 + ox) * 960 + kswz;
    }
    const size_t bga = (size_t)(t >> 2) * 45472 + kswz;
    // q-major K schedule: 1421 steps of 32; ks<7 get 102, else 101
    const int sbase = ks * 101 + min(ks, 7);
    const int nt = 101 + (ks < 7 ? 1 : 0);
    const int wm = (w >> 1) * 128, wn = (w & 1) * 64;
    const int lr = l & 15, cI = l >> 4;
    const int rsw = (cI ^ ((lr >> 1) & 3)) * 8;     // swizzled read chunk (elems)
    f32x4 acc[8][4] = {};
    auto stage = [&](int sidx) {
        const int seg = sidx % 3;
        const int s = sbase + sidx;
        const int qi = s / 49, sq = s - qi * 49;
        const int ky = sq / 7, kx = sq - ky * 7;
        const int aoff = (ky * 30 + kx) * 960 + qi * 32;
        const int boff = sq * 928 + qi * 32;
        #pragma unroll
        for (int i = 0; i < 4; ++i)
            gl16(corr + aga[i] + aoff, &As[seg * 16384 + i * 4096 + w * 512]);
        gl16(Wt + bga + boff, &Bs[seg * 4096 + w * 512]);
    };
    stage(0); stage(1);
    for (int s = 0; s < nt; ++s) {
        if (s + 1 < nt) {
            asm volatile("s_waitcnt vmcnt(5)" ::: "memory");
        } else {
            asm volatile("s_waitcnt vmcnt(0)" ::: "memory");
        }
        __builtin_amdgcn_sched_barrier(0);
        __builtin_amdgcn_s_barrier();
        __builtin_amdgcn_sched_barrier(0);
        const int seg = s % 3;
        bf16x8 af[8], bfv[4];
        #pragma unroll
        for (int i = 0; i < 8; ++i)
            af[i] = *(const bf16x8*)&As[seg * 16384 + (wm + i * 16 + lr) * 32 + rsw];
        #pragma unroll
        for (int j = 0; j < 4; ++j)
            bfv[j] = *(const bf16x8*)&Bs[seg * 4096 + (wn + j * 16 + lr) * 32 + rsw];
        if (s + 2 < nt) stage(s + 2);
        asm volatile("s_waitcnt lgkmcnt(0)" ::: "memory");
        __builtin_amdgcn_sched_barrier(0);
        __builtin_amdgcn_s_setprio(1);
        #pragma unroll
        for (int i = 0; i < 8; ++i)
            #pragma unroll
            for (int j = 0; j < 4; ++j)
                acc[i][j] = __builtin_amdgcn_mfma_f32_16x16x32_bf16(af[i], bfv[j], acc[i][j], 0, 0, 0);
        __builtin_amdgcn_s_setprio(0);
        __builtin_amdgcn_sched_barrier(0);
        __builtin_amdgcn_s_barrier();
        __builtin_amdgcn_sched_barrier(0);
    }
    unsigned short* pb = part + ((size_t)ks * 9216 + m0) * 128;
    #pragma unroll
    for (int i = 0; i < 8; ++i)
        #pragma unroll
        for (int r = 0; r < 4; ++r) {
            int row = wm + i * 16 + (l >> 4) * 4 + r;
            #pragma unroll
            for (int j = 0; j < 4; ++j)
                pb[(size_t)row * 128 + wn + j * 16 + lr] = f2h(acc[i][j][r]);
        }
}

// ======================= reduce 14 fp16 partials + bias + relu + BN -> bf16 ==
__global__ __launch_bounds__(256) void k_r1fin(
        const unsigned short* __restrict__ part, const float* __restrict__ cb1,
        const float* __restrict__ g1, const float* __restrict__ be1,
        const float* __restrict__ m1, const float* __restrict__ v1,
        unsigned short* __restrict__ r1) {
    const int idx = blockIdx.x * 256 + threadIdx.x;        // grid 1152
    const size_t base = (size_t)idx * 4;
    const size_t N = 9216 * 128;
    float s0 = 0.f, s1 = 0.f, s2 = 0.f, s3 = 0.f;
    #pragma unroll
    for (int i = 0; i < 14; ++i) {
        ushort4 u = *(const ushort4*)(part + i * N + base);
        s0 += h2f(u.x); s1 += h2f(u.y); s2 += h2f(u.z); s3 += h2f(u.w);
    }
    const int co = (int)(base & 127);
    float r[4] = {s0, s1, s2, s3};
    ushort4 o;
    unsigned short* op = (unsigned short*)&o;
    #pragma unroll
    for (int j = 0; j < 4; ++j) {
        int c = co + j;
        float x = fmaxf(r[j] + cb1[c], 0.f);
        x = (x - m1[c]) * (g1[c] / sqrtf(v1[c] + BN_EPSF)) + be1[c];
        op[j] = f2bf(x);
    }
    *(ushort4*)(r1 + base) = o;
}

// ======================= cw2 MFMA: M=6400 N=64 K=3200, K-split 4, fp32 part ==
__global__ __launch_bounds__(256) void k_cw2(
        const unsigned short* __restrict__ r1, const unsigned short* __restrict__ Wt2,
        float* __restrict__ partC) {
    __shared__ __align__(16) unsigned short As[3][64 * 32];
    __shared__ __align__(16) unsigned short Bs[3][64 * 32];
    const int t = threadIdx.x, w = t >> 6, l = t & 63;
    const int bid = blockIdx.x;                            // 400
    const int mtb = bid % 100, ks = bid / 100;
    const int m0 = mtb * 64;
    const int sbase = ks * 25;
    const int ko = (l & 3) * 8;
    const int wi = w & 1;
    size_t ga[2];
    #pragma unroll
    for (int i = 0; i < 2; ++i) {
        int r = (wi * 2 + i) * 16 + (l >> 2);
        if (w < 2) {
            int m = m0 + r;
            int b = m / 400, rem = m - b * 400, oy = rem / 20, ox = rem - oy * 20;
            ga[i] = (size_t)((b * 24 + oy) * 24 + ox) * 128 + ko;
        } else {
            ga[i] = (size_t)r * 3200 + ko;
        }
    }
    const int wr = (w >> 1) * 32, wc = (w & 1) * 32, lr = l & 15, lk = (l >> 4) * 8;
    f32x4 acc[2][2] = {};
    auto stage = [&](int buf, int sidx) {
        int s = sbase + sidx;
        int kyx = s >> 2, h = s & 3;
        int ky = kyx / 5, kx = kyx - ky * 5;
        int aoff = (ky * 24 + kx) * 128 + h * 32;
        int boff = s * 32;
        #pragma unroll
        for (int i = 0; i < 2; ++i) {
            unsigned short* dst = (w < 2) ? &As[buf][(wi * 2 + i) * 512]
                                          : &Bs[buf][(wi * 2 + i) * 512];
            const unsigned short* src = (w < 2) ? r1 + ga[i] + aoff : Wt2 + ga[i] + boff;
            gl16(src, dst);
        }
    };
    stage(0, 0); stage(1, 1);
    int cur = 0, pre = 2;
    for (int s = 0; s < 25; ++s) {
        if (s + 1 < 25) { PIPE_WAIT(2) } else { PIPE_WAIT(0) }
        if (s + 2 < 25) stage(pre, s + 2);
        bf16x8 af[2], bfv[2];
        #pragma unroll
        for (int i = 0; i < 2; ++i) af[i] = *(const bf16x8*)&As[cur][(wr + i * 16 + lr) * 32 + lk];
        #pragma unroll
        for (int j = 0; j < 2; ++j) bfv[j] = *(const bf16x8*)&Bs[cur][(wc + j * 16 + lr) * 32 + lk];
        #pragma unroll
        for (int i = 0; i < 2; ++i)
            #pragma unroll
            for (int j = 0; j < 2; ++j)
                acc[i][j] = __builtin_amdgcn_mfma_f32_16x16x32_bf16(af[i], bfv[j], acc[i][j], 0, 0, 0);
        pre = cur; cur = (cur == 2) ? 0 : cur + 1;
    }
    float* pc = partC + (size_t)ks * 409600;
    #pragma unroll
    for (int i = 0; i < 2; ++i)
        #pragma unroll
        for (int r = 0; r < 4; ++r) {
            int m = m0 + wr + i * 16 + (l >> 4) * 4 + r;
            #pragma unroll
            for (int j = 0; j < 2; ++j)
                pc[(size_t)m * 64 + wc + j * 16 + lr] = acc[i][j][r];
        }
}

// ======================= dense: fold cw2 finalize (bias/relu/BN) + matvec ====
__global__ __launch_bounds__(256) void k_dense(
        const float* __restrict__ partC, const float* __restrict__ cb2,
        const float* __restrict__ g2, const float* __restrict__ be2,
        const float* __restrict__ m2, const float* __restrict__ v2,
        const float* __restrict__ dw, float* __restrict__ partD) {
    const int b = blockIdx.x, kb = blockIdx.y, t = threadIdx.x;  // (16,5)
    const int co = t & 63;
    const float sc2 = g2[co] / sqrtf(v2[co] + BN_EPSF);
    const float sh2 = be2[co] - m2[co] * sc2;
    const float bb = cb2[co];
    float s[18] = {};
    for (int k = t; k < 5120; k += 256) {
        const int kk = kb * 5120 + k;
        const size_t pi = (size_t)(b * 400 + (kk >> 6)) * 64 + co;
        float p = partC[pi] + partC[pi + 409600] + partC[pi + 819200] + partC[pi + 1228800];
        p = fmaxf(p + bb, 0.f) * sc2 + sh2;
        const float* dr = dw + (size_t)kk * 18;
        #pragma unroll
        for (int j = 0; j < 18; ++j) s[j] = fmaf(p, dr[j], s[j]);
    }
    #pragma unroll
    for (int j = 0; j < 18; ++j)
        #pragma unroll
        for (int m = 1; m < 64; m <<= 1) s[j] += __shfl_xor(s[j], m);
    __shared__ float red[4][18];
    if ((t & 63) == 0) {
        #pragma unroll
        for (int j = 0; j < 18; ++j) red[t >> 6][j] = s[j];
    }
    __syncthreads();
    if (t < 18) partD[(b * 5 + kb) * 18 + t] = red[0][t] + red[1][t] + red[2][t] + red[3][t];
}
__global__ __launch_bounds__(288) void k_dfin(
        const float* __restrict__ partD, const float* __restrict__ db,
        float* __restrict__ out) {
    const int i = threadIdx.x;                 // 288
    const int b = i / 18, j = i - b * 18;
    float s = db[j];
    #pragma unroll
    for (int k = 0; k < 5; ++k) s += partD[(b * 5 + k) * 18 + j];
    out[i] = s;
}

extern "C" void kernel_launch(void* const* d_in, const int* in_sizes, int n_in,
                              void* d_out, int out_size, void* d_ws, size_t ws_size,
                              hipStream_t stream) {
    const float* imgA = (const float*)d_in[0];
    const float* imgB = (const float*)d_in[1];
    const float* w1  = (const float*)d_in[2];
    const float* b1  = (const float*)d_in[3];
    const float* w2  = (const float*)d_in[4];
    const float* b2  = (const float*)d_in[5];
    const float* w3  = (const float*)d_in[6];
    const float* b3  = (const float*)d_in[7];
    const float* cw1 = (const float*)d_in[8];
    const float* cb1 = (const float*)d_in[9];
    const float* g1  = (const float*)d_in[10];
    const float* be1 = (const float*)d_in[11];
    const float* m1  = (const float*)d_in[12];
    const float* v1  = (const float*)d_in[13];
    const float* cw2 = (const float*)d_in[14];
    const float* cb2 = (const float*)d_in[15];
    const float* g2  = (const float*)d_in[16];
    const float* be2 = (const float*)d_in[17];
    const float* m2  = (const float*)d_in[18];
    const float* v2  = (const float*)d_in[19];
    const float* dw  = (const float*)d_in[20];
    const float* db  = (const float*)d_in[21];

    // ws layout (bytes):
    //  conv phase : c1@0 (30.0MB) c2@29,984,768 (15.2MB) w2t@45,225,984
    //               w3t@45,373,440  feat@45,963,264 (16.8MB, [32][1024][256])
    //  corr phase : corr@0 (29.5MB)  Wt@29,491,200 (11.6MB)
    //  cw1 phase  : part@41,132,032 (33.0MB fp16 x14)
    //  tail       : r1@74,162,176 (2.4MB)  Wt2@76,521,472
    //               partC@41,132,032 (6.6MB, part dead)  partD@48,000,000
    char* ws = (char*)d_ws;
    unsigned short* c1   = (unsigned short*)(ws + 0);
    unsigned short* c2   = (unsigned short*)(ws + 29984768);
    unsigned short* w2t  = (unsigned short*)(ws + 45225984);
    unsigned short* w3t  = (unsigned short*)(ws + 45373440);
    unsigned short* feat = (unsigned short*)(ws + 45963264);
    unsigned short* corr = (unsigned short*)(ws + 0);
    unsigned short* Wt   = (unsigned short*)(ws + 29491200);
    unsigned short* part = (unsigned short*)(ws + 41132032);
    unsigned short* r1   = (unsigned short*)(ws + 74162176);
    unsigned short* Wt2  = (unsigned short*)(ws + 76521472);
    float*          partC= (float*)(ws + 41132032);
    float*          partD= (float*)(ws + 48000000);

    k_wx<<<dim3(2240), 256, 0, stream>>>(w2, w3, cw2, w2t, w3t, Wt2);

    for (int chunk = 0; chunk < 2; ++chunk) {
        const float* img = chunk ? imgB : imgA;
        const int f0 = chunk * 16;
        k_conv1<<<dim3(15, 30, 16), 256, 0, stream>>>(img, w1, b1, c1);
        k_conv2<<<dim3(450),        256, 0, stream>>>(c1, w2t, b2, c2);
        k_conv3<<<dim3(113, 4),     256, 0, stream>>>(c2, w3t, b3, feat, f0);
    }
    k_l2norm  <<<dim3(8192),  256, 0, stream>>>(feat);
    k_corr    <<<dim3(1024),  256, 0, stream>>>(feat, corr);
    k_corrnorm<<<dim3(3600),  256, 0, stream>>>(corr);
    k_wt1     <<<dim3(29, 49),256, 0, stream>>>(cw1, Wt);
    k_cw1     <<<dim3(252),   512, 0, stream>>>(corr, Wt, part);
    k_r1fin   <<<dim3(1152),  256, 0, stream>>>(part, cb1, g1, be1, m1, v1, r1);
    k_cw2     <<<dim3(400),   256, 0, stream>>>(r1, Wt2, partC);
    k_dense   <<<dim3(16, 5), 256, 0, stream>>>(partC, cb2, g2, be2, m2, v2, dw, partD);
    k_dfin    <<<dim3(1),     288, 0, stream>>>(partD, db, (float*)d_out);
}

// Round 10
// 305.353 us; speedup vs baseline: 21.9369x; 1.4278x over previous
//
#include <hip/hip_runtime.h>

#define EPSF    1e-6f
#define BN_EPSF 1e-3f

typedef __attribute__((ext_vector_type(8))) short bf16x8;   // 8 bf16 in 4 VGPRs
typedef __attribute__((ext_vector_type(4))) float f32x4;

__device__ __forceinline__ unsigned short f2bf(float f) {
    unsigned int u = __builtin_bit_cast(unsigned int, f);
    u = (u + 0x7FFFu + ((u >> 16) & 1u)) >> 16;            // RNE
    return (unsigned short)u;
}
__device__ __forceinline__ float bf2f(unsigned short h) {
    unsigned int u = ((unsigned int)h) << 16;
    return __builtin_bit_cast(float, u);
}
__device__ __forceinline__ unsigned short f2h(float f) {
    return __builtin_bit_cast(unsigned short, (_Float16)f);
}
__device__ __forceinline__ float h2f(unsigned short h) {
    return (float)__builtin_bit_cast(_Float16, h);
}
// async global->LDS, 16 bytes per lane; lds dest is wave-uniform base + lane*16
__device__ __forceinline__ void gl16(const void* g, void* l) {
    __builtin_amdgcn_global_load_lds((const __attribute__((address_space(1))) void*)g,
                                     (__attribute__((address_space(3))) void*)l, 16, 0, 0);
}
// counted-vmcnt barrier pair (2-phase kernels)
#define PIPE_WAIT(N)                                        \
    asm volatile("s_waitcnt vmcnt(" #N ")" ::: "memory");   \
    __builtin_amdgcn_sched_barrier(0);                      \
    __builtin_amdgcn_s_barrier();                           \
    __builtin_amdgcn_sched_barrier(0);

// ======================= merged weight conversions (w2t | w3t | wt2) =========
__global__ __launch_bounds__(256) void k_wx(
        const float* __restrict__ w2, const float* __restrict__ w3,
        const float* __restrict__ cw2w,
        unsigned short* __restrict__ w2t, unsigned short* __restrict__ w3t,
        unsigned short* __restrict__ wt2) {
    const int bid = blockIdx.x;                            // 2240
    if (bid < 288) {
        int idx = bid * 256 + threadIdx.x;                 // 73728
        int n = idx / 576, k = idx - n * 576;
        w2t[idx] = f2bf(w2[(size_t)k * 128 + n]);
    } else if (bid < 1440) {
        int idx = (bid - 288) * 256 + threadIdx.x;         // 294912
        int n = idx / 1152, k = idx - n * 1152;
        w3t[idx] = f2bf(w3[(size_t)k * 256 + n]);
    } else {
        int idx = (bid - 1440) * 256 + threadIdx.x;        // 204800
        int n = idx / 3200, k = idx - n * 3200;
        wt2[idx] = f2bf(cw2w[(size_t)k * 64 + n]);
    }
}
// Wt[n][k'], k'=s*928+q, zero for q>=900; coalesced LDS transpose. grid (29,49)
__global__ __launch_bounds__(256) void k_wt1(const float* __restrict__ W,
                                             unsigned short* __restrict__ Wt) {
    __shared__ float tile[32][132];
    const int s = blockIdx.y;              // 49
    const int q0 = blockIdx.x * 32;        // 0..896
    const int t = threadIdx.x;
    const int n = t & 127, rr = t >> 7;
    #pragma unroll
    for (int r = rr; r < 32; r += 2) {
        int q = q0 + r;
        tile[r][n] = (q < 900) ? W[((size_t)(s * 900 + q)) * 128 + n] : 0.f;
    }
    __syncthreads();
    const int n2 = t >> 1, half = t & 1;
    unsigned short* dst = Wt + (size_t)n2 * 45472 + s * 928 + q0 + half * 16;
    #pragma unroll
    for (int u = 0; u < 16; ++u) dst[u] = f2bf(tile[half * 16 + u][n2]);
}

// ======================= conv1 v3: LDS-staged strip, vector loads ============
// grid (15, 30, 16) x 256 thr; block stages 9 img rows x 52 floats in LDS via
// per-lane float4 vector loads (vmcnt path), waves read back as broadcast
// ds_read_b128. FMA order identical to v1 (zero taps add +0.0 exactly).
__global__ __launch_bounds__(256) void k_conv1(
        const float* __restrict__ img,
        const float* __restrict__ w, const float* __restrict__ bias,
        unsigned short* __restrict__ c1) {
    __shared__ float lds[9][56];
    const int t = threadIdx.x;
    const int co = t & 63, wv = t >> 6;
    const int bx = blockIdx.x;                             // 15
    const int x0 = bx * 8;
    const int by = blockIdx.y;                             // 30
    const int b  = blockIdx.z;                             // 16
    // stage 9 rows x 13 float4 (117 threads, one vector load each)
    if (t < 117) {
        const int r = t / 13, j = t - r * 13;
        const int iy = 8 * by + r;
        float4 v = make_float4(0.f, 0.f, 0.f, 0.f);
        const int fbase = 48 * bx + 4 * j;                 // float idx within row
        if (iy < 240 && fbase < 720)
            v = *(const float4*)(img + ((size_t)(b * 240 + iy)) * 720 + fbase);
        *(float4*)&lds[r][4 * j] = v;
    }
    __syncthreads();
    float wr[9][3];
    #pragma unroll
    for (int s = 0; s < 9; ++s)
        #pragma unroll
        for (int c = 0; c < 3; ++c)
            wr[s][c] = w[(s * 3 + c) * 64 + co];
    const float bb = bias[co];
    float acc[8] = {bb, bb, bb, bb, bb, bb, bb, bb};
    #pragma unroll
    for (int ky = 0; ky < 3; ++ky) {
        const int lrow = 2 * wv + ky;                      // iy = 8*by + 2*wv + ky
        float iv[52];
        #pragma unroll
        for (int j = 0; j < 13; ++j) {
            float4 v = *(const float4*)&lds[lrow][4 * j];
            iv[4 * j] = v.x; iv[4 * j + 1] = v.y;
            iv[4 * j + 2] = v.z; iv[4 * j + 3] = v.w;
        }
        #pragma unroll
        for (int u = 0; u < 8; ++u)
            #pragma unroll
            for (int kx = 0; kx < 3; ++kx)
                #pragma unroll
                for (int c = 0; c < 3; ++c)
                    acc[u] = fmaf(iv[(2 * u + kx) * 3 + c], wr[ky * 3 + kx][c], acc[u]);
    }
    const int oy = by * 4 + wv;
    unsigned short* orow = c1 + ((size_t)(b * 121 + oy) * 121 + x0) * 64 + co;
    #pragma unroll
    for (int u = 0; u < 8; ++u)
        orow[(size_t)u * 64] = f2bf(fmaxf(acc[u], 0.f));
    // fused zero-padding of row/col 120
    if (x0 == 112)
        c1[((size_t)(b * 121 + oy) * 121 + 120) * 64 + co] = 0;
    if (oy == 119) {
        #pragma unroll
        for (int u = 0; u < 8; ++u)
            c1[((size_t)(b * 121 + 120) * 121 + x0 + u) * 64 + co] = 0;
        if (x0 == 112)
            c1[((size_t)(b * 121 + 120) * 121 + 120) * 64 + co] = 0;
    }
}

// ======================= conv2 MFMA: M=57600 N=128 K=576 (3-buf pipeline) ====
__global__ __launch_bounds__(256) void k_conv2(
        const unsigned short* __restrict__ c1, const unsigned short* __restrict__ w2t,
        const float* __restrict__ b2, unsigned short* __restrict__ c2) {
    __shared__ __align__(16) unsigned short As[3][128 * 32];
    __shared__ __align__(16) unsigned short Bs[3][128 * 32];
    const int t = threadIdx.x, w = t >> 6, l = t & 63;
    const int m0 = blockIdx.x * 128;                       // grid 450
    const int ko = (l & 3) * 8;
    size_t aga[2], bga[2];
    #pragma unroll
    for (int i = 0; i < 2; ++i) {
        int r = (w * 2 + i) * 16 + (l >> 2);
        int m = m0 + r;
        int bl = m / 3600, rem = m - bl * 3600, oy = rem / 60, ox = rem - oy * 60;
        aga[i] = (size_t)((bl * 121 + 2 * oy) * 121 + 2 * ox) * 64 + ko;
        bga[i] = (size_t)r * 576 + ko;
    }
    const int wr = (w >> 1) * 64, wc = (w & 1) * 64, lr = l & 15, lk = (l >> 4) * 8;
    f32x4 acc[4][4] = {};
    auto stage = [&](int buf, int s) {
        int ky = s / 6, r6 = s - ky * 6, kx = r6 >> 1, h = r6 & 1;
        int aoff = (ky * 121 + kx) * 64 + h * 32;
        int boff = (ky * 3 + kx) * 64 + h * 32;
        #pragma unroll
        for (int i = 0; i < 2; ++i) {
            gl16(c1 + aga[i] + aoff, &As[buf][(w * 2 + i) * 512]);
            gl16(w2t + bga[i] + boff, &Bs[buf][(w * 2 + i) * 512]);
        }
    };
    stage(0, 0); stage(1, 1);
    int cur = 0, pre = 2;
    for (int s = 0; s < 18; ++s) {
        if (s + 1 < 18) { PIPE_WAIT(4) } else { PIPE_WAIT(0) }
        if (s + 2 < 18) stage(pre, s + 2);
        bf16x8 af[4], bfv[4];
        #pragma unroll
        for (int i = 0; i < 4; ++i) af[i] = *(const bf16x8*)&As[cur][(wr + i * 16 + lr) * 32 + lk];
        #pragma unroll
        for (int j = 0; j < 4; ++j) bfv[j] = *(const bf16x8*)&Bs[cur][(wc + j * 16 + lr) * 32 + lk];
        #pragma unroll
        for (int i = 0; i < 4; ++i)
            #pragma unroll
            for (int j = 0; j < 4; ++j)
                acc[i][j] = __builtin_amdgcn_mfma_f32_16x16x32_bf16(af[i], bfv[j], acc[i][j], 0, 0, 0);
        pre = cur; cur = (cur == 2) ? 0 : cur + 1;
    }
    float bias[4];
    #pragma unroll
    for (int j = 0; j < 4; ++j) bias[j] = b2[wc + j * 16 + lr];
    #pragma unroll
    for (int i = 0; i < 4; ++i)
        #pragma unroll
        for (int r = 0; r < 4; ++r) {
            int m = m0 + wr + i * 16 + (l >> 4) * 4 + r;
            int bl = m / 3600, rem = m - bl * 3600, oy = rem / 60, ox = rem - oy * 60;
            size_t ob = (size_t)((bl * 61 + oy) * 61 + ox) * 128;
            #pragma unroll
            for (int j = 0; j < 4; ++j)
                c2[ob + wc + j * 16 + lr] = f2bf(fmaxf(acc[i][j][r] + bias[j], 0.f));
            const bool bx = (ox == 59), by = (oy == 59);
            if (bx) {
                size_t zb = (size_t)((bl * 61 + oy) * 61 + 60) * 128;
                #pragma unroll
                for (int j = 0; j < 4; ++j) c2[zb + wc + j * 16 + lr] = 0;
            }
            if (by) {
                size_t zb = (size_t)((bl * 61 + 60) * 61 + ox) * 128;
                #pragma unroll
                for (int j = 0; j < 4; ++j) c2[zb + wc + j * 16 + lr] = 0;
            }
            if (bx && by) {
                size_t zb = (size_t)((bl * 61 + 60) * 61 + 60) * 128;
                #pragma unroll
                for (int j = 0; j < 4; ++j) c2[zb + wc + j * 16 + lr] = 0;
            }
        }
}

// ======================= conv3 MFMA: M=14400 N=256 K=1152 (3-buf) ============
// feat padded to [32][1024][256]
__global__ __launch_bounds__(256) void k_conv3(
        const unsigned short* __restrict__ c2, const unsigned short* __restrict__ w3t,
        const float* __restrict__ b3, unsigned short* __restrict__ feat, int f0) {
    __shared__ __align__(16) unsigned short As[3][128 * 32];
    __shared__ __align__(16) unsigned short Bs[3][64 * 32];
    const int t = threadIdx.x, w = t >> 6, l = t & 63;
    const int m0 = blockIdx.x * 128, n0 = blockIdx.y * 64;   // grid (113,4)
    const int ko = (l & 3) * 8;
    size_t aga[2], bga;
    #pragma unroll
    for (int i = 0; i < 2; ++i) {
        int r = (w * 2 + i) * 16 + (l >> 2);
        int m = min(m0 + r, 14399);
        int bl = m / 900, rem = m - bl * 900, oy = rem / 30, ox = rem - oy * 30;
        aga[i] = (size_t)((bl * 61 + 2 * oy) * 61 + 2 * ox) * 128 + ko;
    }
    { int n = n0 + w * 16 + (l >> 2); bga = (size_t)n * 1152 + ko; }
    const int wr = (w >> 1) * 64, wc = (w & 1) * 32, lr = l & 15, lk = (l >> 4) * 8;
    f32x4 acc[4][2] = {};
    auto stage = [&](int buf, int s) {
        int ky = s / 12, r12 = s - ky * 12, kx = r12 >> 2, h = r12 & 3;
        int aoff = (ky * 61 + kx) * 128 + h * 32;
        int boff = (ky * 3 + kx) * 128 + h * 32;
        #pragma unroll
        for (int i = 0; i < 2; ++i)
            gl16(c2 + aga[i] + aoff, &As[buf][(w * 2 + i) * 512]);
        gl16(w3t + bga + boff, &Bs[buf][w * 512]);
    };
    stage(0, 0); stage(1, 1);
    int cur = 0, pre = 2;
    for (int s = 0; s < 36; ++s) {
        if (s + 1 < 36) { PIPE_WAIT(3) } else { PIPE_WAIT(0) }
        if (s + 2 < 36) stage(pre, s + 2);
        bf16x8 af[4], bfv[2];
        #pragma unroll
        for (int i = 0; i < 4; ++i) af[i] = *(const bf16x8*)&As[cur][(wr + i * 16 + lr) * 32 + lk];
        #pragma unroll
        for (int j = 0; j < 2; ++j) bfv[j] = *(const bf16x8*)&Bs[cur][(wc + j * 16 + lr) * 32 + lk];
        #pragma unroll
        for (int i = 0; i < 4; ++i)
            #pragma unroll
            for (int j = 0; j < 2; ++j)
                acc[i][j] = __builtin_amdgcn_mfma_f32_16x16x32_bf16(af[i], bfv[j], acc[i][j], 0, 0, 0);
        pre = cur; cur = (cur == 2) ? 0 : cur + 1;
    }
    float bias[2];
    #pragma unroll
    for (int j = 0; j < 2; ++j) bias[j] = b3[n0 + wc + j * 16 + lr];
    #pragma unroll
    for (int i = 0; i < 4; ++i)
        #pragma unroll
        for (int r = 0; r < 4; ++r) {
            int m = m0 + wr + i * 16 + (l >> 4) * 4 + r;
            if (m < 14400) {
                int bl = m / 900, pos = m - bl * 900;
                size_t ob = ((size_t)(f0 + bl) * 1024 + pos) * 256;
                #pragma unroll
                for (int j = 0; j < 2; ++j)
                    feat[ob + n0 + wc + j * 16 + lr] = f2bf(fmaxf(acc[i][j][r] + bias[j], 0.f));
            }
        }
}

// ======================= l2norm: wave per row, rows 900..1023 zeroed =========
__global__ __launch_bounds__(256) void k_l2norm(unsigned short* __restrict__ feat) {
    const int t = threadIdx.x, wv = t >> 6, ln = t & 63;
    const int R = blockIdx.x * 4 + wv;             // 32768 rows, grid 8192
    const int pos = R & 1023;
    ushort4* fp4 = (ushort4*)(feat + (size_t)R * 256);
    if (pos >= 900) { fp4[ln] = make_ushort4(0, 0, 0, 0); return; }
    ushort4 u = fp4[ln];
    float x0 = bf2f(u.x), x1 = bf2f(u.y), x2 = bf2f(u.z), x3 = bf2f(u.w);
    float s = x0 * x0 + x1 * x1 + x2 * x2 + x3 * x3;
    #pragma unroll
    for (int m = 1; m < 64; m <<= 1) s += __shfl_xor(s, m);
    const float inv = 1.f / sqrtf(s + EPSF);
    u.x = f2bf(x0 * inv); u.y = f2bf(x1 * inv);
    u.z = f2bf(x2 * inv); u.w = f2bf(x3 * inv);
    fp4[ln] = u;
}

// ======================= corr MFMA: per-b 1024x1024 padded, 128-tile =========
__global__ __launch_bounds__(256) void k_corr(
        const unsigned short* __restrict__ feat, unsigned short* __restrict__ corr) {
    __shared__ __align__(16) unsigned short As[3][128 * 32];
    __shared__ __align__(16) unsigned short Bs[3][128 * 32];
    const int t = threadIdx.x, w = t >> 6, l = t & 63;
    const int id0 = blockIdx.x;                            // 1024
    const int sw = (id0 & 7) * 128 + (id0 >> 3);           // bijective XCD swizzle
    const int b = sw >> 6, rem = sw & 63;
    const int p0 = (rem >> 3) * 128, q0 = (rem & 7) * 128;
    const int ko = (l & 3) * 8;
    const unsigned short* fA = feat + (size_t)b * 1024 * 256;
    const unsigned short* fB = feat + (size_t)(16 + b) * 1024 * 256;
    size_t aga[2], bga[2];
    #pragma unroll
    for (int i = 0; i < 2; ++i) {
        int r = (w * 2 + i) * 16 + (l >> 2);
        aga[i] = (size_t)(p0 + r) * 256 + ko;
        bga[i] = (size_t)(q0 + r) * 256 + ko;
    }
    const int wr = (w >> 1) * 64, wc = (w & 1) * 64, lr = l & 15, lk = (l >> 4) * 8;
    f32x4 acc[4][4] = {};
    auto stage = [&](int buf, int s) {
        #pragma unroll
        for (int i = 0; i < 2; ++i) {
            gl16(fA + aga[i] + s * 32, &As[buf][(w * 2 + i) * 512]);
            gl16(fB + bga[i] + s * 32, &Bs[buf][(w * 2 + i) * 512]);
        }
    };
    stage(0, 0); stage(1, 1);
    int cur = 0, pre = 2;
    for (int s = 0; s < 8; ++s) {
        if (s + 1 < 8) { PIPE_WAIT(4) } else { PIPE_WAIT(0) }
        if (s + 2 < 8) stage(pre, s + 2);
        bf16x8 af[4], bfv[4];
        #pragma unroll
        for (int i = 0; i < 4; ++i) af[i] = *(const bf16x8*)&As[cur][(wr + i * 16 + lr) * 32 + lk];
        #pragma unroll
        for (int j = 0; j < 4; ++j) bfv[j] = *(const bf16x8*)&Bs[cur][(wc + j * 16 + lr) * 32 + lk];
        #pragma unroll
        for (int i = 0; i < 4; ++i)
            #pragma unroll
            for (int j = 0; j < 4; ++j)
                acc[i][j] = __builtin_amdgcn_mfma_f32_16x16x32_bf16(af[i], bfv[j], acc[i][j], 0, 0, 0);
        pre = cur; cur = (cur == 2) ? 0 : cur + 1;
    }
    unsigned short* cb = corr + (size_t)b * 960 * 960;
    #pragma unroll
    for (int i = 0; i < 4; ++i)
        #pragma unroll
        for (int r = 0; r < 4; ++r) {
            int row = p0 + wr + i * 16 + (l >> 4) * 4 + r;
            if (row < 960) {
                #pragma unroll
                for (int j = 0; j < 4; ++j) {
                    int col = q0 + wc + j * 16 + lr;
                    if (col < 960)
                        cb[(size_t)row * 960 + col] = f2bf(fmaxf(acc[i][j][r], 0.f));
                }
            }
        }
}

// ======================= corr L2 norm: one wave per row ======================
__global__ __launch_bounds__(256) void k_corrnorm(unsigned short* __restrict__ corr) {
    const int t = threadIdx.x, wv = t >> 6, ln = t & 63;
    const int row = blockIdx.x * 4 + wv;       // 14400 rows, grid 3600
    const int b = row / 900, p = row - b * 900;
    ushort4* cp4 = (ushort4*)(corr + ((size_t)b * 960 + p) * 960);
    float x[16];
    float s = 0.f;
    #pragma unroll
    for (int i = 0; i < 4; ++i) {
        const int idx = ln + 64 * i;
        float v0 = 0.f, v1 = 0.f, v2 = 0.f, v3 = 0.f;
        if (idx < 225) {
            ushort4 u = cp4[idx];
            v0 = fmaxf(bf2f(u.x), 0.f); v1 = fmaxf(bf2f(u.y), 0.f);
            v2 = fmaxf(bf2f(u.z), 0.f); v3 = fmaxf(bf2f(u.w), 0.f);
        }
        x[i * 4 + 0] = v0; x[i * 4 + 1] = v1; x[i * 4 + 2] = v2; x[i * 4 + 3] = v3;
        s += v0 * v0 + v1 * v1 + v2 * v2 + v3 * v3;
    }
    #pragma unroll
    for (int m = 1; m < 64; m <<= 1) s += __shfl_xor(s, m);
    const float sc = 1.f / sqrtf(s + EPSF);
    #pragma unroll
    for (int i = 0; i < 4; ++i) {
        const int idx = ln + 64 * i;
        if (idx < 225) {
            ushort4 u;
            u.x = f2bf(x[i * 4 + 0] * sc); u.y = f2bf(x[i * 4 + 1] * sc);
            u.z = f2bf(x[i * 4 + 2] * sc); u.w = f2bf(x[i * 4 + 3] * sc);
            cp4[idx] = u;
        }
    }
}

// ======================= cw1 MFMA v4: phased schedule, 512x128 block =========
// M=9216 N=128; 8 waves of 128x64; BK=32/phase; 3-seg LDS ring; T2 swizzle;
// counted vmcnt(5); setprio around MFMA cluster. grid 252 = 18mt x 14ks.
__global__ __launch_bounds__(512, 2) void k_cw1(
        const unsigned short* __restrict__ corr, const unsigned short* __restrict__ Wt,
        unsigned short* __restrict__ part) {
    __shared__ __align__(16) unsigned short As[3 * 512 * 32];   // 96 KB
    __shared__ __align__(16) unsigned short Bs[3 * 128 * 32];   // 24 KB
    const int t = threadIdx.x, w = t >> 6, l = t & 63;
    const int bid = blockIdx.x;
    const int mt = bid % 18, ks = bid / 18;
    const int m0 = mt * 512;
    // staging: row = t>>2, phys chunk = t&3; fetch global chunk = (t&3)^((row>>1)&3)
    const int kswz = ((t & 3) ^ ((t >> 3) & 3)) * 8;
    size_t aga[4];
    #pragma unroll
    for (int i = 0; i < 4; ++i) {
        int r = i * 128 + (t >> 2);
        int m = m0 + r;
        int b = m / 576, rem = m - b * 576, oy = rem / 24, ox = rem - oy * 24;
        aga[i] = (size_t)(b * 960 + oy * 30 + ox) * 960 + kswz;
    }
    const size_t bga = (size_t)(t >> 2) * 45472 + kswz;
    // q-major K schedule: 1421 steps of 32; ks<7 get 102, else 101
    const int sbase = ks * 101 + min(ks, 7);
    const int nt = 101 + (ks < 7 ? 1 : 0);
    const int wm = (w >> 1) * 128, wn = (w & 1) * 64;
    const int lr = l & 15, cI = l >> 4;
    const int rsw = (cI ^ ((lr >> 1) & 3)) * 8;     // swizzled read chunk (elems)
    f32x4 acc[8][4] = {};
    auto stage = [&](int sidx) {
        const int seg = sidx % 3;
        const int s = sbase + sidx;
        const int qi = s / 49, sq = s - qi * 49;
        const int ky = sq / 7, kx = sq - ky * 7;
        const int aoff = (ky * 30 + kx) * 960 + qi * 32;
        const int boff = sq * 928 + qi * 32;
        #pragma unroll
        for (int i = 0; i < 4; ++i)
            gl16(corr + aga[i] + aoff, &As[seg * 16384 + i * 4096 + w * 512]);
        gl16(Wt + bga + boff, &Bs[seg * 4096 + w * 512]);
    };
    stage(0); stage(1);
    for (int s = 0; s < nt; ++s) {
        if (s + 1 < nt) {
            asm volatile("s_waitcnt vmcnt(5)" ::: "memory");
        } else {
            asm volatile("s_waitcnt vmcnt(0)" ::: "memory");
        }
        __builtin_amdgcn_sched_barrier(0);
        __builtin_amdgcn_s_barrier();
        __builtin_amdgcn_sched_barrier(0);
        const int seg = s % 3;
        bf16x8 af[8], bfv[4];
        #pragma unroll
        for (int i = 0; i < 8; ++i)
            af[i] = *(const bf16x8*)&As[seg * 16384 + (wm + i * 16 + lr) * 32 + rsw];
        #pragma unroll
        for (int j = 0; j < 4; ++j)
            bfv[j] = *(const bf16x8*)&Bs[seg * 4096 + (wn + j * 16 + lr) * 32 + rsw];
        if (s + 2 < nt) stage(s + 2);
        asm volatile("s_waitcnt lgkmcnt(0)" ::: "memory");
        __builtin_amdgcn_sched_barrier(0);
        __builtin_amdgcn_s_setprio(1);
        #pragma unroll
        for (int i = 0; i < 8; ++i)
            #pragma unroll
            for (int j = 0; j < 4; ++j)
                acc[i][j] = __builtin_amdgcn_mfma_f32_16x16x32_bf16(af[i], bfv[j], acc[i][j], 0, 0, 0);
        __builtin_amdgcn_s_setprio(0);
        __builtin_amdgcn_sched_barrier(0);
        __builtin_amdgcn_s_barrier();
        __builtin_amdgcn_sched_barrier(0);
    }
    unsigned short* pb = part + ((size_t)ks * 9216 + m0) * 128;
    #pragma unroll
    for (int i = 0; i < 8; ++i)
        #pragma unroll
        for (int r = 0; r < 4; ++r) {
            int row = wm + i * 16 + (l >> 4) * 4 + r;
            #pragma unroll
            for (int j = 0; j < 4; ++j)
                pb[(size_t)row * 128 + wn + j * 16 + lr] = f2h(acc[i][j][r]);
        }
}

// ======================= reduce 14 fp16 partials + bias + relu + BN -> bf16 ==
__global__ __launch_bounds__(256) void k_r1fin(
        const unsigned short* __restrict__ part, const float* __restrict__ cb1,
        const float* __restrict__ g1, const float* __restrict__ be1,
        const float* __restrict__ m1, const float* __restrict__ v1,
        unsigned short* __restrict__ r1) {
    const int idx = blockIdx.x * 256 + threadIdx.x;        // grid 1152
    const size_t base = (size_t)idx * 4;
    const size_t N = 9216 * 128;
    float s0 = 0.f, s1 = 0.f, s2 = 0.f, s3 = 0.f;
    #pragma unroll
    for (int i = 0; i < 14; ++i) {
        ushort4 u = *(const ushort4*)(part + i * N + base);
        s0 += h2f(u.x); s1 += h2f(u.y); s2 += h2f(u.z); s3 += h2f(u.w);
    }
    const int co = (int)(base & 127);
    float r[4] = {s0, s1, s2, s3};
    ushort4 o;
    unsigned short* op = (unsigned short*)&o;
    #pragma unroll
    for (int j = 0; j < 4; ++j) {
        int c = co + j;
        float x = fmaxf(r[j] + cb1[c], 0.f);
        x = (x - m1[c]) * (g1[c] / sqrtf(v1[c] + BN_EPSF)) + be1[c];
        op[j] = f2bf(x);
    }
    *(ushort4*)(r1 + base) = o;
}

// ======================= cw2 MFMA: M=6400 N=64 K=3200, K-split 4, fp32 part ==
__global__ __launch_bounds__(256) void k_cw2(
        const unsigned short* __restrict__ r1, const unsigned short* __restrict__ Wt2,
        float* __restrict__ partC) {
    __shared__ __align__(16) unsigned short As[3][64 * 32];
    __shared__ __align__(16) unsigned short Bs[3][64 * 32];
    const int t = threadIdx.x, w = t >> 6, l = t & 63;
    const int bid = blockIdx.x;                            // 400
    const int mtb = bid % 100, ks = bid / 100;
    const int m0 = mtb * 64;
    const int sbase = ks * 25;
    const int ko = (l & 3) * 8;
    const int wi = w & 1;
    size_t ga[2];
    #pragma unroll
    for (int i = 0; i < 2; ++i) {
        int r = (wi * 2 + i) * 16 + (l >> 2);
        if (w < 2) {
            int m = m0 + r;
            int b = m / 400, rem = m - b * 400, oy = rem / 20, ox = rem - oy * 20;
            ga[i] = (size_t)((b * 24 + oy) * 24 + ox) * 128 + ko;
        } else {
            ga[i] = (size_t)r * 3200 + ko;
        }
    }
    const int wr = (w >> 1) * 32, wc = (w & 1) * 32, lr = l & 15, lk = (l >> 4) * 8;
    f32x4 acc[2][2] = {};
    auto stage = [&](int buf, int sidx) {
        int s = sbase + sidx;
        int kyx = s >> 2, h = s & 3;
        int ky = kyx / 5, kx = kyx - ky * 5;
        int aoff = (ky * 24 + kx) * 128 + h * 32;
        int boff = s * 32;
        #pragma unroll
        for (int i = 0; i < 2; ++i) {
            unsigned short* dst = (w < 2) ? &As[buf][(wi * 2 + i) * 512]
                                          : &Bs[buf][(wi * 2 + i) * 512];
            const unsigned short* src = (w < 2) ? r1 + ga[i] + aoff : Wt2 + ga[i] + boff;
            gl16(src, dst);
        }
    };
    stage(0, 0); stage(1, 1);
    int cur = 0, pre = 2;
    for (int s = 0; s < 25; ++s) {
        if (s + 1 < 25) { PIPE_WAIT(2) } else { PIPE_WAIT(0) }
        if (s + 2 < 25) stage(pre, s + 2);
        bf16x8 af[2], bfv[2];
        #pragma unroll
        for (int i = 0; i < 2; ++i) af[i] = *(const bf16x8*)&As[cur][(wr + i * 16 + lr) * 32 + lk];
        #pragma unroll
        for (int j = 0; j < 2; ++j) bfv[j] = *(const bf16x8*)&Bs[cur][(wc + j * 16 + lr) * 32 + lk];
        #pragma unroll
        for (int i = 0; i < 2; ++i)
            #pragma unroll
            for (int j = 0; j < 2; ++j)
                acc[i][j] = __builtin_amdgcn_mfma_f32_16x16x32_bf16(af[i], bfv[j], acc[i][j], 0, 0, 0);
        pre = cur; cur = (cur == 2) ? 0 : cur + 1;
    }
    float* pc = partC + (size_t)ks * 409600;
    #pragma unroll
    for (int i = 0; i < 2; ++i)
        #pragma unroll
        for (int r = 0; r < 4; ++r) {
            int m = m0 + wr + i * 16 + (l >> 4) * 4 + r;
            #pragma unroll
            for (int j = 0; j < 2; ++j)
                pc[(size_t)m * 64 + wc + j * 16 + lr] = acc[i][j][r];
        }
}

// ======================= dense: fold cw2 finalize (bias/relu/BN) + matvec ====
__global__ __launch_bounds__(256) void k_dense(
        const float* __restrict__ partC, const float* __restrict__ cb2,
        const float* __restrict__ g2, const float* __restrict__ be2,
        const float* __restrict__ m2, const float* __restrict__ v2,
        const float* __restrict__ dw, float* __restrict__ partD) {
    const int b = blockIdx.x, kb = blockIdx.y, t = threadIdx.x;  // (16,5)
    const int co = t & 63;
    const float sc2 = g2[co] / sqrtf(v2[co] + BN_EPSF);
    const float sh2 = be2[co] - m2[co] * sc2;
    const float bb = cb2[co];
    float s[18] = {};
    for (int k = t; k < 5120; k += 256) {
        const int kk = kb * 5120 + k;
        const size_t pi = (size_t)(b * 400 + (kk >> 6)) * 64 + co;
        float p = partC[pi] + partC[pi + 409600] + partC[pi + 819200] + partC[pi + 1228800];
        p = fmaxf(p + bb, 0.f) * sc2 + sh2;
        const float* dr = dw + (size_t)kk * 18;
        #pragma unroll
        for (int j = 0; j < 18; ++j) s[j] = fmaf(p, dr[j], s[j]);
    }
    #pragma unroll
    for (int j = 0; j < 18; ++j)
        #pragma unroll
        for (int m = 1; m < 64; m <<= 1) s[j] += __shfl_xor(s[j], m);
    __shared__ float red[4][18];
    if ((t & 63) == 0) {
        #pragma unroll
        for (int j = 0; j < 18; ++j) red[t >> 6][j] = s[j];
    }
    __syncthreads();
    if (t < 18) partD[(b * 5 + kb) * 18 + t] = red[0][t] + red[1][t] + red[2][t] + red[3][t];
}
__global__ __launch_bounds__(288) void k_dfin(
        const float* __restrict__ partD, const float* __restrict__ db,
        float* __restrict__ out) {
    const int i = threadIdx.x;                 // 288
    const int b = i / 18, j = i - b * 18;
    float s = db[j];
    #pragma unroll
    for (int k = 0; k < 5; ++k) s += partD[(b * 5 + k) * 18 + j];
    out[i] = s;
}

extern "C" void kernel_launch(void* const* d_in, const int* in_sizes, int n_in,
                              void* d_out, int out_size, void* d_ws, size_t ws_size,
                              hipStream_t stream) {
    const float* imgA = (const float*)d_in[0];
    const float* imgB = (const float*)d_in[1];
    const float* w1  = (const float*)d_in[2];
    const float* b1  = (const float*)d_in[3];
    const float* w2  = (const float*)d_in[4];
    const float* b2  = (const float*)d_in[5];
    const float* w3  = (const float*)d_in[6];
    const float* b3  = (const float*)d_in[7];
    const float* cw1 = (const float*)d_in[8];
    const float* cb1 = (const float*)d_in[9];
    const float* g1  = (const float*)d_in[10];
    const float* be1 = (const float*)d_in[11];
    const float* m1  = (const float*)d_in[12];
    const float* v1  = (const float*)d_in[13];
    const float* cw2 = (const float*)d_in[14];
    const float* cb2 = (const float*)d_in[15];
    const float* g2  = (const float*)d_in[16];
    const float* be2 = (const float*)d_in[17];
    const float* m2  = (const float*)d_in[18];
    const float* v2  = (const float*)d_in[19];
    const float* dw  = (const float*)d_in[20];
    const float* db  = (const float*)d_in[21];

    // ws layout (bytes):
    //  conv phase : c1@0 (30.0MB) c2@29,984,768 (15.2MB) w2t@45,225,984
    //               w3t@45,373,440  feat@45,963,264 (16.8MB, [32][1024][256])
    //  corr phase : corr@0 (29.5MB)  Wt@29,491,200 (11.6MB)
    //  cw1 phase  : part@41,132,032 (33.0MB fp16 x14)
    //  tail       : r1@74,162,176 (2.4MB)  Wt2@76,521,472
    //               partC@41,132,032 (6.6MB, part dead)  partD@48,000,000
    char* ws = (char*)d_ws;
    unsigned short* c1   = (unsigned short*)(ws + 0);
    unsigned short* c2   = (unsigned short*)(ws + 29984768);
    unsigned short* w2t  = (unsigned short*)(ws + 45225984);
    unsigned short* w3t  = (unsigned short*)(ws + 45373440);
    unsigned short* feat = (unsigned short*)(ws + 45963264);
    unsigned short* corr = (unsigned short*)(ws + 0);
    unsigned short* Wt   = (unsigned short*)(ws + 29491200);
    unsigned short* part = (unsigned short*)(ws + 41132032);
    unsigned short* r1   = (unsigned short*)(ws + 74162176);
    unsigned short* Wt2  = (unsigned short*)(ws + 76521472);
    float*          partC= (float*)(ws + 41132032);
    float*          partD= (float*)(ws + 48000000);

    k_wx<<<dim3(2240), 256, 0, stream>>>(w2, w3, cw2, w2t, w3t, Wt2);

    for (int chunk = 0; chunk < 2; ++chunk) {
        const float* img = chunk ? imgB : imgA;
        const int f0 = chunk * 16;
        k_conv1<<<dim3(15, 30, 16), 256, 0, stream>>>(img, w1, b1, c1);
        k_conv2<<<dim3(450),        256, 0, stream>>>(c1, w2t, b2, c2);
        k_conv3<<<dim3(113, 4),     256, 0, stream>>>(c2, w3t, b3, feat, f0);
    }
    k_l2norm  <<<dim3(8192),  256, 0, stream>>>(feat);
    k_corr    <<<dim3(1024),  256, 0, stream>>>(feat, corr);
    k_corrnorm<<<dim3(3600),  256, 0, stream>>>(corr);
    k_wt1     <<<dim3(29, 49),256, 0, stream>>>(cw1, Wt);
    k_cw1     <<<dim3(252),   512, 0, stream>>>(corr, Wt, part);
    k_r1fin   <<<dim3(1152),  256, 0, stream>>>(part, cb1, g1, be1, m1, v1, r1);
    k_cw2     <<<dim3(400),   256, 0, stream>>>(r1, Wt2, partC);
    k_dense   <<<dim3(16, 5), 256, 0, stream>>>(partC, cb2, g2, be2, m2, v2, dw, partD);
    k_dfin    <<<dim3(1),     288, 0, stream>>>(partD, db, (float*)d_out);
}

// Round 11
// 304.244 us; speedup vs baseline: 22.0169x; 1.0036x over previous
//
#include <hip/hip_runtime.h>

#define EPSF    1e-6f
#define BN_EPSF 1e-3f

typedef __attribute__((ext_vector_type(8))) short bf16x8;   // 8 bf16 in 4 VGPRs
typedef __attribute__((ext_vector_type(4))) float f32x4;

__device__ __forceinline__ unsigned short f2bf(float f) {
    unsigned int u = __builtin_bit_cast(unsigned int, f);
    u = (u + 0x7FFFu + ((u >> 16) & 1u)) >> 16;            // RNE
    return (unsigned short)u;
}
__device__ __forceinline__ float bf2f(unsigned short h) {
    unsigned int u = ((unsigned int)h) << 16;
    return __builtin_bit_cast(float, u);
}
__device__ __forceinline__ unsigned short f2h(float f) {
    return __builtin_bit_cast(unsigned short, (_Float16)f);
}
__device__ __forceinline__ float h2f(unsigned short h) {
    return (float)__builtin_bit_cast(_Float16, h);
}
// async global->LDS, 16 bytes per lane; lds dest is wave-uniform base + lane*16
__device__ __forceinline__ void gl16(const void* g, void* l) {
    __builtin_amdgcn_global_load_lds((const __attribute__((address_space(1))) void*)g,
                                     (__attribute__((address_space(3))) void*)l, 16, 0, 0);
}
// counted-vmcnt barrier pair
#define PIPE_WAIT(N)                                        \
    asm volatile("s_waitcnt vmcnt(" #N ")" ::: "memory");   \
    __builtin_amdgcn_sched_barrier(0);                      \
    __builtin_amdgcn_s_barrier();                           \
    __builtin_amdgcn_sched_barrier(0);

// ======================= merged weight conversions (w2t | w3t | wt2) =========
__global__ __launch_bounds__(256) void k_wx(
        const float* __restrict__ w2, const float* __restrict__ w3,
        const float* __restrict__ cw2w,
        unsigned short* __restrict__ w2t, unsigned short* __restrict__ w3t,
        unsigned short* __restrict__ wt2) {
    const int bid = blockIdx.x;                            // 2240
    if (bid < 288) {
        int idx = bid * 256 + threadIdx.x;                 // 73728
        int n = idx / 576, k = idx - n * 576;
        w2t[idx] = f2bf(w2[(size_t)k * 128 + n]);
    } else if (bid < 1440) {
        int idx = (bid - 288) * 256 + threadIdx.x;         // 294912
        int n = idx / 1152, k = idx - n * 1152;
        w3t[idx] = f2bf(w3[(size_t)k * 256 + n]);
    } else {
        int idx = (bid - 1440) * 256 + threadIdx.x;        // 204800
        int n = idx / 3200, k = idx - n * 3200;
        wt2[idx] = f2bf(cw2w[(size_t)k * 64 + n]);
    }
}
// Wt[n][k'], k'=s*928+q, zero for q>=900; coalesced LDS transpose. grid (29,49)
__global__ __launch_bounds__(256) void k_wt1(const float* __restrict__ W,
                                             unsigned short* __restrict__ Wt) {
    __shared__ float tile[32][132];
    const int s = blockIdx.y;              // 49
    const int q0 = blockIdx.x * 32;        // 0..896
    const int t = threadIdx.x;
    const int n = t & 127, rr = t >> 7;
    #pragma unroll
    for (int r = rr; r < 32; r += 2) {
        int q = q0 + r;
        tile[r][n] = (q < 900) ? W[((size_t)(s * 900 + q)) * 128 + n] : 0.f;
    }
    __syncthreads();
    const int n2 = t >> 1, half = t & 1;
    unsigned short* dst = Wt + (size_t)n2 * 45472 + s * 928 + q0 + half * 16;
    #pragma unroll
    for (int u = 0; u < 16; ++u) dst[u] = f2bf(tile[half * 16 + u][n2]);
}

// ======================= conv1 v3: LDS-staged strip, vector loads ============
__global__ __launch_bounds__(256) void k_conv1(
        const float* __restrict__ img,
        const float* __restrict__ w, const float* __restrict__ bias,
        unsigned short* __restrict__ c1) {
    __shared__ float lds[9][56];
    const int t = threadIdx.x;
    const int co = t & 63, wv = t >> 6;
    const int bx = blockIdx.x;                             // 15
    const int x0 = bx * 8;
    const int by = blockIdx.y;                             // 30
    const int b  = blockIdx.z;                             // 16
    if (t < 117) {
        const int r = t / 13, j = t - r * 13;
        const int iy = 8 * by + r;
        float4 v = make_float4(0.f, 0.f, 0.f, 0.f);
        const int fbase = 48 * bx + 4 * j;
        if (iy < 240 && fbase < 720)
            v = *(const float4*)(img + ((size_t)(b * 240 + iy)) * 720 + fbase);
        *(float4*)&lds[r][4 * j] = v;
    }
    __syncthreads();
    float wr[9][3];
    #pragma unroll
    for (int s = 0; s < 9; ++s)
        #pragma unroll
        for (int c = 0; c < 3; ++c)
            wr[s][c] = w[(s * 3 + c) * 64 + co];
    const float bb = bias[co];
    float acc[8] = {bb, bb, bb, bb, bb, bb, bb, bb};
    #pragma unroll
    for (int ky = 0; ky < 3; ++ky) {
        const int lrow = 2 * wv + ky;
        float iv[52];
        #pragma unroll
        for (int j = 0; j < 13; ++j) {
            float4 v = *(const float4*)&lds[lrow][4 * j];
            iv[4 * j] = v.x; iv[4 * j + 1] = v.y;
            iv[4 * j + 2] = v.z; iv[4 * j + 3] = v.w;
        }
        #pragma unroll
        for (int u = 0; u < 8; ++u)
            #pragma unroll
            for (int kx = 0; kx < 3; ++kx)
                #pragma unroll
                for (int c = 0; c < 3; ++c)
                    acc[u] = fmaf(iv[(2 * u + kx) * 3 + c], wr[ky * 3 + kx][c], acc[u]);
    }
    const int oy = by * 4 + wv;
    unsigned short* orow = c1 + ((size_t)(b * 121 + oy) * 121 + x0) * 64 + co;
    #pragma unroll
    for (int u = 0; u < 8; ++u)
        orow[(size_t)u * 64] = f2bf(fmaxf(acc[u], 0.f));
    if (x0 == 112)
        c1[((size_t)(b * 121 + oy) * 121 + 120) * 64 + co] = 0;
    if (oy == 119) {
        #pragma unroll
        for (int u = 0; u < 8; ++u)
            c1[((size_t)(b * 121 + 120) * 121 + x0 + u) * 64 + co] = 0;
        if (x0 == 112)
            c1[((size_t)(b * 121 + 120) * 121 + 120) * 64 + co] = 0;
    }
}

// ======================= conv2 MFMA: M=57600 N=128 K=576 (4-buf ring) ========
__global__ __launch_bounds__(256) void k_conv2(
        const unsigned short* __restrict__ c1, const unsigned short* __restrict__ w2t,
        const float* __restrict__ b2, unsigned short* __restrict__ c2) {
    __shared__ __align__(16) unsigned short As[4][128 * 32];
    __shared__ __align__(16) unsigned short Bs[4][128 * 32];
    const int t = threadIdx.x, w = t >> 6, l = t & 63;
    const int m0 = blockIdx.x * 128;                       // grid 450
    const int ko = (l & 3) * 8;
    size_t aga[2], bga[2];
    #pragma unroll
    for (int i = 0; i < 2; ++i) {
        int r = (w * 2 + i) * 16 + (l >> 2);
        int m = m0 + r;
        int bl = m / 3600, rem = m - bl * 3600, oy = rem / 60, ox = rem - oy * 60;
        aga[i] = (size_t)((bl * 121 + 2 * oy) * 121 + 2 * ox) * 64 + ko;
        bga[i] = (size_t)r * 576 + ko;
    }
    const int wr = (w >> 1) * 64, wc = (w & 1) * 64, lr = l & 15, lk = (l >> 4) * 8;
    f32x4 acc[4][4] = {};
    auto stage = [&](int s) {
        int buf = s & 3;
        int ky = s / 6, r6 = s - ky * 6, kx = r6 >> 1, h = r6 & 1;
        int aoff = (ky * 121 + kx) * 64 + h * 32;
        int boff = (ky * 3 + kx) * 64 + h * 32;
        #pragma unroll
        for (int i = 0; i < 2; ++i) {
            gl16(c1 + aga[i] + aoff, &As[buf][(w * 2 + i) * 512]);
            gl16(w2t + bga[i] + boff, &Bs[buf][(w * 2 + i) * 512]);
        }
    };
    stage(0); stage(1); stage(2);
    for (int s = 0; s < 18; ++s) {
        if (s + 2 < 18)      { PIPE_WAIT(8) }
        else if (s + 1 < 18) { PIPE_WAIT(4) }
        else                 { PIPE_WAIT(0) }
        if (s + 3 < 18) stage(s + 3);
        const int cur = s & 3;
        bf16x8 af[4], bfv[4];
        #pragma unroll
        for (int i = 0; i < 4; ++i) af[i] = *(const bf16x8*)&As[cur][(wr + i * 16 + lr) * 32 + lk];
        #pragma unroll
        for (int j = 0; j < 4; ++j) bfv[j] = *(const bf16x8*)&Bs[cur][(wc + j * 16 + lr) * 32 + lk];
        #pragma unroll
        for (int i = 0; i < 4; ++i)
            #pragma unroll
            for (int j = 0; j < 4; ++j)
                acc[i][j] = __builtin_amdgcn_mfma_f32_16x16x32_bf16(af[i], bfv[j], acc[i][j], 0, 0, 0);
    }
    float bias[4];
    #pragma unroll
    for (int j = 0; j < 4; ++j) bias[j] = b2[wc + j * 16 + lr];
    #pragma unroll
    for (int i = 0; i < 4; ++i)
        #pragma unroll
        for (int r = 0; r < 4; ++r) {
            int m = m0 + wr + i * 16 + (l >> 4) * 4 + r;
            int bl = m / 3600, rem = m - bl * 3600, oy = rem / 60, ox = rem - oy * 60;
            size_t ob = (size_t)((bl * 61 + oy) * 61 + ox) * 128;
            #pragma unroll
            for (int j = 0; j < 4; ++j)
                c2[ob + wc + j * 16 + lr] = f2bf(fmaxf(acc[i][j][r] + bias[j], 0.f));
            const bool bx = (ox == 59), by = (oy == 59);
            if (bx) {
                size_t zb = (size_t)((bl * 61 + oy) * 61 + 60) * 128;
                #pragma unroll
                for (int j = 0; j < 4; ++j) c2[zb + wc + j * 16 + lr] = 0;
            }
            if (by) {
                size_t zb = (size_t)((bl * 61 + 60) * 61 + ox) * 128;
                #pragma unroll
                for (int j = 0; j < 4; ++j) c2[zb + wc + j * 16 + lr] = 0;
            }
            if (bx && by) {
                size_t zb = (size_t)((bl * 61 + 60) * 61 + 60) * 128;
                #pragma unroll
                for (int j = 0; j < 4; ++j) c2[zb + wc + j * 16 + lr] = 0;
            }
        }
}

// ======================= conv3 MFMA: M=14400 N=256 K=1152 (4-buf ring) =======
// feat padded to [32][1024][256]
__global__ __launch_bounds__(256) void k_conv3(
        const unsigned short* __restrict__ c2, const unsigned short* __restrict__ w3t,
        const float* __restrict__ b3, unsigned short* __restrict__ feat, int f0) {
    __shared__ __align__(16) unsigned short As[4][128 * 32];
    __shared__ __align__(16) unsigned short Bs[4][64 * 32];
    const int t = threadIdx.x, w = t >> 6, l = t & 63;
    const int m0 = blockIdx.x * 128, n0 = blockIdx.y * 64;   // grid (113,4)
    const int ko = (l & 3) * 8;
    size_t aga[2], bga;
    #pragma unroll
    for (int i = 0; i < 2; ++i) {
        int r = (w * 2 + i) * 16 + (l >> 2);
        int m = min(m0 + r, 14399);
        int bl = m / 900, rem = m - bl * 900, oy = rem / 30, ox = rem - oy * 30;
        aga[i] = (size_t)((bl * 61 + 2 * oy) * 61 + 2 * ox) * 128 + ko;
    }
    { int n = n0 + w * 16 + (l >> 2); bga = (size_t)n * 1152 + ko; }
    const int wr = (w >> 1) * 64, wc = (w & 1) * 32, lr = l & 15, lk = (l >> 4) * 8;
    f32x4 acc[4][2] = {};
    auto stage = [&](int s) {
        int buf = s & 3;
        int ky = s / 12, r12 = s - ky * 12, kx = r12 >> 2, h = r12 & 3;
        int aoff = (ky * 61 + kx) * 128 + h * 32;
        int boff = (ky * 3 + kx) * 128 + h * 32;
        #pragma unroll
        for (int i = 0; i < 2; ++i)
            gl16(c2 + aga[i] + aoff, &As[buf][(w * 2 + i) * 512]);
        gl16(w3t + bga + boff, &Bs[buf][w * 512]);
    };
    stage(0); stage(1); stage(2);
    for (int s = 0; s < 36; ++s) {
        if (s + 2 < 36)      { PIPE_WAIT(6) }
        else if (s + 1 < 36) { PIPE_WAIT(3) }
        else                 { PIPE_WAIT(0) }
        if (s + 3 < 36) stage(s + 3);
        const int cur = s & 3;
        bf16x8 af[4], bfv[2];
        #pragma unroll
        for (int i = 0; i < 4; ++i) af[i] = *(const bf16x8*)&As[cur][(wr + i * 16 + lr) * 32 + lk];
        #pragma unroll
        for (int j = 0; j < 2; ++j) bfv[j] = *(const bf16x8*)&Bs[cur][(wc + j * 16 + lr) * 32 + lk];
        #pragma unroll
        for (int i = 0; i < 4; ++i)
            #pragma unroll
            for (int j = 0; j < 2; ++j)
                acc[i][j] = __builtin_amdgcn_mfma_f32_16x16x32_bf16(af[i], bfv[j], acc[i][j], 0, 0, 0);
    }
    float bias[2];
    #pragma unroll
    for (int j = 0; j < 2; ++j) bias[j] = b3[n0 + wc + j * 16 + lr];
    #pragma unroll
    for (int i = 0; i < 4; ++i)
        #pragma unroll
        for (int r = 0; r < 4; ++r) {
            int m = m0 + wr + i * 16 + (l >> 4) * 4 + r;
            if (m < 14400) {
                int bl = m / 900, pos = m - bl * 900;
                size_t ob = ((size_t)(f0 + bl) * 1024 + pos) * 256;
                #pragma unroll
                for (int j = 0; j < 2; ++j)
                    feat[ob + n0 + wc + j * 16 + lr] = f2bf(fmaxf(acc[i][j][r] + bias[j], 0.f));
            }
        }
}

// ======================= l2norm: wave per row, rows 900..1023 zeroed =========
__global__ __launch_bounds__(256) void k_l2norm(unsigned short* __restrict__ feat) {
    const int t = threadIdx.x, wv = t >> 6, ln = t & 63;
    const int R = blockIdx.x * 4 + wv;             // 32768 rows, grid 8192
    const int pos = R & 1023;
    ushort4* fp4 = (ushort4*)(feat + (size_t)R * 256);
    if (pos >= 900) { fp4[ln] = make_ushort4(0, 0, 0, 0); return; }
    ushort4 u = fp4[ln];
    float x0 = bf2f(u.x), x1 = bf2f(u.y), x2 = bf2f(u.z), x3 = bf2f(u.w);
    float s = x0 * x0 + x1 * x1 + x2 * x2 + x3 * x3;
    #pragma unroll
    for (int m = 1; m < 64; m <<= 1) s += __shfl_xor(s, m);
    const float inv = 1.f / sqrtf(s + EPSF);
    u.x = f2bf(x0 * inv); u.y = f2bf(x1 * inv);
    u.z = f2bf(x2 * inv); u.w = f2bf(x3 * inv);
    fp4[ln] = u;
}

// ======================= corr MFMA: per-b 1024x1024 padded, 128-tile =========
__global__ __launch_bounds__(256) void k_corr(
        const unsigned short* __restrict__ feat, unsigned short* __restrict__ corr) {
    __shared__ __align__(16) unsigned short As[4][128 * 32];
    __shared__ __align__(16) unsigned short Bs[4][128 * 32];
    const int t = threadIdx.x, w = t >> 6, l = t & 63;
    const int id0 = blockIdx.x;                            // 1024
    const int sw = (id0 & 7) * 128 + (id0 >> 3);           // bijective XCD swizzle
    const int b = sw >> 6, rem = sw & 63;
    const int p0 = (rem >> 3) * 128, q0 = (rem & 7) * 128;
    const int ko = (l & 3) * 8;
    const unsigned short* fA = feat + (size_t)b * 1024 * 256;
    const unsigned short* fB = feat + (size_t)(16 + b) * 1024 * 256;
    size_t aga[2], bga[2];
    #pragma unroll
    for (int i = 0; i < 2; ++i) {
        int r = (w * 2 + i) * 16 + (l >> 2);
        aga[i] = (size_t)(p0 + r) * 256 + ko;
        bga[i] = (size_t)(q0 + r) * 256 + ko;
    }
    const int wr = (w >> 1) * 64, wc = (w & 1) * 64, lr = l & 15, lk = (l >> 4) * 8;
    f32x4 acc[4][4] = {};
    auto stage = [&](int s) {
        int buf = s & 3;
        #pragma unroll
        for (int i = 0; i < 2; ++i) {
            gl16(fA + aga[i] + s * 32, &As[buf][(w * 2 + i) * 512]);
            gl16(fB + bga[i] + s * 32, &Bs[buf][(w * 2 + i) * 512]);
        }
    };
    stage(0); stage(1); stage(2);
    for (int s = 0; s < 8; ++s) {
        if (s + 2 < 8)      { PIPE_WAIT(8) }
        else if (s + 1 < 8) { PIPE_WAIT(4) }
        else                { PIPE_WAIT(0) }
        if (s + 3 < 8) stage(s + 3);
        const int cur = s & 3;
        bf16x8 af[4], bfv[4];
        #pragma unroll
        for (int i = 0; i < 4; ++i) af[i] = *(const bf16x8*)&As[cur][(wr + i * 16 + lr) * 32 + lk];
        #pragma unroll
        for (int j = 0; j < 4; ++j) bfv[j] = *(const bf16x8*)&Bs[cur][(wc + j * 16 + lr) * 32 + lk];
        #pragma unroll
        for (int i = 0; i < 4; ++i)
            #pragma unroll
            for (int j = 0; j < 4; ++j)
                acc[i][j] = __builtin_amdgcn_mfma_f32_16x16x32_bf16(af[i], bfv[j], acc[i][j], 0, 0, 0);
    }
    unsigned short* cb = corr + (size_t)b * 960 * 960;
    #pragma unroll
    for (int i = 0; i < 4; ++i)
        #pragma unroll
        for (int r = 0; r < 4; ++r) {
            int row = p0 + wr + i * 16 + (l >> 4) * 4 + r;
            if (row < 960) {
                #pragma unroll
                for (int j = 0; j < 4; ++j) {
                    int col = q0 + wc + j * 16 + lr;
                    if (col < 960)
                        cb[(size_t)row * 960 + col] = f2bf(fmaxf(acc[i][j][r], 0.f));
                }
            }
        }
}

// ======================= corr L2 norm: one wave per row ======================
__global__ __launch_bounds__(256) void k_corrnorm(unsigned short* __restrict__ corr) {
    const int t = threadIdx.x, wv = t >> 6, ln = t & 63;
    const int row = blockIdx.x * 4 + wv;       // 14400 rows, grid 3600
    const int b = row / 900, p = row - b * 900;
    ushort4* cp4 = (ushort4*)(corr + ((size_t)b * 960 + p) * 960);
    float x[16];
    float s = 0.f;
    #pragma unroll
    for (int i = 0; i < 4; ++i) {
        const int idx = ln + 64 * i;
        float v0 = 0.f, v1 = 0.f, v2 = 0.f, v3 = 0.f;
        if (idx < 225) {
            ushort4 u = cp4[idx];
            v0 = fmaxf(bf2f(u.x), 0.f); v1 = fmaxf(bf2f(u.y), 0.f);
            v2 = fmaxf(bf2f(u.z), 0.f); v3 = fmaxf(bf2f(u.w), 0.f);
        }
        x[i * 4 + 0] = v0; x[i * 4 + 1] = v1; x[i * 4 + 2] = v2; x[i * 4 + 3] = v3;
        s += v0 * v0 + v1 * v1 + v2 * v2 + v3 * v3;
    }
    #pragma unroll
    for (int m = 1; m < 64; m <<= 1) s += __shfl_xor(s, m);
    const float sc = 1.f / sqrtf(s + EPSF);
    #pragma unroll
    for (int i = 0; i < 4; ++i) {
        const int idx = ln + 64 * i;
        if (idx < 225) {
            ushort4 u;
            u.x = f2bf(x[i * 4 + 0] * sc); u.y = f2bf(x[i * 4 + 1] * sc);
            u.z = f2bf(x[i * 4 + 2] * sc); u.w = f2bf(x[i * 4 + 3] * sc);
            cp4[idx] = u;
        }
    }
}

// ======================= cw1 MFMA v5: phased, 512x128 block, 4-seg/160KB =====
// M=9216 N=128; 8 waves of 128x64; BK=32/phase; 4-seg LDS ring (2 stages in
// flight); T2 swizzle; counted vmcnt(10); setprio. grid 252 = 18mt x 14ks.
__global__ __launch_bounds__(512, 1) void k_cw1(
        const unsigned short* __restrict__ corr, const unsigned short* __restrict__ Wt,
        unsigned short* __restrict__ part) {
    __shared__ __align__(16) unsigned short As[4 * 512 * 32];   // 128 KB
    __shared__ __align__(16) unsigned short Bs[4 * 128 * 32];   // 32 KB
    const int t = threadIdx.x, w = t >> 6, l = t & 63;
    const int bid = blockIdx.x;
    const int mt = bid % 18, ks = bid / 18;
    const int m0 = mt * 512;
    // staging: row = t>>2, phys chunk = t&3; fetch global chunk = (t&3)^((row>>1)&3)
    const int kswz = ((t & 3) ^ ((t >> 3) & 3)) * 8;
    size_t aga[4];
    #pragma unroll
    for (int i = 0; i < 4; ++i) {
        int r = i * 128 + (t >> 2);
        int m = m0 + r;
        int b = m / 576, rem = m - b * 576, oy = rem / 24, ox = rem - oy * 24;
        aga[i] = (size_t)(b * 960 + oy * 30 + ox) * 960 + kswz;
    }
    const size_t bga = (size_t)(t >> 2) * 45472 + kswz;
    // q-major K schedule: 1421 steps of 32; ks<7 get 102, else 101
    const int sbase = ks * 101 + min(ks, 7);
    const int nt = 101 + (ks < 7 ? 1 : 0);
    const int wm = (w >> 1) * 128, wn = (w & 1) * 64;
    const int lr = l & 15, cI = l >> 4;
    const int rsw = (cI ^ ((lr >> 1) & 3)) * 8;     // swizzled read chunk (elems)
    f32x4 acc[8][4] = {};
    auto stage = [&](int sidx) {
        const int seg = sidx & 3;
        const int s = sbase + sidx;
        const int qi = s / 49, sq = s - qi * 49;
        const int ky = sq / 7, kx = sq - ky * 7;
        const int aoff = (ky * 30 + kx) * 960 + qi * 32;
        const int boff = sq * 928 + qi * 32;
        #pragma unroll
        for (int i = 0; i < 4; ++i)
            gl16(corr + aga[i] + aoff, &As[seg * 16384 + i * 4096 + w * 512]);
        gl16(Wt + bga + boff, &Bs[seg * 4096 + w * 512]);
    };
    stage(0); stage(1); stage(2);
    for (int s = 0; s < nt; ++s) {
        if (s + 2 < nt) {
            asm volatile("s_waitcnt vmcnt(10)" ::: "memory");
        } else if (s + 1 < nt) {
            asm volatile("s_waitcnt vmcnt(5)" ::: "memory");
        } else {
            asm volatile("s_waitcnt vmcnt(0)" ::: "memory");
        }
        __builtin_amdgcn_sched_barrier(0);
        __builtin_amdgcn_s_barrier();
        __builtin_amdgcn_sched_barrier(0);
        const int seg = s & 3;
        bf16x8 af[8], bfv[4];
        #pragma unroll
        for (int i = 0; i < 8; ++i)
            af[i] = *(const bf16x8*)&As[seg * 16384 + (wm + i * 16 + lr) * 32 + rsw];
        #pragma unroll
        for (int j = 0; j < 4; ++j)
            bfv[j] = *(const bf16x8*)&Bs[seg * 4096 + (wn + j * 16 + lr) * 32 + rsw];
        if (s + 3 < nt) stage(s + 3);
        asm volatile("s_waitcnt lgkmcnt(0)" ::: "memory");
        __builtin_amdgcn_sched_barrier(0);
        __builtin_amdgcn_s_setprio(1);
        #pragma unroll
        for (int i = 0; i < 8; ++i)
            #pragma unroll
            for (int j = 0; j < 4; ++j)
                acc[i][j] = __builtin_amdgcn_mfma_f32_16x16x32_bf16(af[i], bfv[j], acc[i][j], 0, 0, 0);
        __builtin_amdgcn_s_setprio(0);
        __builtin_amdgcn_sched_barrier(0);
        __builtin_amdgcn_s_barrier();
        __builtin_amdgcn_sched_barrier(0);
    }
    unsigned short* pb = part + ((size_t)ks * 9216 + m0) * 128;
    #pragma unroll
    for (int i = 0; i < 8; ++i)
        #pragma unroll
        for (int r = 0; r < 4; ++r) {
            int row = wm + i * 16 + (l >> 4) * 4 + r;
            #pragma unroll
            for (int j = 0; j < 4; ++j)
                pb[(size_t)row * 128 + wn + j * 16 + lr] = f2h(acc[i][j][r]);
        }
}

// ======================= reduce 14 fp16 partials + bias + relu + BN -> bf16 ==
__global__ __launch_bounds__(256) void k_r1fin(
        const unsigned short* __restrict__ part, const float* __restrict__ cb1,
        const float* __restrict__ g1, const float* __restrict__ be1,
        const float* __restrict__ m1, const float* __restrict__ v1,
        unsigned short* __restrict__ r1) {
    const int idx = blockIdx.x * 256 + threadIdx.x;        // grid 1152
    const size_t base = (size_t)idx * 4;
    const size_t N = 9216 * 128;
    float s0 = 0.f, s1 = 0.f, s2 = 0.f, s3 = 0.f;
    #pragma unroll
    for (int i = 0; i < 14; ++i) {
        ushort4 u = *(const ushort4*)(part + i * N + base);
        s0 += h2f(u.x); s1 += h2f(u.y); s2 += h2f(u.z); s3 += h2f(u.w);
    }
    const int co = (int)(base & 127);
    float r[4] = {s0, s1, s2, s3};
    ushort4 o;
    unsigned short* op = (unsigned short*)&o;
    #pragma unroll
    for (int j = 0; j < 4; ++j) {
        int c = co + j;
        float x = fmaxf(r[j] + cb1[c], 0.f);
        x = (x - m1[c]) * (g1[c] / sqrtf(v1[c] + BN_EPSF)) + be1[c];
        op[j] = f2bf(x);
    }
    *(ushort4*)(r1 + base) = o;
}

// ======================= cw2 MFMA: M=6400 N=64 K=3200, K-split 4, 4-buf ======
__global__ __launch_bounds__(256) void k_cw2(
        const unsigned short* __restrict__ r1, const unsigned short* __restrict__ Wt2,
        float* __restrict__ partC) {
    __shared__ __align__(16) unsigned short As[4][64 * 32];
    __shared__ __align__(16) unsigned short Bs[4][64 * 32];
    const int t = threadIdx.x, w = t >> 6, l = t & 63;
    const int bid = blockIdx.x;                            // 400
    const int mtb = bid % 100, ks = bid / 100;
    const int m0 = mtb * 64;
    const int sbase = ks * 25;
    const int ko = (l & 3) * 8;
    const int wi = w & 1;
    size_t ga[2];
    #pragma unroll
    for (int i = 0; i < 2; ++i) {
        int r = (wi * 2 + i) * 16 + (l >> 2);
        if (w < 2) {
            int m = m0 + r;
            int b = m / 400, rem = m - b * 400, oy = rem / 20, ox = rem - oy * 20;
            ga[i] = (size_t)((b * 24 + oy) * 24 + ox) * 128 + ko;
        } else {
            ga[i] = (size_t)r * 3200 + ko;
        }
    }
    const int wr = (w >> 1) * 32, wc = (w & 1) * 32, lr = l & 15, lk = (l >> 4) * 8;
    f32x4 acc[2][2] = {};
    auto stage = [&](int sidx) {
        int buf = sidx & 3;
        int s = sbase + sidx;
        int kyx = s >> 2, h = s & 3;
        int ky = kyx / 5, kx = kyx - ky * 5;
        int aoff = (ky * 24 + kx) * 128 + h * 32;
        int boff = s * 32;
        #pragma unroll
        for (int i = 0; i < 2; ++i) {
            unsigned short* dst = (w < 2) ? &As[buf][(wi * 2 + i) * 512]
                                          : &Bs[buf][(wi * 2 + i) * 512];
            const unsigned short* src = (w < 2) ? r1 + ga[i] + aoff : Wt2 + ga[i] + boff;
            gl16(src, dst);
        }
    };
    stage(0); stage(1); stage(2);
    for (int s = 0; s < 25; ++s) {
        if (s + 2 < 25)      { PIPE_WAIT(4) }
        else if (s + 1 < 25) { PIPE_WAIT(2) }
        else                 { PIPE_WAIT(0) }
        if (s + 3 < 25) stage(s + 3);
        const int cur = s & 3;
        bf16x8 af[2], bfv[2];
        #pragma unroll
        for (int i = 0; i < 2; ++i) af[i] = *(const bf16x8*)&As[cur][(wr + i * 16 + lr) * 32 + lk];
        #pragma unroll
        for (int j = 0; j < 2; ++j) bfv[j] = *(const bf16x8*)&Bs[cur][(wc + j * 16 + lr) * 32 + lk];
        #pragma unroll
        for (int i = 0; i < 2; ++i)
            #pragma unroll
            for (int j = 0; j < 2; ++j)
                acc[i][j] = __builtin_amdgcn_mfma_f32_16x16x32_bf16(af[i], bfv[j], acc[i][j], 0, 0, 0);
    }
    float* pc = partC + (size_t)ks * 409600;
    #pragma unroll
    for (int i = 0; i < 2; ++i)
        #pragma unroll
        for (int r = 0; r < 4; ++r) {
            int m = m0 + wr + i * 16 + (l >> 4) * 4 + r;
            #pragma unroll
            for (int j = 0; j < 2; ++j)
                pc[(size_t)m * 64 + wc + j * 16 + lr] = acc[i][j][r];
        }
}

// ======================= dense: fold cw2 finalize (bias/relu/BN) + matvec ====
__global__ __launch_bounds__(256) void k_dense(
        const float* __restrict__ partC, const float* __restrict__ cb2,
        const float* __restrict__ g2, const float* __restrict__ be2,
        const float* __restrict__ m2, const float* __restrict__ v2,
        const float* __restrict__ dw, float* __restrict__ partD) {
    const int b = blockIdx.x, kb = blockIdx.y, t = threadIdx.x;  // (16,5)
    const int co = t & 63;
    const float sc2 = g2[co] / sqrtf(v2[co] + BN_EPSF);
    const float sh2 = be2[co] - m2[co] * sc2;
    const float bb = cb2[co];
    float s[18] = {};
    for (int k = t; k < 5120; k += 256) {
        const int kk = kb * 5120 + k;
        const size_t pi = (size_t)(b * 400 + (kk >> 6)) * 64 + co;
        float p = partC[pi] + partC[pi + 409600] + partC[pi + 819200] + partC[pi + 1228800];
        p = fmaxf(p + bb, 0.f) * sc2 + sh2;
        const float* dr = dw + (size_t)kk * 18;
        #pragma unroll
        for (int j = 0; j < 18; ++j) s[j] = fmaf(p, dr[j], s[j]);
    }
    #pragma unroll
    for (int j = 0; j < 18; ++j)
        #pragma unroll
        for (int m = 1; m < 64; m <<= 1) s[j] += __shfl_xor(s[j], m);
    __shared__ float red[4][18];
    if ((t & 63) == 0) {
        #pragma unroll
        for (int j = 0; j < 18; ++j) red[t >> 6][j] = s[j];
    }
    __syncthreads();
    if (t < 18) partD[(b * 5 + kb) * 18 + t] = red[0][t] + red[1][t] + red[2][t] + red[3][t];
}
__global__ __launch_bounds__(288) void k_dfin(
        const float* __restrict__ partD, const float* __restrict__ db,
        float* __restrict__ out) {
    const int i = threadIdx.x;                 // 288
    const int b = i / 18, j = i - b * 18;
    float s = db[j];
    #pragma unroll
    for (int k = 0; k < 5; ++k) s += partD[(b * 5 + k) * 18 + j];
    out[i] = s;
}

extern "C" void kernel_launch(void* const* d_in, const int* in_sizes, int n_in,
                              void* d_out, int out_size, void* d_ws, size_t ws_size,
                              hipStream_t stream) {
    const float* imgA = (const float*)d_in[0];
    const float* imgB = (const float*)d_in[1];
    const float* w1  = (const float*)d_in[2];
    const float* b1  = (const float*)d_in[3];
    const float* w2  = (const float*)d_in[4];
    const float* b2  = (const float*)d_in[5];
    const float* w3  = (const float*)d_in[6];
    const float* b3  = (const float*)d_in[7];
    const float* cw1 = (const float*)d_in[8];
    const float* cb1 = (const float*)d_in[9];
    const float* g1  = (const float*)d_in[10];
    const float* be1 = (const float*)d_in[11];
    const float* m1  = (const float*)d_in[12];
    const float* v1  = (const float*)d_in[13];
    const float* cw2 = (const float*)d_in[14];
    const float* cb2 = (const float*)d_in[15];
    const float* g2  = (const float*)d_in[16];
    const float* be2 = (const float*)d_in[17];
    const float* m2  = (const float*)d_in[18];
    const float* v2  = (const float*)d_in[19];
    const float* dw  = (const float*)d_in[20];
    const float* db  = (const float*)d_in[21];

    // ws layout (bytes):
    //  conv phase : c1@0 (30.0MB) c2@29,984,768 (15.2MB) w2t@45,225,984
    //               w3t@45,373,440  feat@45,963,264 (16.8MB, [32][1024][256])
    //  corr phase : corr@0 (29.5MB)  Wt@29,491,200 (11.6MB)
    //  cw1 phase  : part@41,132,032 (33.0MB fp16 x14)
    //  tail       : r1@74,162,176 (2.4MB)  Wt2@76,521,472
    //               partC@41,132,032 (6.6MB, part dead)  partD@48,000,000
    char* ws = (char*)d_ws;
    unsigned short* c1   = (unsigned short*)(ws + 0);
    unsigned short* c2   = (unsigned short*)(ws + 29984768);
    unsigned short* w2t  = (unsigned short*)(ws + 45225984);
    unsigned short* w3t  = (unsigned short*)(ws + 45373440);
    unsigned short* feat = (unsigned short*)(ws + 45963264);
    unsigned short* corr = (unsigned short*)(ws + 0);
    unsigned short* Wt   = (unsigned short*)(ws + 29491200);
    unsigned short* part = (unsigned short*)(ws + 41132032);
    unsigned short* r1   = (unsigned short*)(ws + 74162176);
    unsigned short* Wt2  = (unsigned short*)(ws + 76521472);
    float*          partC= (float*)(ws + 41132032);
    float*          partD= (float*)(ws + 48000000);

    k_wx<<<dim3(2240), 256, 0, stream>>>(w2, w3, cw2, w2t, w3t, Wt2);

    for (int chunk = 0; chunk < 2; ++chunk) {
        const float* img = chunk ? imgB : imgA;
        const int f0 = chunk * 16;
        k_conv1<<<dim3(15, 30, 16), 256, 0, stream>>>(img, w1, b1, c1);
        k_conv2<<<dim3(450),        256, 0, stream>>>(c1, w2t, b2, c2);
        k_conv3<<<dim3(113, 4),     256, 0, stream>>>(c2, w3t, b3, feat, f0);
    }
    k_l2norm  <<<dim3(8192),  256, 0, stream>>>(feat);
    k_corr    <<<dim3(1024),  256, 0, stream>>>(feat, corr);
    k_corrnorm<<<dim3(3600),  256, 0, stream>>>(corr);
    k_wt1     <<<dim3(29, 49),256, 0, stream>>>(cw1, Wt);
    k_cw1     <<<dim3(252),   512, 0, stream>>>(corr, Wt, part);
    k_r1fin   <<<dim3(1152),  256, 0, stream>>>(part, cb1, g1, be1, m1, v1, r1);
    k_cw2     <<<dim3(400),   256, 0, stream>>>(r1, Wt2, partC);
    k_dense   <<<dim3(16, 5), 256, 0, stream>>>(partC, cb2, g2, be2, m2, v2, dw, partD);
    k_dfin    <<<dim3(1),     288, 0, stream>>>(partD, db, (float*)d_out);
}